// Round 1
// baseline (3237.787 us; speedup 1.0000x reference)
//
#include <hip/hip_runtime.h>
#include <cstddef>
#include <cstdint>

// Problem constants
#define BB   64
#define NN   512
#define BN   (BB*NN)          // 32768
#define EE   524288
#define DA   70
#define DE   14
#define DH   200
#define DI   6
#define T_SCALE 0.07071067811865475f   // sqrt(1/200)

// ---------------------------------------------------------------------------
// Kernel 1: per-node  h = layernorm(relu(atom @ W_atom))
// one block (256 threads) per node; blockIdx.y = side
// ---------------------------------------------------------------------------
__global__ __launch_bounds__(256) void node_kernel(
    const float* __restrict__ atom1, const float* __restrict__ atom2,
    const float* __restrict__ W_atom,
    const float* __restrict__ ln_g, const float* __restrict__ ln_b,
    float* __restrict__ h1, float* __restrict__ h2)
{
    const int side = blockIdx.y;
    const float* atom = side ? atom2 : atom1;
    float* h = side ? h2 : h1;
    const int node = blockIdx.x;
    const int tid = threadIdx.x;

    __shared__ float arow[DA];
    __shared__ float vals[DH];
    __shared__ float rs[256], rs2[256];

    if (tid < DA) arow[tid] = atom[(size_t)node*DA + tid];
    __syncthreads();

    float v = 0.0f;
    if (tid < DH) {
        float acc = 0.0f;
        #pragma unroll 10
        for (int k = 0; k < DA; k++) acc += arow[k] * W_atom[k*DH + tid];
        v = fmaxf(acc, 0.0f);
        vals[tid] = v;
    }
    rs[tid] = v; rs2[tid] = v*v;
    __syncthreads();
    for (int s = 128; s > 0; s >>= 1) {
        if (tid < s) { rs[tid] += rs[tid+s]; rs2[tid] += rs2[tid+s]; }
        __syncthreads();
    }
    const float mean = rs[0] * (1.0f/DH);
    const float var  = rs2[0] * (1.0f/DH) - mean*mean;
    const float rstd = rsqrtf(var + 1e-5f);
    if (tid < DH)
        h[(size_t)node*DH + tid] = ln_g[tid]*(vals[tid]-mean)*rstd + ln_b[tid];
}

// ---------------------------------------------------------------------------
// Kernel 2: per-edge  eh = layernorm(concat(relu(ef@W_edge), relu(rbf@W_rbf+b)))
// scatter-add into h[dst], count deg[dst].  1 wave per edge, 4 edges/block.
// ---------------------------------------------------------------------------
__global__ __launch_bounds__(256) void edge_kernel(
    const float* __restrict__ efeat1, const float* __restrict__ efeat2,
    const int* __restrict__ esrc1, const int* __restrict__ edst1,
    const int* __restrict__ esrc2, const int* __restrict__ edst2,
    const float* __restrict__ coords1, const float* __restrict__ coords2,
    const float* __restrict__ W_edge, const float* __restrict__ W_rbf,
    const float* __restrict__ b_rbf,
    const float* __restrict__ ln_g, const float* __restrict__ ln_b,
    float* __restrict__ h1, float* __restrict__ h2,
    int* __restrict__ deg1, int* __restrict__ deg2)
{
    const int side = blockIdx.y;
    const float* ef     = side ? efeat2  : efeat1;
    const int*   esrc   = side ? esrc2   : esrc1;
    const int*   edst   = side ? edst2   : edst1;
    const float* coords = side ? coords2 : coords1;
    float* h  = side ? h2 : h1;
    int*   dg = side ? deg2 : deg1;

    __shared__ float sWe[DE*100];
    __shared__ float sWr[16*100];
    __shared__ float sbr[100];
    __shared__ float sg[DH], sb[DH];

    const int tid = threadIdx.x;
    for (int i = tid; i < DE*100; i += 256) sWe[i] = W_edge[i];
    for (int i = tid; i < 16*100; i += 256) sWr[i] = W_rbf[i];
    if (tid < 100) sbr[tid] = b_rbf[tid];
    if (tid < DH) { sg[tid] = ln_g[tid]; sb[tid] = ln_b[tid]; }
    __syncthreads();

    const int wave = tid >> 6, lane = tid & 63;
    const int eid = blockIdx.x * 4 + wave;   // E = 131072*4 exactly

    const int src = esrc[eid], dst = edst[eid];
    float efr[DE];
    #pragma unroll
    for (int k = 0; k < DE; k++) efr[k] = ef[(size_t)eid*DE + k];

    const float dx = coords[src*3+0] - coords[dst*3+0];
    const float dy = coords[src*3+1] - coords[dst*3+1];
    const float dz = coords[src*3+2] - coords[dst*3+2];
    const float dist = sqrtf(dx*dx + dy*dy + dz*dz + 1e-12f);

    float rbf[16];
    #pragma unroll
    for (int k = 0; k < 16; k++) {
        const float t = (dist - (float)k*(5.0f/15.0f)) * (1.0f/0.3125f);
        rbf[k] = expf(-t*t);
    }

    float val[4];
    #pragma unroll
    for (int j = 0; j < 4; j++) {
        const int c = lane + 64*j;
        float v = 0.0f;
        if (c < 100) {
            #pragma unroll
            for (int k = 0; k < DE; k++) v += efr[k]*sWe[k*100 + c];
            v = fmaxf(v, 0.0f);
        } else if (c < DH) {
            const int cc = c - 100;
            v = sbr[cc];
            #pragma unroll
            for (int k = 0; k < 16; k++) v += rbf[k]*sWr[k*100 + cc];
            v = fmaxf(v, 0.0f);
        }
        val[j] = v;
    }
    float s  = val[0]+val[1]+val[2]+val[3];
    float s2 = val[0]*val[0]+val[1]*val[1]+val[2]*val[2]+val[3]*val[3];
    #pragma unroll
    for (int off = 1; off < 64; off <<= 1) {
        s  += __shfl_xor(s,  off, 64);
        s2 += __shfl_xor(s2, off, 64);
    }
    const float mean = s * (1.0f/DH);
    const float var  = s2 * (1.0f/DH) - mean*mean;
    const float rstd = rsqrtf(var + 1e-5f);

    #pragma unroll
    for (int j = 0; j < 4; j++) {
        const int c = lane + 64*j;
        if (c < DH) {
            const float o = sg[c]*(val[j]-mean)*rstd + sb[c];
            unsafeAtomicAdd(&h[(size_t)dst*DH + c], o);
        }
    }
    if (lane == 0) atomicAdd(&dg[dst], 1);
}

// ---------------------------------------------------------------------------
// Kernel 3: att[b] = (h1[b] @ h2[b]^T) * T_SCALE   (512x512, K=200)
// 32x32 tile per block(16x16), 2x2 per thread
// ---------------------------------------------------------------------------
__global__ __launch_bounds__(256) void att_kernel(
    const float* __restrict__ h1, const float* __restrict__ h2,
    float* __restrict__ att)
{
    const int b = blockIdx.z;
    const int row0 = blockIdx.y * 32, col0 = blockIdx.x * 32;
    const float* A  = h1 + (size_t)b*NN*DH;
    const float* Bm = h2 + (size_t)b*NN*DH;

    __shared__ float As[32][9], Bs[32][9];
    const int tx = threadIdx.x, ty = threadIdx.y;
    const int tid = ty*16 + tx;
    const int lr = tid >> 3, lk = tid & 7;

    float acc00 = 0.f, acc01 = 0.f, acc10 = 0.f, acc11 = 0.f;
    for (int k0 = 0; k0 < DH; k0 += 8) {
        As[lr][lk] = A [(size_t)(row0+lr)*DH + k0 + lk];
        Bs[lr][lk] = Bm[(size_t)(col0+lr)*DH + k0 + lk];
        __syncthreads();
        #pragma unroll
        for (int kk = 0; kk < 8; kk++) {
            const float a0 = As[ty*2][kk],   a1 = As[ty*2+1][kk];
            const float b0 = Bs[tx*2][kk],   b1 = Bs[tx*2+1][kk];
            acc00 += a0*b0; acc01 += a0*b1; acc10 += a1*b0; acc11 += a1*b1;
        }
        __syncthreads();
    }
    const size_t base = (size_t)b*NN*NN;
    const int r0 = row0 + ty*2, c0 = col0 + tx*2;
    att[base + (size_t)r0*NN + c0    ] = acc00*T_SCALE;
    att[base + (size_t)r0*NN + c0 + 1] = acc01*T_SCALE;
    att[base + (size_t)(r0+1)*NN + c0    ] = acc10*T_SCALE;
    att[base + (size_t)(r0+1)*NN + c0 + 1] = acc11*T_SCALE;
}

// ---------------------------------------------------------------------------
// Kernel 4: softmax (rows of att, or rows of att^T) then @ V  -> out [B,N,DH]
// block 256 handles 16 output rows; wave w owns rows 4w..4w+3,
// lane l owns cols {l, l+64, l+128, l+192}
// ---------------------------------------------------------------------------
__global__ __launch_bounds__(256) void ckern(
    const float* __restrict__ att, const float* __restrict__ V,
    float* __restrict__ out, const int trans)
{
    const int b = blockIdx.y;
    const int row0 = blockIdx.x * 16;
    const float* attb = att + (size_t)b*NN*NN;
    const float* Vb   = V   + (size_t)b*NN*DH;

    __shared__ float p[16][513];
    __shared__ float hv[8][200];
    const int tid = threadIdx.x;

    if (!trans) {
        #pragma unroll 4
        for (int i = 0; i < 32; i++) {
            const int flat = tid + 256*i;
            const int r = flat >> 9, k = flat & 511;
            p[r][k] = attb[(size_t)(row0+r)*NN + k];
        }
    } else {
        #pragma unroll 4
        for (int i = 0; i < 32; i++) {
            const int flat = tid + 256*i;
            const int k = flat >> 4, r = flat & 15;
            p[r][k] = attb[(size_t)k*NN + row0 + r];
        }
    }
    __syncthreads();

    const int wave = tid >> 6, lane = tid & 63;
    for (int r = wave*4; r < wave*4 + 4; r++) {
        float v[8];
        float m = -1e30f;
        #pragma unroll
        for (int i = 0; i < 8; i++) { v[i] = p[r][lane + 64*i]; m = fmaxf(m, v[i]); }
        #pragma unroll
        for (int off = 1; off < 64; off <<= 1) m = fmaxf(m, __shfl_xor(m, off, 64));
        float s = 0.f;
        #pragma unroll
        for (int i = 0; i < 8; i++) { v[i] = expf(v[i]-m); s += v[i]; }
        #pragma unroll
        for (int off = 1; off < 64; off <<= 1) s += __shfl_xor(s, off, 64);
        const float inv = 1.0f / s;
        #pragma unroll
        for (int i = 0; i < 8; i++) p[r][lane + 64*i] = v[i]*inv;
    }

    float acc[4][4];
    #pragma unroll
    for (int r = 0; r < 4; r++)
        #pragma unroll
        for (int j = 0; j < 4; j++) acc[r][j] = 0.0f;

    for (int m0 = 0; m0 < NN; m0 += 8) {
        __syncthreads();
        for (int i = tid; i < 8*DH; i += 256) {
            const int mm = i / DH, c = i % DH;
            hv[mm][c] = Vb[(size_t)(m0+mm)*DH + c];
        }
        __syncthreads();
        #pragma unroll
        for (int mm = 0; mm < 8; mm++) {
            const float pv0 = p[wave*4+0][m0+mm];
            const float pv1 = p[wave*4+1][m0+mm];
            const float pv2 = p[wave*4+2][m0+mm];
            const float pv3 = p[wave*4+3][m0+mm];
            #pragma unroll
            for (int j = 0; j < 4; j++) {
                const int c = lane + 64*j;
                if (c < DH) {
                    const float hvv = hv[mm][c];
                    acc[0][j] += pv0*hvv;
                    acc[1][j] += pv1*hvv;
                    acc[2][j] += pv2*hvv;
                    acc[3][j] += pv3*hvv;
                }
            }
        }
    }
    #pragma unroll
    for (int r = 0; r < 4; r++)
        #pragma unroll
        for (int j = 0; j < 4; j++) {
            const int c = lane + 64*j;
            if (c < DH)
                out[((size_t)b*NN + row0 + wave*4 + r)*DH + c] = acc[r][j];
        }
}

// ---------------------------------------------------------------------------
// Kernel 5: relu(concat(h,c)@W_down) + degree_table[deg]  -> mean over nodes
// block 256 handles 16 nodes (all in the same batch: 512 % 16 == 0)
// ---------------------------------------------------------------------------
__global__ __launch_bounds__(256) void down_kernel(
    const float* __restrict__ h1, const float* __restrict__ h2,
    const float* __restrict__ c1, const float* __restrict__ c2,
    const int* __restrict__ deg1, const int* __restrict__ deg2,
    const float* __restrict__ W_down, const float* __restrict__ degree_table,
    float* __restrict__ hsg1, float* __restrict__ hsg2)
{
    const int side = blockIdx.y;
    const float* h  = side ? h2 : h1;
    const float* cc = side ? c2 : c1;
    const int*   dg = side ? deg2 : deg1;
    float* hsg = side ? hsg2 : hsg1;

    const int node0 = blockIdx.x * 16;
    const int b = node0 >> 9;

    __shared__ float x[16][400];
    __shared__ float ws[8][200];
    __shared__ float part[4][200];
    const int tid = threadIdx.x;

    for (int i = tid; i < 16*400; i += 256) {
        const int r = i / 400, c = i % 400;
        x[r][c] = (c < DH) ? h[(size_t)(node0+r)*DH + c]
                           : cc[(size_t)(node0+r)*DH + (c-DH)];
    }
    __syncthreads();

    const int wave = tid >> 6, lane = tid & 63;
    float acc[4][4];
    #pragma unroll
    for (int r = 0; r < 4; r++)
        #pragma unroll
        for (int j = 0; j < 4; j++) acc[r][j] = 0.0f;

    for (int k0 = 0; k0 < 400; k0 += 8) {
        __syncthreads();
        for (int i = tid; i < 8*DH; i += 256) {
            const int kk = i / DH, c = i % DH;
            ws[kk][c] = W_down[(size_t)(k0+kk)*DH + c];
        }
        __syncthreads();
        #pragma unroll
        for (int kk = 0; kk < 8; kk++) {
            const float a0 = x[wave*4+0][k0+kk];
            const float a1 = x[wave*4+1][k0+kk];
            const float a2 = x[wave*4+2][k0+kk];
            const float a3 = x[wave*4+3][k0+kk];
            #pragma unroll
            for (int j = 0; j < 4; j++) {
                const int c = lane + 64*j;
                if (c < DH) {
                    const float w = ws[kk][c];
                    acc[0][j] += a0*w; acc[1][j] += a1*w;
                    acc[2][j] += a2*w; acc[3][j] += a3*w;
                }
            }
        }
    }

    #pragma unroll
    for (int j = 0; j < 4; j++) {
        const int c = lane + 64*j;
        if (c < DH) {
            float colsum = 0.0f;
            #pragma unroll
            for (int r = 0; r < 4; r++) {
                int d = dg[node0 + wave*4 + r];
                d = d > 199 ? 199 : d;
                colsum += fmaxf(acc[r][j], 0.0f) + degree_table[d*DH + c];
            }
            part[wave][c] = colsum;
        }
    }
    __syncthreads();
    if (tid < DH) {
        const float tot = part[0][tid]+part[1][tid]+part[2][tid]+part[3][tid];
        unsafeAtomicAdd(&hsg[b*206 + tid], tot * (1.0f/512.0f));
    }
}

// ---------------------------------------------------------------------------
// Kernel 6: interaction mean over nodes -> hsg cols 200..205
// ---------------------------------------------------------------------------
__global__ __launch_bounds__(192) void inter_kernel(
    const float* __restrict__ i1, const float* __restrict__ i2,
    float* __restrict__ hsg1, float* __restrict__ hsg2)
{
    const int side = blockIdx.y;
    const float* it = side ? i2 : i1;
    float* hsg = side ? hsg2 : hsg1;
    const int b = blockIdx.x;
    __shared__ float red[192];
    const int tid = threadIdx.x;
    const int j = tid % 6, seg = tid / 6;   // seg < 32
    float s = 0.0f;
    for (int n = seg*16; n < seg*16 + 16; n++)
        s += it[(size_t)b*NN*DI + n*DI + j];
    red[tid] = s;
    __syncthreads();
    if (tid < 6) {
        float tot = 0.0f;
        for (int sg2 = 0; sg2 < 32; sg2++) tot += red[sg2*6 + tid];
        hsg[b*206 + 200 + tid] = tot * (1.0f/512.0f);
    }
}

// ---------------------------------------------------------------------------
// Kernel 7: final MLP, one block per batch row
// ---------------------------------------------------------------------------
__global__ __launch_bounds__(256) void mlp_kernel(
    const float* __restrict__ hsg1, const float* __restrict__ hsg2,
    const float* __restrict__ W_f1, const float* __restrict__ b_f1,
    const float* __restrict__ W_f2, const float* __restrict__ b_f2,
    const float* __restrict__ W_f3, const float* __restrict__ b_f3,
    const float* __restrict__ W_f4, const float* __restrict__ b_f4,
    float* __restrict__ out)
{
    const int b = blockIdx.x;
    __shared__ float x[618];
    __shared__ float y1[400];
    __shared__ float y2[200];
    __shared__ float y3[100];
    __shared__ float red[256];
    const int tid = threadIdx.x;

    if (tid < 206) {
        const float a = hsg1[b*206 + tid], bb = hsg2[b*206 + tid];
        x[tid] = a; x[206 + tid] = bb; x[412 + tid] = a - bb;
    }
    __syncthreads();
    for (int c = tid; c < 400; c += 256) {
        float acc = b_f1[c];
        for (int k = 0; k < 618; k++) acc += x[k]*W_f1[(size_t)k*400 + c];
        y1[c] = fmaxf(acc, 0.0f);
    }
    __syncthreads();
    if (tid < 200) {
        float acc = b_f2[tid];
        for (int k = 0; k < 400; k++) acc += y1[k]*W_f2[k*200 + tid];
        y2[tid] = fmaxf(acc, 0.0f);
    }
    __syncthreads();
    if (tid < 100) {
        float acc = b_f3[tid];
        for (int k = 0; k < 200; k++) acc += y2[k]*W_f3[k*100 + tid];
        y3[tid] = fmaxf(acc, 0.0f);
    }
    __syncthreads();
    red[tid] = (tid < 100) ? y3[tid]*W_f4[tid] : 0.0f;
    __syncthreads();
    for (int s = 128; s > 0; s >>= 1) {
        if (tid < s) red[tid] += red[tid + s];
        __syncthreads();
    }
    if (tid == 0) out[b] = red[0] + b_f4[0];
}

// ---------------------------------------------------------------------------
extern "C" void kernel_launch(void* const* d_in, const int* in_sizes, int n_in,
                              void* d_out, int out_size, void* d_ws, size_t ws_size,
                              hipStream_t stream)
{
    const float* atom1  = (const float*)d_in[0];
    const float* atom2  = (const float*)d_in[1];
    const float* coords1= (const float*)d_in[2];
    const float* coords2= (const float*)d_in[3];
    const float* efeat1 = (const float*)d_in[4];
    const float* efeat2 = (const float*)d_in[5];
    const float* inter1 = (const float*)d_in[6];
    const float* inter2 = (const float*)d_in[7];
    const int*   esrc1  = (const int*)d_in[8];
    const int*   edst1  = (const int*)d_in[9];
    const int*   esrc2  = (const int*)d_in[10];
    const int*   edst2  = (const int*)d_in[11];
    const float* W_atom = (const float*)d_in[12];
    const float* W_edge = (const float*)d_in[13];
    const float* W_rbf  = (const float*)d_in[14];
    const float* b_rbf  = (const float*)d_in[15];
    const float* ln_g   = (const float*)d_in[16];
    const float* ln_b   = (const float*)d_in[17];
    const float* W_down = (const float*)d_in[18];
    const float* deg_tab= (const float*)d_in[19];
    const float* W_f1   = (const float*)d_in[20];
    const float* b_f1   = (const float*)d_in[21];
    const float* W_f2   = (const float*)d_in[22];
    const float* b_f2   = (const float*)d_in[23];
    const float* W_f3   = (const float*)d_in[24];
    const float* b_f3   = (const float*)d_in[25];
    const float* W_f4   = (const float*)d_in[26];
    const float* b_f4   = (const float*)d_in[27];
    float* out = (float*)d_out;

    // workspace layout (floats)
    float* ws = (float*)d_ws;
    const size_t HSZ = (size_t)BN*DH;          // 6,553,600
    float* h1  = ws;
    float* h2  = h1 + HSZ;
    float* att = h2 + HSZ;                      // B*N*N = 16,777,216
    float* c1  = att + (size_t)BB*NN*NN;
    float* c2  = c1 + HSZ;
    float* hsg1 = c2 + HSZ;                     // 64*206
    float* hsg2 = hsg1 + (size_t)BB*206;
    int* deg1 = (int*)(hsg2 + (size_t)BB*206);
    int* deg2 = deg1 + BN;

    hipMemsetAsync(deg1, 0, 2*(size_t)BN*sizeof(int), stream);
    hipMemsetAsync(hsg1, 0, 2*(size_t)BB*206*sizeof(float), stream);

    node_kernel<<<dim3(BN, 2), 256, 0, stream>>>(
        atom1, atom2, W_atom, ln_g, ln_b, h1, h2);

    edge_kernel<<<dim3(EE/4, 2), 256, 0, stream>>>(
        efeat1, efeat2, esrc1, edst1, esrc2, edst2, coords1, coords2,
        W_edge, W_rbf, b_rbf, ln_g, ln_b, h1, h2, deg1, deg2);

    att_kernel<<<dim3(16, 16, BB), dim3(16, 16), 0, stream>>>(h1, h2, att);

    ckern<<<dim3(NN/16, BB), 256, 0, stream>>>(att, h2, c1, 0);
    ckern<<<dim3(NN/16, BB), 256, 0, stream>>>(att, h1, c2, 1);

    down_kernel<<<dim3(BN/16, 2), 256, 0, stream>>>(
        h1, h2, c1, c2, deg1, deg2, W_down, deg_tab, hsg1, hsg2);

    inter_kernel<<<dim3(BB, 2), 192, 0, stream>>>(inter1, inter2, hsg1, hsg2);

    mlp_kernel<<<BB, 256, 0, stream>>>(
        hsg1, hsg2, W_f1, b_f1, W_f2, b_f2, W_f3, b_f3, W_f4, b_f4, out);
}

// Round 2
// 2849.734 us; speedup vs baseline: 1.1362x; 1.1362x over previous
//
#include <hip/hip_runtime.h>
#include <cstddef>
#include <cstdint>

// Problem constants
#define BB   64
#define NN   512
#define BN   (BB*NN)          // 32768
#define EE   524288
#define DA   70
#define DE   14
#define DH   200
#define DI   6
#define T_SCALE 0.07071067811865475f   // sqrt(1/200)

// ---------------------------------------------------------------------------
// Kernel 1: per-node  h = layernorm(relu(atom @ W_atom))
// ---------------------------------------------------------------------------
__global__ __launch_bounds__(256) void node_kernel(
    const float* __restrict__ atom1, const float* __restrict__ atom2,
    const float* __restrict__ W_atom,
    const float* __restrict__ ln_g, const float* __restrict__ ln_b,
    float* __restrict__ h1, float* __restrict__ h2)
{
    const int side = blockIdx.y;
    const float* atom = side ? atom2 : atom1;
    float* h = side ? h2 : h1;
    const int node = blockIdx.x;
    const int tid = threadIdx.x;

    __shared__ float arow[DA];
    __shared__ float vals[DH];
    __shared__ float rs[256], rs2[256];

    if (tid < DA) arow[tid] = atom[(size_t)node*DA + tid];
    __syncthreads();

    float v = 0.0f;
    if (tid < DH) {
        float acc = 0.0f;
        #pragma unroll 10
        for (int k = 0; k < DA; k++) acc += arow[k] * W_atom[k*DH + tid];
        v = fmaxf(acc, 0.0f);
        vals[tid] = v;
    }
    rs[tid] = v; rs2[tid] = v*v;
    __syncthreads();
    for (int s = 128; s > 0; s >>= 1) {
        if (tid < s) { rs[tid] += rs[tid+s]; rs2[tid] += rs2[tid+s]; }
        __syncthreads();
    }
    const float mean = rs[0] * (1.0f/DH);
    const float var  = rs2[0] * (1.0f/DH) - mean*mean;
    const float rstd = rsqrtf(var + 1e-5f);
    if (tid < DH)
        h[(size_t)node*DH + tid] = ln_g[tid]*(vals[tid]-mean)*rstd + ln_b[tid];
}

// ---------------------------------------------------------------------------
// Counting sort by dst: hist -> scan -> scatter
// ---------------------------------------------------------------------------
__global__ __launch_bounds__(256) void hist_kernel(
    const int* __restrict__ edst1, const int* __restrict__ edst2,
    int* __restrict__ deg1, int* __restrict__ deg2)
{
    const int e = blockIdx.x*256 + threadIdx.x;
    atomicAdd(&deg1[edst1[e]], 1);
    atomicAdd(&deg2[edst2[e]], 1);
}

__global__ __launch_bounds__(1024) void scan_kernel(
    const int* __restrict__ deg1, const int* __restrict__ deg2,
    int* __restrict__ start1, int* __restrict__ start2,
    int* __restrict__ cursor1, int* __restrict__ cursor2)
{
    const int side = blockIdx.x;
    const int* deg   = side ? deg2 : deg1;
    int* start  = side ? start2 : start1;
    int* cursor = side ? cursor2 : cursor1;

    __shared__ int part[1024];
    const int t = threadIdx.x;
    const int base = t * 32;
    int local[32];
    int sum = 0;
    #pragma unroll
    for (int i = 0; i < 32; i++) { local[i] = deg[base+i]; sum += local[i]; }
    part[t] = sum;
    __syncthreads();
    // Hillis-Steele inclusive scan
    for (int off = 1; off < 1024; off <<= 1) {
        int v = (t >= off) ? part[t-off] : 0;
        __syncthreads();
        part[t] += v;
        __syncthreads();
    }
    int run = part[t] - sum;   // exclusive
    #pragma unroll
    for (int i = 0; i < 32; i++) {
        start[base+i] = run;
        cursor[base+i] = run;
        run += local[i];
    }
}

__global__ __launch_bounds__(256) void scatter_kernel(
    const int* __restrict__ edst1, const int* __restrict__ edst2,
    int* __restrict__ cursor1, int* __restrict__ cursor2,
    int* __restrict__ sorted1, int* __restrict__ sorted2)
{
    const int e = blockIdx.x*256 + threadIdx.x;
    {
        const int d = edst1[e];
        const int p = atomicAdd(&cursor1[d], 1);
        sorted1[p] = e;
    }
    {
        const int d = edst2[e];
        const int p = atomicAdd(&cursor2[d], 1);
        sorted2[p] = e;
    }
}

// ---------------------------------------------------------------------------
// Kernel 2': per-node gather of edge messages.
// One wave per node; weight columns cached in per-lane registers and reused
// across the node's ~16 edges; per-edge layernorm via 64-lane shuffles;
// one non-atomic accumulated store of the 200-float row.
// Column map per lane l: c in {l, 64+l, 128+l, 192+l(l<8)}
// ---------------------------------------------------------------------------
__global__ __launch_bounds__(256) void gather_edge_kernel(
    const float* __restrict__ efeat1, const float* __restrict__ efeat2,
    const int* __restrict__ esrc1, const int* __restrict__ esrc2,
    const float* __restrict__ coords1, const float* __restrict__ coords2,
    const int* __restrict__ sorted1, const int* __restrict__ sorted2,
    const int* __restrict__ start1, const int* __restrict__ start2,
    const int* __restrict__ deg1, const int* __restrict__ deg2,
    const float* __restrict__ W_edge, const float* __restrict__ W_rbf,
    const float* __restrict__ b_rbf,
    const float* __restrict__ ln_g, const float* __restrict__ ln_b,
    float* __restrict__ h1, float* __restrict__ h2)
{
    const int side = blockIdx.y;
    const float* ef     = side ? efeat2  : efeat1;
    const int*   esrc   = side ? esrc2   : esrc1;
    const float* coords = side ? coords2 : coords1;
    const int*   sorted = side ? sorted2 : sorted1;
    const int*   start  = side ? start2  : start1;
    const int*   deg    = side ? deg2    : deg1;
    float* h = side ? h2 : h1;

    const int lane = threadIdx.x & 63;
    const int node = blockIdx.x*4 + (threadIdx.x >> 6);

    // ---- per-lane register weights (reused across all edges of the node)
    float wA[14], wB[16], wC[16], wD[16];
    #pragma unroll
    for (int k = 0; k < 14; k++) wA[k] = W_edge[k*100 + lane];          // c=lane
    #pragma unroll
    for (int k = 0; k < 16; k++) wB[k] = W_rbf[k*100 + 28 + lane];      // c=128+lane
    if (lane < 36) {
        #pragma unroll
        for (int k = 0; k < 14; k++) wC[k] = W_edge[k*100 + 64 + lane]; // c=64+lane (<100)
        #pragma unroll
        for (int k = 14; k < 16; k++) wC[k] = 0.0f;
    } else {
        #pragma unroll
        for (int k = 0; k < 16; k++) wC[k] = W_rbf[k*100 + (lane-36)];  // c=64+lane (>=100)
    }
    if (lane < 8) {
        #pragma unroll
        for (int k = 0; k < 16; k++) wD[k] = W_rbf[k*100 + 92 + lane];  // c=192+lane
    } else {
        #pragma unroll
        for (int k = 0; k < 16; k++) wD[k] = 0.0f;
    }
    const float g0 = ln_g[lane],       bb0 = ln_b[lane];
    const float g1 = ln_g[64+lane],    bb1 = ln_b[64+lane];
    const float g2 = ln_g[128+lane],   bb2 = ln_b[128+lane];
    const float g3 = (lane<8) ? ln_g[192+lane] : 0.0f;
    const float bb3= (lane<8) ? ln_b[192+lane] : 0.0f;
    const float br2 = b_rbf[28+lane];
    const float br1 = (lane >= 36) ? b_rbf[lane-36] : 0.0f;
    const float br3 = (lane < 8)  ? b_rbf[92+lane] : 0.0f;

    const int st = start[node], dg = deg[node];
    const size_t base = (size_t)node * DH;

    // prefetch node h (written by node_kernel)
    float h0 = h[base + lane];
    float h1v = h[base + 64 + lane];
    float h2v = h[base + 128 + lane];
    float h3v = (lane < 8) ? h[base + 192 + lane] : 0.0f;

    const float cdx = coords[node*3+0];
    const float cdy = coords[node*3+1];
    const float cdz = coords[node*3+2];

    float acc0 = 0.f, acc1 = 0.f, acc2 = 0.f, acc3 = 0.f;

    for (int i = 0; i < dg; i++) {
        const int eid = sorted[st + i];
        const int src = esrc[eid];
        const float dx = coords[src*3+0] - cdx;
        const float dy = coords[src*3+1] - cdy;
        const float dz = coords[src*3+2] - cdz;
        const float dist = sqrtf(dx*dx + dy*dy + dz*dz + 1e-12f);

        float efr[14];
        #pragma unroll
        for (int k = 0; k < 14; k++) efr[k] = ef[(size_t)eid*DE + k];

        float rbf[16];
        #pragma unroll
        for (int k = 0; k < 16; k++) {
            const float t = (dist - (float)k*(5.0f/15.0f)) * (1.0f/0.3125f);
            rbf[k] = __expf(-t*t);
        }

        // v0: c = lane (e-branch)
        float v0 = 0.f;
        #pragma unroll
        for (int k = 0; k < 14; k++) v0 += efr[k]*wA[k];
        v0 = fmaxf(v0, 0.f);
        // v2: c = 128+lane (rbf-branch)
        float v2 = br2;
        #pragma unroll
        for (int k = 0; k < 16; k++) v2 += rbf[k]*wB[k];
        v2 = fmaxf(v2, 0.f);
        // v1: c = 64+lane
        float v1;
        if (lane < 36) {
            v1 = 0.f;
            #pragma unroll
            for (int k = 0; k < 14; k++) v1 += efr[k]*wC[k];
        } else {
            v1 = br1;
            #pragma unroll
            for (int k = 0; k < 16; k++) v1 += rbf[k]*wC[k];
        }
        v1 = fmaxf(v1, 0.f);
        // v3: c = 192+lane, lanes < 8 only
        float v3 = 0.f;
        if (lane < 8) {
            v3 = br3;
            #pragma unroll
            for (int k = 0; k < 16; k++) v3 += rbf[k]*wD[k];
            v3 = fmaxf(v3, 0.f);
        }

        float s  = v0 + v1 + v2 + v3;
        float s2 = v0*v0 + v1*v1 + v2*v2 + v3*v3;
        #pragma unroll
        for (int off = 1; off < 64; off <<= 1) {
            s  += __shfl_xor(s,  off, 64);
            s2 += __shfl_xor(s2, off, 64);
        }
        const float mean = s * (1.0f/DH);
        const float var  = s2 * (1.0f/DH) - mean*mean;
        const float rstd = rsqrtf(var + 1e-5f);

        acc0 += g0*(v0-mean)*rstd + bb0;
        acc1 += g1*(v1-mean)*rstd + bb1;
        acc2 += g2*(v2-mean)*rstd + bb2;
        if (lane < 8) acc3 += g3*(v3-mean)*rstd + bb3;
    }

    h[base + lane]        = h0  + acc0;
    h[base + 64 + lane]   = h1v + acc1;
    h[base + 128 + lane]  = h2v + acc2;
    if (lane < 8) h[base + 192 + lane] = h3v + acc3;
}

// ---------------------------------------------------------------------------
// Kernel 3: att[b] = (h1[b] @ h2[b]^T) * T_SCALE   (512x512, K=200)
// ---------------------------------------------------------------------------
__global__ __launch_bounds__(256) void att_kernel(
    const float* __restrict__ h1, const float* __restrict__ h2,
    float* __restrict__ att)
{
    const int b = blockIdx.z;
    const int row0 = blockIdx.y * 32, col0 = blockIdx.x * 32;
    const float* A  = h1 + (size_t)b*NN*DH;
    const float* Bm = h2 + (size_t)b*NN*DH;

    __shared__ float As[32][9], Bs[32][9];
    const int tx = threadIdx.x, ty = threadIdx.y;
    const int tid = ty*16 + tx;
    const int lr = tid >> 3, lk = tid & 7;

    float acc00 = 0.f, acc01 = 0.f, acc10 = 0.f, acc11 = 0.f;
    for (int k0 = 0; k0 < DH; k0 += 8) {
        As[lr][lk] = A [(size_t)(row0+lr)*DH + k0 + lk];
        Bs[lr][lk] = Bm[(size_t)(col0+lr)*DH + k0 + lk];
        __syncthreads();
        #pragma unroll
        for (int kk = 0; kk < 8; kk++) {
            const float a0 = As[ty*2][kk],   a1 = As[ty*2+1][kk];
            const float b0 = Bs[tx*2][kk],   b1 = Bs[tx*2+1][kk];
            acc00 += a0*b0; acc01 += a0*b1; acc10 += a1*b0; acc11 += a1*b1;
        }
        __syncthreads();
    }
    const size_t base = (size_t)b*NN*NN;
    const int r0 = row0 + ty*2, c0 = col0 + tx*2;
    att[base + (size_t)r0*NN + c0    ] = acc00*T_SCALE;
    att[base + (size_t)r0*NN + c0 + 1] = acc01*T_SCALE;
    att[base + (size_t)(r0+1)*NN + c0    ] = acc10*T_SCALE;
    att[base + (size_t)(r0+1)*NN + c0 + 1] = acc11*T_SCALE;
}

// ---------------------------------------------------------------------------
// Kernel 4: softmax (rows of att, or rows of att^T) then @ V  -> out [B,N,DH]
// ---------------------------------------------------------------------------
__global__ __launch_bounds__(256) void ckern(
    const float* __restrict__ att, const float* __restrict__ V,
    float* __restrict__ out, const int trans)
{
    const int b = blockIdx.y;
    const int row0 = blockIdx.x * 16;
    const float* attb = att + (size_t)b*NN*NN;
    const float* Vb   = V   + (size_t)b*NN*DH;

    __shared__ float p[16][513];
    __shared__ float hv[8][200];
    const int tid = threadIdx.x;

    if (!trans) {
        #pragma unroll 4
        for (int i = 0; i < 32; i++) {
            const int flat = tid + 256*i;
            const int r = flat >> 9, k = flat & 511;
            p[r][k] = attb[(size_t)(row0+r)*NN + k];
        }
    } else {
        #pragma unroll 4
        for (int i = 0; i < 32; i++) {
            const int flat = tid + 256*i;
            const int k = flat >> 4, r = flat & 15;
            p[r][k] = attb[(size_t)k*NN + row0 + r];
        }
    }
    __syncthreads();

    const int wave = tid >> 6, lane = tid & 63;
    for (int r = wave*4; r < wave*4 + 4; r++) {
        float v[8];
        float m = -1e30f;
        #pragma unroll
        for (int i = 0; i < 8; i++) { v[i] = p[r][lane + 64*i]; m = fmaxf(m, v[i]); }
        #pragma unroll
        for (int off = 1; off < 64; off <<= 1) m = fmaxf(m, __shfl_xor(m, off, 64));
        float s = 0.f;
        #pragma unroll
        for (int i = 0; i < 8; i++) { v[i] = expf(v[i]-m); s += v[i]; }
        #pragma unroll
        for (int off = 1; off < 64; off <<= 1) s += __shfl_xor(s, off, 64);
        const float inv = 1.0f / s;
        #pragma unroll
        for (int i = 0; i < 8; i++) p[r][lane + 64*i] = v[i]*inv;
    }

    float acc[4][4];
    #pragma unroll
    for (int r = 0; r < 4; r++)
        #pragma unroll
        for (int j = 0; j < 4; j++) acc[r][j] = 0.0f;

    for (int m0 = 0; m0 < NN; m0 += 8) {
        __syncthreads();
        for (int i = tid; i < 8*DH; i += 256) {
            const int mm = i / DH, c = i % DH;
            hv[mm][c] = Vb[(size_t)(m0+mm)*DH + c];
        }
        __syncthreads();
        #pragma unroll
        for (int mm = 0; mm < 8; mm++) {
            const float pv0 = p[wave*4+0][m0+mm];
            const float pv1 = p[wave*4+1][m0+mm];
            const float pv2 = p[wave*4+2][m0+mm];
            const float pv3 = p[wave*4+3][m0+mm];
            #pragma unroll
            for (int j = 0; j < 4; j++) {
                const int c = lane + 64*j;
                if (c < DH) {
                    const float hvv = hv[mm][c];
                    acc[0][j] += pv0*hvv;
                    acc[1][j] += pv1*hvv;
                    acc[2][j] += pv2*hvv;
                    acc[3][j] += pv3*hvv;
                }
            }
        }
    }
    #pragma unroll
    for (int r = 0; r < 4; r++)
        #pragma unroll
        for (int j = 0; j < 4; j++) {
            const int c = lane + 64*j;
            if (c < DH)
                out[((size_t)b*NN + row0 + wave*4 + r)*DH + c] = acc[r][j];
        }
}

// ---------------------------------------------------------------------------
// Kernel 5: relu(concat(h,c)@W_down) + degree_table[deg]  -> mean over nodes
// ---------------------------------------------------------------------------
__global__ __launch_bounds__(256) void down_kernel(
    const float* __restrict__ h1, const float* __restrict__ h2,
    const float* __restrict__ c1, const float* __restrict__ c2,
    const int* __restrict__ deg1, const int* __restrict__ deg2,
    const float* __restrict__ W_down, const float* __restrict__ degree_table,
    float* __restrict__ hsg1, float* __restrict__ hsg2)
{
    const int side = blockIdx.y;
    const float* h  = side ? h2 : h1;
    const float* cc = side ? c2 : c1;
    const int*   dg = side ? deg2 : deg1;
    float* hsg = side ? hsg2 : hsg1;

    const int node0 = blockIdx.x * 16;
    const int b = node0 >> 9;

    __shared__ float x[16][400];
    __shared__ float ws[8][200];
    __shared__ float part[4][200];
    const int tid = threadIdx.x;

    for (int i = tid; i < 16*400; i += 256) {
        const int r = i / 400, c = i % 400;
        x[r][c] = (c < DH) ? h[(size_t)(node0+r)*DH + c]
                           : cc[(size_t)(node0+r)*DH + (c-DH)];
    }
    __syncthreads();

    const int wave = tid >> 6, lane = tid & 63;
    float acc[4][4];
    #pragma unroll
    for (int r = 0; r < 4; r++)
        #pragma unroll
        for (int j = 0; j < 4; j++) acc[r][j] = 0.0f;

    for (int k0 = 0; k0 < 400; k0 += 8) {
        __syncthreads();
        for (int i = tid; i < 8*DH; i += 256) {
            const int kk = i / DH, c = i % DH;
            ws[kk][c] = W_down[(size_t)(k0+kk)*DH + c];
        }
        __syncthreads();
        #pragma unroll
        for (int kk = 0; kk < 8; kk++) {
            const float a0 = x[wave*4+0][k0+kk];
            const float a1 = x[wave*4+1][k0+kk];
            const float a2 = x[wave*4+2][k0+kk];
            const float a3 = x[wave*4+3][k0+kk];
            #pragma unroll
            for (int j = 0; j < 4; j++) {
                const int c = lane + 64*j;
                if (c < DH) {
                    const float w = ws[kk][c];
                    acc[0][j] += a0*w; acc[1][j] += a1*w;
                    acc[2][j] += a2*w; acc[3][j] += a3*w;
                }
            }
        }
    }

    #pragma unroll
    for (int j = 0; j < 4; j++) {
        const int c = lane + 64*j;
        if (c < DH) {
            float colsum = 0.0f;
            #pragma unroll
            for (int r = 0; r < 4; r++) {
                int d = dg[node0 + wave*4 + r];
                d = d > 199 ? 199 : d;
                colsum += fmaxf(acc[r][j], 0.0f) + degree_table[d*DH + c];
            }
            part[wave][c] = colsum;
        }
    }
    __syncthreads();
    if (tid < DH) {
        const float tot = part[0][tid]+part[1][tid]+part[2][tid]+part[3][tid];
        unsafeAtomicAdd(&hsg[b*206 + tid], tot * (1.0f/512.0f));
    }
}

// ---------------------------------------------------------------------------
// Kernel 6: interaction mean over nodes -> hsg cols 200..205
// ---------------------------------------------------------------------------
__global__ __launch_bounds__(192) void inter_kernel(
    const float* __restrict__ i1, const float* __restrict__ i2,
    float* __restrict__ hsg1, float* __restrict__ hsg2)
{
    const int side = blockIdx.y;
    const float* it = side ? i2 : i1;
    float* hsg = side ? hsg2 : hsg1;
    const int b = blockIdx.x;
    __shared__ float red[192];
    const int tid = threadIdx.x;
    const int j = tid % 6, seg = tid / 6;   // seg < 32
    float s = 0.0f;
    for (int n = seg*16; n < seg*16 + 16; n++)
        s += it[(size_t)b*NN*DI + n*DI + j];
    red[tid] = s;
    __syncthreads();
    if (tid < 6) {
        float tot = 0.0f;
        for (int sg2 = 0; sg2 < 32; sg2++) tot += red[sg2*6 + tid];
        hsg[b*206 + 200 + tid] = tot * (1.0f/512.0f);
    }
}

// ---------------------------------------------------------------------------
// Kernel 7: final MLP, one block per batch row
// ---------------------------------------------------------------------------
__global__ __launch_bounds__(256) void mlp_kernel(
    const float* __restrict__ hsg1, const float* __restrict__ hsg2,
    const float* __restrict__ W_f1, const float* __restrict__ b_f1,
    const float* __restrict__ W_f2, const float* __restrict__ b_f2,
    const float* __restrict__ W_f3, const float* __restrict__ b_f3,
    const float* __restrict__ W_f4, const float* __restrict__ b_f4,
    float* __restrict__ out)
{
    const int b = blockIdx.x;
    __shared__ float x[618];
    __shared__ float y1[400];
    __shared__ float y2[200];
    __shared__ float y3[100];
    __shared__ float red[256];
    const int tid = threadIdx.x;

    if (tid < 206) {
        const float a = hsg1[b*206 + tid], bb = hsg2[b*206 + tid];
        x[tid] = a; x[206 + tid] = bb; x[412 + tid] = a - bb;
    }
    __syncthreads();
    for (int c = tid; c < 400; c += 256) {
        float acc = b_f1[c];
        for (int k = 0; k < 618; k++) acc += x[k]*W_f1[(size_t)k*400 + c];
        y1[c] = fmaxf(acc, 0.0f);
    }
    __syncthreads();
    if (tid < 200) {
        float acc = b_f2[tid];
        for (int k = 0; k < 400; k++) acc += y1[k]*W_f2[k*200 + tid];
        y2[tid] = fmaxf(acc, 0.0f);
    }
    __syncthreads();
    if (tid < 100) {
        float acc = b_f3[tid];
        for (int k = 0; k < 200; k++) acc += y2[k]*W_f3[k*100 + tid];
        y3[tid] = fmaxf(acc, 0.0f);
    }
    __syncthreads();
    red[tid] = (tid < 100) ? y3[tid]*W_f4[tid] : 0.0f;
    __syncthreads();
    for (int s = 128; s > 0; s >>= 1) {
        if (tid < s) red[tid] += red[tid + s];
        __syncthreads();
    }
    if (tid == 0) out[b] = red[0] + b_f4[0];
}

// ---------------------------------------------------------------------------
extern "C" void kernel_launch(void* const* d_in, const int* in_sizes, int n_in,
                              void* d_out, int out_size, void* d_ws, size_t ws_size,
                              hipStream_t stream)
{
    const float* atom1  = (const float*)d_in[0];
    const float* atom2  = (const float*)d_in[1];
    const float* coords1= (const float*)d_in[2];
    const float* coords2= (const float*)d_in[3];
    const float* efeat1 = (const float*)d_in[4];
    const float* efeat2 = (const float*)d_in[5];
    const float* inter1 = (const float*)d_in[6];
    const float* inter2 = (const float*)d_in[7];
    const int*   esrc1  = (const int*)d_in[8];
    const int*   edst1  = (const int*)d_in[9];
    const int*   esrc2  = (const int*)d_in[10];
    const int*   edst2  = (const int*)d_in[11];
    const float* W_atom = (const float*)d_in[12];
    const float* W_edge = (const float*)d_in[13];
    const float* W_rbf  = (const float*)d_in[14];
    const float* b_rbf  = (const float*)d_in[15];
    const float* ln_g   = (const float*)d_in[16];
    const float* ln_b   = (const float*)d_in[17];
    const float* W_down = (const float*)d_in[18];
    const float* deg_tab= (const float*)d_in[19];
    const float* W_f1   = (const float*)d_in[20];
    const float* b_f1   = (const float*)d_in[21];
    const float* W_f2   = (const float*)d_in[22];
    const float* b_f2   = (const float*)d_in[23];
    const float* W_f3   = (const float*)d_in[24];
    const float* b_f3   = (const float*)d_in[25];
    const float* W_f4   = (const float*)d_in[26];
    const float* b_f4   = (const float*)d_in[27];
    float* out = (float*)d_out;

    // workspace layout (floats)
    float* ws = (float*)d_ws;
    const size_t HSZ = (size_t)BN*DH;          // 6,553,600
    float* h1  = ws;
    float* h2  = h1 + HSZ;
    float* att = h2 + HSZ;                      // B*N*N = 16,777,216
    float* c1  = att + (size_t)BB*NN*NN;
    float* c2  = c1 + HSZ;
    float* hsg1 = c2 + HSZ;                     // 64*206
    float* hsg2 = hsg1 + (size_t)BB*206;
    int* deg1 = (int*)(hsg2 + (size_t)BB*206);
    int* deg2 = deg1 + BN;
    int* start1 = deg2 + BN;
    int* start2 = start1 + BN;
    int* cursor1 = start2 + BN;
    int* cursor2 = cursor1 + BN;
    int* sorted1 = cursor2 + BN;
    int* sorted2 = sorted1 + EE;

    hipMemsetAsync(deg1, 0, 2*(size_t)BN*sizeof(int), stream);
    hipMemsetAsync(hsg1, 0, 2*(size_t)BB*206*sizeof(float), stream);

    node_kernel<<<dim3(BN, 2), 256, 0, stream>>>(
        atom1, atom2, W_atom, ln_g, ln_b, h1, h2);

    hist_kernel<<<EE/256, 256, 0, stream>>>(edst1, edst2, deg1, deg2);
    scan_kernel<<<2, 1024, 0, stream>>>(deg1, deg2, start1, start2, cursor1, cursor2);
    scatter_kernel<<<EE/256, 256, 0, stream>>>(edst1, edst2, cursor1, cursor2, sorted1, sorted2);

    gather_edge_kernel<<<dim3(BN/4, 2), 256, 0, stream>>>(
        efeat1, efeat2, esrc1, esrc2, coords1, coords2,
        sorted1, sorted2, start1, start2, deg1, deg2,
        W_edge, W_rbf, b_rbf, ln_g, ln_b, h1, h2);

    att_kernel<<<dim3(16, 16, BB), dim3(16, 16), 0, stream>>>(h1, h2, att);

    ckern<<<dim3(NN/16, BB), 256, 0, stream>>>(att, h2, c1, 0);
    ckern<<<dim3(NN/16, BB), 256, 0, stream>>>(att, h1, c2, 1);

    down_kernel<<<dim3(BN/16, 2), 256, 0, stream>>>(
        h1, h2, c1, c2, deg1, deg2, W_down, deg_tab, hsg1, hsg2);

    inter_kernel<<<dim3(BB, 2), 192, 0, stream>>>(inter1, inter2, hsg1, hsg2);

    mlp_kernel<<<BB, 256, 0, stream>>>(
        hsg1, hsg2, W_f1, b_f1, W_f2, b_f2, W_f3, b_f3, W_f4, b_f4, out);
}

// Round 3
// 1958.676 us; speedup vs baseline: 1.6530x; 1.4549x over previous
//
#include <hip/hip_runtime.h>
#include <cstddef>
#include <cstdint>

// Problem constants
#define BB   64
#define NN   512
#define BN   (BB*NN)          // 32768
#define EE   524288
#define DA   70
#define DE   14
#define DH   200
#define DI   6
#define T_SCALE 0.07071067811865475f   // sqrt(1/200)

// ---------------------------------------------------------------------------
// Kernel 1: per-node  h = layernorm(relu(atom @ W_atom))
// 4 nodes per block; W_atom element reused 4x from a register.
// ---------------------------------------------------------------------------
__global__ __launch_bounds__(256) void node_kernel(
    const float* __restrict__ atom1, const float* __restrict__ atom2,
    const float* __restrict__ W_atom,
    const float* __restrict__ ln_g, const float* __restrict__ ln_b,
    float* __restrict__ h1, float* __restrict__ h2)
{
    const int side = blockIdx.y;
    const float* atom = side ? atom2 : atom1;
    float* h = side ? h2 : h1;
    const int node0 = blockIdx.x * 4;
    const int tid = threadIdx.x;

    __shared__ float arow[4][DA];
    __shared__ float vals[4][DH];

    for (int i = tid; i < 4*DA; i += 256) {
        const int n = i / DA, k = i % DA;
        arow[n][k] = atom[(size_t)(node0+n)*DA + k];
    }
    __syncthreads();

    if (tid < DH) {
        float a0 = 0.f, a1 = 0.f, a2 = 0.f, a3 = 0.f;
        #pragma unroll 7
        for (int k = 0; k < DA; k++) {
            const float w = W_atom[k*DH + tid];
            a0 += arow[0][k]*w; a1 += arow[1][k]*w;
            a2 += arow[2][k]*w; a3 += arow[3][k]*w;
        }
        vals[0][tid] = fmaxf(a0, 0.f);
        vals[1][tid] = fmaxf(a1, 0.f);
        vals[2][tid] = fmaxf(a2, 0.f);
        vals[3][tid] = fmaxf(a3, 0.f);
    }
    __syncthreads();

    // wave wv reduces node wv
    const int wv = tid >> 6, lane = tid & 63;
    float v0 = vals[wv][lane];
    float v1 = vals[wv][64+lane];
    float v2 = vals[wv][128+lane];
    float v3 = (lane < 8) ? vals[wv][192+lane] : 0.0f;
    float s  = v0+v1+v2+v3;
    float s2 = v0*v0+v1*v1+v2*v2+v3*v3;
    #pragma unroll
    for (int off = 1; off < 64; off <<= 1) {
        s  += __shfl_xor(s,  off, 64);
        s2 += __shfl_xor(s2, off, 64);
    }
    const float mean = s * (1.0f/DH);
    const float var  = s2 * (1.0f/DH) - mean*mean;
    const float rstd = rsqrtf(var + 1e-5f);
    const size_t base = (size_t)(node0+wv)*DH;
    h[base + lane]       = ln_g[lane]     *(v0-mean)*rstd + ln_b[lane];
    h[base + 64 + lane]  = ln_g[64+lane]  *(v1-mean)*rstd + ln_b[64+lane];
    h[base + 128 + lane] = ln_g[128+lane] *(v2-mean)*rstd + ln_b[128+lane];
    if (lane < 8)
        h[base + 192 + lane] = ln_g[192+lane]*(v3-mean)*rstd + ln_b[192+lane];
}

// ---------------------------------------------------------------------------
// Counting sort by dst: hist -> scan -> scatter
// ---------------------------------------------------------------------------
__global__ __launch_bounds__(256) void hist_kernel(
    const int* __restrict__ edst1, const int* __restrict__ edst2,
    int* __restrict__ deg1, int* __restrict__ deg2)
{
    const int e = blockIdx.x*256 + threadIdx.x;
    atomicAdd(&deg1[edst1[e]], 1);
    atomicAdd(&deg2[edst2[e]], 1);
}

__global__ __launch_bounds__(1024) void scan_kernel(
    const int* __restrict__ deg1, const int* __restrict__ deg2,
    int* __restrict__ start1, int* __restrict__ start2,
    int* __restrict__ cursor1, int* __restrict__ cursor2)
{
    const int side = blockIdx.x;
    const int* deg   = side ? deg2 : deg1;
    int* start  = side ? start2 : start1;
    int* cursor = side ? cursor2 : cursor1;

    __shared__ int part[1024];
    const int t = threadIdx.x;
    const int base = t * 32;
    int local[32];
    int sum = 0;
    #pragma unroll
    for (int i = 0; i < 32; i++) { local[i] = deg[base+i]; sum += local[i]; }
    part[t] = sum;
    __syncthreads();
    for (int off = 1; off < 1024; off <<= 1) {
        int v = (t >= off) ? part[t-off] : 0;
        __syncthreads();
        part[t] += v;
        __syncthreads();
    }
    int run = part[t] - sum;   // exclusive
    #pragma unroll
    for (int i = 0; i < 32; i++) {
        start[base+i] = run;
        cursor[base+i] = run;
        run += local[i];
    }
}

__global__ __launch_bounds__(256) void scatter_kernel(
    const int* __restrict__ edst1, const int* __restrict__ edst2,
    int* __restrict__ cursor1, int* __restrict__ cursor2,
    int* __restrict__ sorted1, int* __restrict__ sorted2)
{
    const int e = blockIdx.x*256 + threadIdx.x;
    {
        const int d = edst1[e];
        const int p = atomicAdd(&cursor1[d], 1);
        sorted1[p] = e;
    }
    {
        const int d = edst2[e];
        const int p = atomicAdd(&cursor2[d], 1);
        sorted2[p] = e;
    }
}

// ---------------------------------------------------------------------------
// Kernel 2': per-node gather of edge messages. One wave per node.
// Wave-uniform scalarized loads (sorted/esrc/ef/coords via s_load),
// edge loop unrolled by 2 for ILP across the shuffle reductions.
// ---------------------------------------------------------------------------
__global__ __launch_bounds__(256) void gather_edge_kernel(
    const float* __restrict__ efeat1, const float* __restrict__ efeat2,
    const int* __restrict__ esrc1, const int* __restrict__ esrc2,
    const float* __restrict__ coords1, const float* __restrict__ coords2,
    const int* __restrict__ sorted1, const int* __restrict__ sorted2,
    const int* __restrict__ start1, const int* __restrict__ start2,
    const int* __restrict__ deg1, const int* __restrict__ deg2,
    const float* __restrict__ W_edge, const float* __restrict__ W_rbf,
    const float* __restrict__ b_rbf,
    const float* __restrict__ ln_g, const float* __restrict__ ln_b,
    float* __restrict__ h1, float* __restrict__ h2)
{
    const int side = blockIdx.y;
    const float* ef     = side ? efeat2  : efeat1;
    const int*   esrc   = side ? esrc2   : esrc1;
    const float* coords = side ? coords2 : coords1;
    const int*   sorted = side ? sorted2 : sorted1;
    const int*   start  = side ? start2  : start1;
    const int*   deg    = side ? deg2    : deg1;
    float* h = side ? h2 : h1;

    const int lane = threadIdx.x & 63;
    const int wv = __builtin_amdgcn_readfirstlane(threadIdx.x >> 6);
    const int node = blockIdx.x*4 + wv;

    // ---- per-lane register weights (reused across all edges of the node)
    float wA[14], wB[16], wC[16], wD[16];
    #pragma unroll
    for (int k = 0; k < 14; k++) wA[k] = W_edge[k*100 + lane];          // c=lane
    #pragma unroll
    for (int k = 0; k < 16; k++) wB[k] = W_rbf[k*100 + 28 + lane];      // c=128+lane
    if (lane < 36) {
        #pragma unroll
        for (int k = 0; k < 14; k++) wC[k] = W_edge[k*100 + 64 + lane]; // c=64+lane (<100)
        #pragma unroll
        for (int k = 14; k < 16; k++) wC[k] = 0.0f;
    } else {
        #pragma unroll
        for (int k = 0; k < 16; k++) wC[k] = W_rbf[k*100 + (lane-36)];  // c=64+lane (>=100)
    }
    if (lane < 8) {
        #pragma unroll
        for (int k = 0; k < 16; k++) wD[k] = W_rbf[k*100 + 92 + lane];  // c=192+lane
    } else {
        #pragma unroll
        for (int k = 0; k < 16; k++) wD[k] = 0.0f;
    }
    const float g0 = ln_g[lane],       bb0 = ln_b[lane];
    const float g1 = ln_g[64+lane],    bb1 = ln_b[64+lane];
    const float g2 = ln_g[128+lane],   bb2 = ln_b[128+lane];
    const float g3 = (lane<8) ? ln_g[192+lane] : 0.0f;
    const float bb3= (lane<8) ? ln_b[192+lane] : 0.0f;
    const float br2 = b_rbf[28+lane];
    const float br1 = (lane >= 36) ? b_rbf[lane-36] : 0.0f;
    const float br3 = (lane < 8)  ? b_rbf[92+lane] : 0.0f;

    const int st = start[node], dg = deg[node];
    const size_t base = (size_t)node * DH;

    float h0 = h[base + lane];
    float h1v = h[base + 64 + lane];
    float h2v = h[base + 128 + lane];
    float h3v = (lane < 8) ? h[base + 192 + lane] : 0.0f;

    const float cdx = coords[node*3+0];
    const float cdy = coords[node*3+1];
    const float cdz = coords[node*3+2];

    float acc0 = 0.f, acc1 = 0.f, acc2 = 0.f, acc3 = 0.f;

    auto edge_vals = [&](int eid, float& v0, float& v1, float& v2, float& v3) {
        const int src = esrc[eid];
        const float dx = coords[src*3+0] - cdx;
        const float dy = coords[src*3+1] - cdy;
        const float dz = coords[src*3+2] - cdz;
        const float dist = sqrtf(dx*dx + dy*dy + dz*dz + 1e-12f);

        float efr[14];
        #pragma unroll
        for (int k = 0; k < 14; k++) efr[k] = ef[(size_t)eid*DE + k];

        float rbf[16];
        #pragma unroll
        for (int k = 0; k < 16; k++) {
            const float t = 3.2f*dist - 1.0666666667f*(float)k;
            rbf[k] = __expf(-t*t);
        }
        v0 = 0.f;
        #pragma unroll
        for (int k = 0; k < 14; k++) v0 += efr[k]*wA[k];
        v0 = fmaxf(v0, 0.f);
        v2 = br2;
        #pragma unroll
        for (int k = 0; k < 16; k++) v2 += rbf[k]*wB[k];
        v2 = fmaxf(v2, 0.f);
        if (lane < 36) {
            v1 = 0.f;
            #pragma unroll
            for (int k = 0; k < 14; k++) v1 += efr[k]*wC[k];
        } else {
            v1 = br1;
            #pragma unroll
            for (int k = 0; k < 16; k++) v1 += rbf[k]*wC[k];
        }
        v1 = fmaxf(v1, 0.f);
        v3 = 0.f;
        if (lane < 8) {
            v3 = br3;
            #pragma unroll
            for (int k = 0; k < 16; k++) v3 += rbf[k]*wD[k];
            v3 = fmaxf(v3, 0.f);
        }
    };

    for (int i = 0; i < dg; i += 2) {
        const bool two = (i+1) < dg;
        const int e0 = sorted[st + i];
        const int e1 = sorted[st + i + (two ? 1 : 0)];

        float a0,a1,a2,a3, b0,b1,b2,b3;
        edge_vals(e0, a0,a1,a2,a3);
        edge_vals(e1, b0,b1,b2,b3);

        float sa  = a0+a1+a2+a3,      sb  = b0+b1+b2+b3;
        float s2a = a0*a0+a1*a1+a2*a2+a3*a3;
        float s2b = b0*b0+b1*b1+b2*b2+b3*b3;
        #pragma unroll
        for (int off = 1; off < 64; off <<= 1) {
            sa  += __shfl_xor(sa,  off, 64);
            s2a += __shfl_xor(s2a, off, 64);
            sb  += __shfl_xor(sb,  off, 64);
            s2b += __shfl_xor(s2b, off, 64);
        }
        {
            const float mean = sa * (1.0f/DH);
            const float var  = s2a * (1.0f/DH) - mean*mean;
            const float rstd = rsqrtf(var + 1e-5f);
            acc0 += g0*(a0-mean)*rstd + bb0;
            acc1 += g1*(a1-mean)*rstd + bb1;
            acc2 += g2*(a2-mean)*rstd + bb2;
            if (lane < 8) acc3 += g3*(a3-mean)*rstd + bb3;
        }
        if (two) {
            const float mean = sb * (1.0f/DH);
            const float var  = s2b * (1.0f/DH) - mean*mean;
            const float rstd = rsqrtf(var + 1e-5f);
            acc0 += g0*(b0-mean)*rstd + bb0;
            acc1 += g1*(b1-mean)*rstd + bb1;
            acc2 += g2*(b2-mean)*rstd + bb2;
            if (lane < 8) acc3 += g3*(b3-mean)*rstd + bb3;
        }
    }

    h[base + lane]        = h0  + acc0;
    h[base + 64 + lane]   = h1v + acc1;
    h[base + 128 + lane]  = h2v + acc2;
    if (lane < 8) h[base + 192 + lane] = h3v + acc3;
}

// ---------------------------------------------------------------------------
// Kernel 3: att[b] = (h1[b] @ h2[b]^T) * T_SCALE   (512x512, K=200)
// 64x64 tile, 256 threads, 4x4 per thread, transposed LDS (b128 reads)
// ---------------------------------------------------------------------------
__global__ __launch_bounds__(256) void att_kernel(
    const float* __restrict__ h1, const float* __restrict__ h2,
    float* __restrict__ att)
{
    const int b = blockIdx.z;
    const int row0 = blockIdx.y * 64, col0 = blockIdx.x * 64;
    const float* A  = h1 + (size_t)b*NN*DH;
    const float* Bm = h2 + (size_t)b*NN*DH;

    __shared__ float Ast[8][68];   // [k][row]
    __shared__ float Bst[8][68];   // [k][col]
    const int tid = threadIdx.x;
    const int tx = tid & 15, ty = tid >> 4;
    const int lr = tid >> 2, lk = (tid & 3)*2;

    float acc[4][4];
    #pragma unroll
    for (int i = 0; i < 4; i++)
        #pragma unroll
        for (int j = 0; j < 4; j++) acc[i][j] = 0.f;

    for (int k0 = 0; k0 < DH; k0 += 8) {
        const float2 av = *(const float2*)&A [(size_t)(row0+lr)*DH + k0 + lk];
        const float2 bv = *(const float2*)&Bm[(size_t)(col0+lr)*DH + k0 + lk];
        __syncthreads();
        Ast[lk][lr] = av.x; Ast[lk+1][lr] = av.y;
        Bst[lk][lr] = bv.x; Bst[lk+1][lr] = bv.y;
        __syncthreads();
        #pragma unroll
        for (int kk = 0; kk < 8; kk++) {
            const float4 a4 = *(const float4*)&Ast[kk][ty*4];
            const float4 b4 = *(const float4*)&Bst[kk][tx*4];
            acc[0][0] += a4.x*b4.x; acc[0][1] += a4.x*b4.y; acc[0][2] += a4.x*b4.z; acc[0][3] += a4.x*b4.w;
            acc[1][0] += a4.y*b4.x; acc[1][1] += a4.y*b4.y; acc[1][2] += a4.y*b4.z; acc[1][3] += a4.y*b4.w;
            acc[2][0] += a4.z*b4.x; acc[2][1] += a4.z*b4.y; acc[2][2] += a4.z*b4.z; acc[2][3] += a4.z*b4.w;
            acc[3][0] += a4.w*b4.x; acc[3][1] += a4.w*b4.y; acc[3][2] += a4.w*b4.z; acc[3][3] += a4.w*b4.w;
        }
    }
    const size_t base = (size_t)b*NN*NN;
    #pragma unroll
    for (int i = 0; i < 4; i++) {
        float4 o;
        o.x = acc[i][0]*T_SCALE; o.y = acc[i][1]*T_SCALE;
        o.z = acc[i][2]*T_SCALE; o.w = acc[i][3]*T_SCALE;
        *(float4*)&att[base + (size_t)(row0+ty*4+i)*NN + col0 + tx*4] = o;
    }
}

// ---------------------------------------------------------------------------
// Kernel 4: softmax (rows of att, or of att^T) then @ V  -> out [B,N,DH]
// 32 rows per block, 8 rows per wave; p row-major [32][516] (b128-aligned);
// lane owns cols {l, 64+l, 128+l, 192+l(l<8)}
// ---------------------------------------------------------------------------
__global__ __launch_bounds__(256) void ckern(
    const float* __restrict__ att, const float* __restrict__ V,
    float* __restrict__ out, const int trans)
{
    const int b = blockIdx.y;
    const int row0 = blockIdx.x * 32;
    const float* attb = att + (size_t)b*NN*NN;
    const float* Vb   = V   + (size_t)b*NN*DH;

    __shared__ float p[32][516];
    __shared__ float hv[8][DH];
    const int tid = threadIdx.x;

    if (!trans) {
        #pragma unroll
        for (int pass = 0; pass < 16; pass++) {
            const int f = pass*256 + tid;          // f4 index
            const int r = f >> 7, m4 = f & 127;
            const float4 v = *(const float4*)&attb[(size_t)(row0+r)*NN + 4*m4];
            *(float4*)&p[r][4*m4] = v;
        }
    } else {
        #pragma unroll
        for (int pass = 0; pass < 16; pass++) {
            const int f = pass*256 + tid;
            const int k = f >> 3, r4 = f & 7;
            const float4 v = *(const float4*)&attb[(size_t)k*NN + row0 + 4*r4];
            p[4*r4  ][k] = v.x;
            p[4*r4+1][k] = v.y;
            p[4*r4+2][k] = v.z;
            p[4*r4+3][k] = v.w;
        }
    }
    __syncthreads();

    const int wv = tid >> 6, lane = tid & 63;
    #pragma unroll
    for (int rr = 0; rr < 8; rr++) {
        const int r = wv*8 + rr;
        float v[8];
        float m = -1e30f;
        #pragma unroll
        for (int i = 0; i < 8; i++) { v[i] = p[r][lane + 64*i]; m = fmaxf(m, v[i]); }
        #pragma unroll
        for (int off = 1; off < 64; off <<= 1) m = fmaxf(m, __shfl_xor(m, off, 64));
        float s = 0.f;
        #pragma unroll
        for (int i = 0; i < 8; i++) { v[i] = __expf(v[i]-m); s += v[i]; }
        #pragma unroll
        for (int off = 1; off < 64; off <<= 1) s += __shfl_xor(s, off, 64);
        const float inv = 1.0f / s;
        #pragma unroll
        for (int i = 0; i < 8; i++) p[r][lane + 64*i] = v[i]*inv;
    }

    float acc[8][4];
    #pragma unroll
    for (int r = 0; r < 8; r++)
        #pragma unroll
        for (int j = 0; j < 4; j++) acc[r][j] = 0.0f;

    for (int m0 = 0; m0 < NN; m0 += 8) {
        __syncthreads();
        #pragma unroll
        for (int mm = 0; mm < 8; mm++)
            if (tid < DH) hv[mm][tid] = Vb[(size_t)(m0+mm)*DH + tid];
        __syncthreads();
        #pragma unroll
        for (int mm = 0; mm < 8; mm++) {
            float hvv[4];
            #pragma unroll
            for (int j = 0; j < 4; j++) {
                const int c = lane + 64*j;
                hvv[j] = (c < DH) ? hv[mm][c] : 0.0f;
            }
            #pragma unroll
            for (int r = 0; r < 8; r++) {
                const float pv = p[wv*8 + r][m0 + mm];
                acc[r][0] += pv*hvv[0];
                acc[r][1] += pv*hvv[1];
                acc[r][2] += pv*hvv[2];
                acc[r][3] += pv*hvv[3];
            }
        }
    }
    #pragma unroll
    for (int r = 0; r < 8; r++)
        #pragma unroll
        for (int j = 0; j < 4; j++) {
            const int c = lane + 64*j;
            if (c < DH)
                out[((size_t)b*NN + row0 + wv*8 + r)*DH + c] = acc[r][j];
        }
}

// ---------------------------------------------------------------------------
// Kernel 5: relu(concat(h,c)@W_down) + degree_table[deg]  -> mean over nodes
// 32 nodes per block, 8 per wave
// ---------------------------------------------------------------------------
__global__ __launch_bounds__(256) void down_kernel(
    const float* __restrict__ h1, const float* __restrict__ h2,
    const float* __restrict__ c1, const float* __restrict__ c2,
    const int* __restrict__ deg1, const int* __restrict__ deg2,
    const float* __restrict__ W_down, const float* __restrict__ degree_table,
    float* __restrict__ hsg1, float* __restrict__ hsg2)
{
    const int side = blockIdx.y;
    const float* h  = side ? h2 : h1;
    const float* cc = side ? c2 : c1;
    const int*   dg = side ? deg2 : deg1;
    float* hsg = side ? hsg2 : hsg1;

    const int node0 = blockIdx.x * 32;
    const int b = node0 >> 9;

    __shared__ float x[32][404];
    __shared__ float ws[8][DH];
    __shared__ float part[4][DH];
    const int tid = threadIdx.x;

    for (int pass = 0; pass < 13; pass++) {
        const int f = pass*256 + tid;       // f4 index over 32x100
        if (f < 3200) {
            const int r = f / 100, q = f % 100;
            float4 v;
            if (q < 50) v = *(const float4*)&h [(size_t)(node0+r)*DH + 4*q];
            else        v = *(const float4*)&cc[(size_t)(node0+r)*DH + 4*q - DH];
            *(float4*)&x[r][4*q] = v;
        }
    }
    __syncthreads();

    const int wv = tid >> 6, lane = tid & 63;
    float acc[8][4];
    #pragma unroll
    for (int r = 0; r < 8; r++)
        #pragma unroll
        for (int j = 0; j < 4; j++) acc[r][j] = 0.0f;

    for (int k0 = 0; k0 < 400; k0 += 8) {
        __syncthreads();
        #pragma unroll
        for (int kk = 0; kk < 8; kk++)
            if (tid < DH) ws[kk][tid] = W_down[(size_t)(k0+kk)*DH + tid];
        __syncthreads();
        #pragma unroll
        for (int kk = 0; kk < 8; kk++) {
            float wv4[4];
            #pragma unroll
            for (int j = 0; j < 4; j++) {
                const int c = lane + 64*j;
                wv4[j] = (c < DH) ? ws[kk][c] : 0.0f;
            }
            #pragma unroll
            for (int r = 0; r < 8; r++) {
                const float xv = x[wv*8 + r][k0 + kk];
                acc[r][0] += xv*wv4[0];
                acc[r][1] += xv*wv4[1];
                acc[r][2] += xv*wv4[2];
                acc[r][3] += xv*wv4[3];
            }
        }
    }

    #pragma unroll
    for (int j = 0; j < 4; j++) {
        const int c = lane + 64*j;
        if (c < DH) {
            float colsum = 0.0f;
            #pragma unroll
            for (int r = 0; r < 8; r++) {
                int d = dg[node0 + wv*8 + r];
                d = d > 199 ? 199 : d;
                colsum += fmaxf(acc[r][j], 0.0f) + degree_table[d*DH + c];
            }
            part[wv][c] = colsum;
        }
    }
    __syncthreads();
    if (tid < DH) {
        const float tot = part[0][tid]+part[1][tid]+part[2][tid]+part[3][tid];
        unsafeAtomicAdd(&hsg[b*206 + tid], tot * (1.0f/512.0f));
    }
}

// ---------------------------------------------------------------------------
// Kernel 6: interaction mean over nodes -> hsg cols 200..205
// ---------------------------------------------------------------------------
__global__ __launch_bounds__(192) void inter_kernel(
    const float* __restrict__ i1, const float* __restrict__ i2,
    float* __restrict__ hsg1, float* __restrict__ hsg2)
{
    const int side = blockIdx.y;
    const float* it = side ? i2 : i1;
    float* hsg = side ? hsg2 : hsg1;
    const int b = blockIdx.x;
    __shared__ float red[192];
    const int tid = threadIdx.x;
    const int j = tid % 6, seg = tid / 6;   // seg < 32
    float s = 0.0f;
    for (int n = seg*16; n < seg*16 + 16; n++)
        s += it[(size_t)b*NN*DI + n*DI + j];
    red[tid] = s;
    __syncthreads();
    if (tid < 6) {
        float tot = 0.0f;
        for (int sg2 = 0; sg2 < 32; sg2++) tot += red[sg2*6 + tid];
        hsg[b*206 + 200 + tid] = tot * (1.0f/512.0f);
    }
}

// ---------------------------------------------------------------------------
// Kernel 7: final MLP, one block per batch row
// ---------------------------------------------------------------------------
__global__ __launch_bounds__(256) void mlp_kernel(
    const float* __restrict__ hsg1, const float* __restrict__ hsg2,
    const float* __restrict__ W_f1, const float* __restrict__ b_f1,
    const float* __restrict__ W_f2, const float* __restrict__ b_f2,
    const float* __restrict__ W_f3, const float* __restrict__ b_f3,
    const float* __restrict__ W_f4, const float* __restrict__ b_f4,
    float* __restrict__ out)
{
    const int b = blockIdx.x;
    __shared__ float x[618];
    __shared__ float y1[400];
    __shared__ float y2[200];
    __shared__ float y3[100];
    __shared__ float red[256];
    const int tid = threadIdx.x;

    if (tid < 206) {
        const float a = hsg1[b*206 + tid], bb = hsg2[b*206 + tid];
        x[tid] = a; x[206 + tid] = bb; x[412 + tid] = a - bb;
    }
    __syncthreads();
    for (int c = tid; c < 400; c += 256) {
        float acc = b_f1[c];
        for (int k = 0; k < 618; k++) acc += x[k]*W_f1[(size_t)k*400 + c];
        y1[c] = fmaxf(acc, 0.0f);
    }
    __syncthreads();
    if (tid < 200) {
        float acc = b_f2[tid];
        for (int k = 0; k < 400; k++) acc += y1[k]*W_f2[k*200 + tid];
        y2[tid] = fmaxf(acc, 0.0f);
    }
    __syncthreads();
    if (tid < 100) {
        float acc = b_f3[tid];
        for (int k = 0; k < 200; k++) acc += y2[k]*W_f3[k*100 + tid];
        y3[tid] = fmaxf(acc, 0.0f);
    }
    __syncthreads();
    red[tid] = (tid < 100) ? y3[tid]*W_f4[tid] : 0.0f;
    __syncthreads();
    for (int s = 128; s > 0; s >>= 1) {
        if (tid < s) red[tid] += red[tid + s];
        __syncthreads();
    }
    if (tid == 0) out[b] = red[0] + b_f4[0];
}

// ---------------------------------------------------------------------------
extern "C" void kernel_launch(void* const* d_in, const int* in_sizes, int n_in,
                              void* d_out, int out_size, void* d_ws, size_t ws_size,
                              hipStream_t stream)
{
    const float* atom1  = (const float*)d_in[0];
    const float* atom2  = (const float*)d_in[1];
    const float* coords1= (const float*)d_in[2];
    const float* coords2= (const float*)d_in[3];
    const float* efeat1 = (const float*)d_in[4];
    const float* efeat2 = (const float*)d_in[5];
    const float* inter1 = (const float*)d_in[6];
    const float* inter2 = (const float*)d_in[7];
    const int*   esrc1  = (const int*)d_in[8];
    const int*   edst1  = (const int*)d_in[9];
    const int*   esrc2  = (const int*)d_in[10];
    const int*   edst2  = (const int*)d_in[11];
    const float* W_atom = (const float*)d_in[12];
    const float* W_edge = (const float*)d_in[13];
    const float* W_rbf  = (const float*)d_in[14];
    const float* b_rbf  = (const float*)d_in[15];
    const float* ln_g   = (const float*)d_in[16];
    const float* ln_b   = (const float*)d_in[17];
    const float* W_down = (const float*)d_in[18];
    const float* deg_tab= (const float*)d_in[19];
    const float* W_f1   = (const float*)d_in[20];
    const float* b_f1   = (const float*)d_in[21];
    const float* W_f2   = (const float*)d_in[22];
    const float* b_f2   = (const float*)d_in[23];
    const float* W_f3   = (const float*)d_in[24];
    const float* b_f3   = (const float*)d_in[25];
    const float* W_f4   = (const float*)d_in[26];
    const float* b_f4   = (const float*)d_in[27];
    float* out = (float*)d_out;

    // workspace layout (floats)
    float* ws = (float*)d_ws;
    const size_t HSZ = (size_t)BN*DH;          // 6,553,600
    float* h1  = ws;
    float* h2  = h1 + HSZ;
    float* att = h2 + HSZ;                      // B*N*N = 16,777,216
    float* c1  = att + (size_t)BB*NN*NN;
    float* c2  = c1 + HSZ;
    float* hsg1 = c2 + HSZ;                     // 64*206
    float* hsg2 = hsg1 + (size_t)BB*206;
    int* deg1 = (int*)(hsg2 + (size_t)BB*206);
    int* deg2 = deg1 + BN;
    int* start1 = deg2 + BN;
    int* start2 = start1 + BN;
    int* cursor1 = start2 + BN;
    int* cursor2 = cursor1 + BN;
    int* sorted1 = cursor2 + BN;
    int* sorted2 = sorted1 + EE;

    hipMemsetAsync(deg1, 0, 2*(size_t)BN*sizeof(int), stream);
    hipMemsetAsync(hsg1, 0, 2*(size_t)BB*206*sizeof(float), stream);

    node_kernel<<<dim3(BN/4, 2), 256, 0, stream>>>(
        atom1, atom2, W_atom, ln_g, ln_b, h1, h2);

    hist_kernel<<<EE/256, 256, 0, stream>>>(edst1, edst2, deg1, deg2);
    scan_kernel<<<2, 1024, 0, stream>>>(deg1, deg2, start1, start2, cursor1, cursor2);
    scatter_kernel<<<EE/256, 256, 0, stream>>>(edst1, edst2, cursor1, cursor2, sorted1, sorted2);

    gather_edge_kernel<<<dim3(BN/4, 2), 256, 0, stream>>>(
        efeat1, efeat2, esrc1, esrc2, coords1, coords2,
        sorted1, sorted2, start1, start2, deg1, deg2,
        W_edge, W_rbf, b_rbf, ln_g, ln_b, h1, h2);

    att_kernel<<<dim3(8, 8, BB), 256, 0, stream>>>(h1, h2, att);

    ckern<<<dim3(NN/32, BB), 256, 0, stream>>>(att, h2, c1, 0);
    ckern<<<dim3(NN/32, BB), 256, 0, stream>>>(att, h1, c2, 1);

    down_kernel<<<dim3(BN/32, 2), 256, 0, stream>>>(
        h1, h2, c1, c2, deg1, deg2, W_down, deg_tab, hsg1, hsg2);

    inter_kernel<<<dim3(BB, 2), 192, 0, stream>>>(inter1, inter2, hsg1, hsg2);

    mlp_kernel<<<BB, 256, 0, stream>>>(
        hsg1, hsg2, W_f1, b_f1, W_f2, b_f2, W_f3, b_f3, W_f4, b_f4, out);
}

// Round 4
// 1589.691 us; speedup vs baseline: 2.0367x; 1.2321x over previous
//
#include <hip/hip_runtime.h>
#include <cstddef>
#include <cstdint>

// Problem constants
#define BB   64
#define NN   512
#define BN   (BB*NN)          // 32768
#define EE   524288
#define DA   70
#define DE   14
#define DH   200
#define DI   6
#define T_SCALE 0.07071067811865475f   // sqrt(1/200)

// ---------------------------------------------------------------------------
// Kernel 1: per-node  h = layernorm(relu(atom @ W_atom))
// ---------------------------------------------------------------------------
__global__ __launch_bounds__(256) void node_kernel(
    const float* __restrict__ atom1, const float* __restrict__ atom2,
    const float* __restrict__ W_atom,
    const float* __restrict__ ln_g, const float* __restrict__ ln_b,
    float* __restrict__ h1, float* __restrict__ h2)
{
    const int side = blockIdx.y;
    const float* atom = side ? atom2 : atom1;
    float* h = side ? h2 : h1;
    const int node0 = blockIdx.x * 4;
    const int tid = threadIdx.x;

    __shared__ float arow[4][DA];
    __shared__ float vals[4][DH];

    for (int i = tid; i < 4*DA; i += 256) {
        const int n = i / DA, k = i % DA;
        arow[n][k] = atom[(size_t)(node0+n)*DA + k];
    }
    __syncthreads();

    if (tid < DH) {
        float a0 = 0.f, a1 = 0.f, a2 = 0.f, a3 = 0.f;
        #pragma unroll 7
        for (int k = 0; k < DA; k++) {
            const float w = W_atom[k*DH + tid];
            a0 += arow[0][k]*w; a1 += arow[1][k]*w;
            a2 += arow[2][k]*w; a3 += arow[3][k]*w;
        }
        vals[0][tid] = fmaxf(a0, 0.f);
        vals[1][tid] = fmaxf(a1, 0.f);
        vals[2][tid] = fmaxf(a2, 0.f);
        vals[3][tid] = fmaxf(a3, 0.f);
    }
    __syncthreads();

    const int wv = tid >> 6, lane = tid & 63;
    float v0 = vals[wv][lane];
    float v1 = vals[wv][64+lane];
    float v2 = vals[wv][128+lane];
    float v3 = (lane < 8) ? vals[wv][192+lane] : 0.0f;
    float s  = v0+v1+v2+v3;
    float s2 = v0*v0+v1*v1+v2*v2+v3*v3;
    #pragma unroll
    for (int off = 1; off < 64; off <<= 1) {
        s  += __shfl_xor(s,  off, 64);
        s2 += __shfl_xor(s2, off, 64);
    }
    const float mean = s * (1.0f/DH);
    const float var  = s2 * (1.0f/DH) - mean*mean;
    const float rstd = rsqrtf(var + 1e-5f);
    const size_t base = (size_t)(node0+wv)*DH;
    h[base + lane]       = ln_g[lane]     *(v0-mean)*rstd + ln_b[lane];
    h[base + 64 + lane]  = ln_g[64+lane]  *(v1-mean)*rstd + ln_b[64+lane];
    h[base + 128 + lane] = ln_g[128+lane] *(v2-mean)*rstd + ln_b[128+lane];
    if (lane < 8)
        h[base + 192 + lane] = ln_g[192+lane]*(v3-mean)*rstd + ln_b[192+lane];
}

// ---------------------------------------------------------------------------
// Counting sort by dst: hist -> scan -> scatter
// ---------------------------------------------------------------------------
__global__ __launch_bounds__(256) void hist_kernel(
    const int* __restrict__ edst1, const int* __restrict__ edst2,
    int* __restrict__ deg1, int* __restrict__ deg2)
{
    const int e = blockIdx.x*256 + threadIdx.x;
    atomicAdd(&deg1[edst1[e]], 1);
    atomicAdd(&deg2[edst2[e]], 1);
}

__global__ __launch_bounds__(1024) void scan_kernel(
    const int* __restrict__ deg1, const int* __restrict__ deg2,
    int* __restrict__ start1, int* __restrict__ start2,
    int* __restrict__ cursor1, int* __restrict__ cursor2)
{
    const int side = blockIdx.x;
    const int* deg   = side ? deg2 : deg1;
    int* start  = side ? start2 : start1;
    int* cursor = side ? cursor2 : cursor1;

    __shared__ int part[1024];
    const int t = threadIdx.x;
    const int base = t * 32;
    int local[32];
    int sum = 0;
    #pragma unroll
    for (int i = 0; i < 32; i++) { local[i] = deg[base+i]; sum += local[i]; }
    part[t] = sum;
    __syncthreads();
    for (int off = 1; off < 1024; off <<= 1) {
        int v = (t >= off) ? part[t-off] : 0;
        __syncthreads();
        part[t] += v;
        __syncthreads();
    }
    int run = part[t] - sum;   // exclusive
    #pragma unroll
    for (int i = 0; i < 32; i++) {
        start[base+i] = run;
        cursor[base+i] = run;
        run += local[i];
    }
}

__global__ __launch_bounds__(256) void scatter_kernel(
    const int* __restrict__ edst1, const int* __restrict__ edst2,
    int* __restrict__ cursor1, int* __restrict__ cursor2,
    int* __restrict__ sorted1, int* __restrict__ sorted2)
{
    const int e = blockIdx.x*256 + threadIdx.x;
    {
        const int d = edst1[e];
        const int p = atomicAdd(&cursor1[d], 1);
        sorted1[p] = e;
    }
    {
        const int d = edst2[e];
        const int p = atomicAdd(&cursor2[d], 1);
        sorted2[p] = e;
    }
}

// ---------------------------------------------------------------------------
// Phase 1: per-edge precompute (lane = edge, natural order, balanced).
// Computes rbf[16] (one set of exps per edge TOTAL) and LayerNorm stats.
// Writes 18 floats/edge: [rbf 0..15][mu*rstd][rstd]
// ---------------------------------------------------------------------------
__global__ __launch_bounds__(256) void edge_pre_kernel(
    const float* __restrict__ efeat1, const float* __restrict__ efeat2,
    const int* __restrict__ esrc1, const int* __restrict__ esrc2,
    const int* __restrict__ edst1, const int* __restrict__ edst2,
    const float* __restrict__ coords1, const float* __restrict__ coords2,
    const float* __restrict__ W_edge, const float* __restrict__ W_rbf,
    const float* __restrict__ b_rbf,
    float* __restrict__ pre1, float* __restrict__ pre2)
{
    const int side = blockIdx.y;
    const float* ef     = side ? efeat2  : efeat1;
    const int*   esrc   = side ? esrc2   : esrc1;
    const int*   edst   = side ? edst2   : edst1;
    const float* coords = side ? coords2 : coords1;
    float* pre = side ? pre2 : pre1;

    __shared__ float WeT[100][16];   // [c][k], k padded 14->16 (pad=0)
    __shared__ float WrT[100][16];   // [c][k]
    __shared__ float sbr[100];
    const int tid = threadIdx.x;

    for (int i = tid; i < 1400; i += 256) {
        const int k = i / 100, c = i % 100;
        WeT[c][k] = W_edge[i];
    }
    for (int i = tid; i < 1600; i += 256) {
        const int k = i / 100, c = i % 100;
        WrT[c][k] = W_rbf[i];
    }
    for (int c = tid; c < 100; c += 256) { WeT[c][14] = 0.f; WeT[c][15] = 0.f; }
    if (tid < 100) sbr[tid] = b_rbf[tid];
    __syncthreads();

    const int e = blockIdx.x*256 + tid;
    const int src = esrc[e], dst = edst[e];

    float efr[16];
    #pragma unroll
    for (int k = 0; k < 14; k++) efr[k] = ef[(size_t)e*DE + k];
    efr[14] = 0.f; efr[15] = 0.f;

    const float dx = coords[src*3+0] - coords[dst*3+0];
    const float dy = coords[src*3+1] - coords[dst*3+1];
    const float dz = coords[src*3+2] - coords[dst*3+2];
    const float dist = sqrtf(dx*dx + dy*dy + dz*dz + 1e-12f);

    float rbf[16];
    #pragma unroll
    for (int k = 0; k < 16; k++) {
        const float t = 3.2f*dist - 1.0666666667f*(float)k;
        rbf[k] = __expf(-t*t);
    }

    float s = 0.f, s2 = 0.f;
    for (int c = 0; c < 100; c++) {
        const float4 we0 = *(const float4*)&WeT[c][0];
        const float4 we1 = *(const float4*)&WeT[c][4];
        const float4 we2 = *(const float4*)&WeT[c][8];
        const float4 we3 = *(const float4*)&WeT[c][12];
        float xe = efr[0]*we0.x + efr[1]*we0.y + efr[2]*we0.z + efr[3]*we0.w
                 + efr[4]*we1.x + efr[5]*we1.y + efr[6]*we1.z + efr[7]*we1.w
                 + efr[8]*we2.x + efr[9]*we2.y + efr[10]*we2.z + efr[11]*we2.w
                 + efr[12]*we3.x + efr[13]*we3.y;
        xe = fmaxf(xe, 0.f);
        s += xe; s2 += xe*xe;

        const float4 wr0 = *(const float4*)&WrT[c][0];
        const float4 wr1 = *(const float4*)&WrT[c][4];
        const float4 wr2 = *(const float4*)&WrT[c][8];
        const float4 wr3 = *(const float4*)&WrT[c][12];
        float xr = sbr[c]
                 + rbf[0]*wr0.x + rbf[1]*wr0.y + rbf[2]*wr0.z + rbf[3]*wr0.w
                 + rbf[4]*wr1.x + rbf[5]*wr1.y + rbf[6]*wr1.z + rbf[7]*wr1.w
                 + rbf[8]*wr2.x + rbf[9]*wr2.y + rbf[10]*wr2.z + rbf[11]*wr2.w
                 + rbf[12]*wr3.x + rbf[13]*wr3.y + rbf[14]*wr3.z + rbf[15]*wr3.w;
        xr = fmaxf(xr, 0.f);
        s += xr; s2 += xr*xr;
    }
    const float mean = s * (1.0f/DH);
    const float var  = s2 * (1.0f/DH) - mean*mean;
    const float rstd = rsqrtf(var + 1e-5f);

    float* pe = pre + (size_t)e*18;
    #pragma unroll
    for (int k = 0; k < 16; k += 2) {
        float2 v; v.x = rbf[k]; v.y = rbf[k+1];
        *(float2*)&pe[k] = v;
    }
    float2 st; st.x = mean*rstd; st.y = rstd;
    *(float2*)&pe[16] = st;
}

// ---------------------------------------------------------------------------
// Phase 2: per-node gather. One wave per node. Inner loop: two small dots +
// rstd-weighted accumulate. No exp, no shuffles, no per-edge LN.
// h_c += g_c*(sum_e rstd*x_ec - sum_e mu*rstd) + deg*b_c
// ---------------------------------------------------------------------------
__global__ __launch_bounds__(256) void gather_edge_kernel(
    const float* __restrict__ efeat1, const float* __restrict__ efeat2,
    const float* __restrict__ pre1, const float* __restrict__ pre2,
    const int* __restrict__ sorted1, const int* __restrict__ sorted2,
    const int* __restrict__ start1, const int* __restrict__ start2,
    const int* __restrict__ deg1, const int* __restrict__ deg2,
    const float* __restrict__ W_edge, const float* __restrict__ W_rbf,
    const float* __restrict__ b_rbf,
    const float* __restrict__ ln_g, const float* __restrict__ ln_b,
    float* __restrict__ h1, float* __restrict__ h2)
{
    const int side = blockIdx.y;
    const float* ef     = side ? efeat2  : efeat1;
    const float* pre    = side ? pre2    : pre1;
    const int*   sorted = side ? sorted2 : sorted1;
    const int*   start  = side ? start2  : start1;
    const int*   deg    = side ? deg2    : deg1;
    float* h = side ? h2 : h1;

    const int lane = threadIdx.x & 63;
    const int wv = __builtin_amdgcn_readfirstlane(threadIdx.x >> 6);
    const int node = blockIdx.x*4 + wv;

    // per-lane register weights: lane owns cols {l, 64+l, 128+l, 192+l(l<8)}
    float wA[14], wB[16], wC[16], wD[16];
    #pragma unroll
    for (int k = 0; k < 14; k++) wA[k] = W_edge[k*100 + lane];
    #pragma unroll
    for (int k = 0; k < 16; k++) wB[k] = W_rbf[k*100 + 28 + lane];
    if (lane < 36) {
        #pragma unroll
        for (int k = 0; k < 14; k++) wC[k] = W_edge[k*100 + 64 + lane];
        #pragma unroll
        for (int k = 14; k < 16; k++) wC[k] = 0.0f;
    } else {
        #pragma unroll
        for (int k = 0; k < 16; k++) wC[k] = W_rbf[k*100 + (lane-36)];
    }
    if (lane < 8) {
        #pragma unroll
        for (int k = 0; k < 16; k++) wD[k] = W_rbf[k*100 + 92 + lane];
    } else {
        #pragma unroll
        for (int k = 0; k < 16; k++) wD[k] = 0.0f;
    }
    const float g0 = ln_g[lane],       bb0 = ln_b[lane];
    const float g1 = ln_g[64+lane],    bb1 = ln_b[64+lane];
    const float g2 = ln_g[128+lane],   bb2 = ln_b[128+lane];
    const float g3 = (lane<8) ? ln_g[192+lane] : 0.0f;
    const float bb3= (lane<8) ? ln_b[192+lane] : 0.0f;
    const float br2 = b_rbf[28+lane];
    const float br1 = (lane >= 36) ? b_rbf[lane-36] : 0.0f;
    const float br3 = (lane < 8)  ? b_rbf[92+lane] : 0.0f;

    const int st = start[node], dg = deg[node];
    const size_t base = (size_t)node * DH;

    const float h0  = h[base + lane];
    const float h1v = h[base + 64 + lane];
    const float h2v = h[base + 128 + lane];
    const float h3v = (lane < 8) ? h[base + 192 + lane] : 0.0f;

    float acc0 = 0.f, acc1 = 0.f, acc2 = 0.f, acc3 = 0.f, musum = 0.f;

    auto do_edge = [&](int eid) {
        const float* pe = pre + (size_t)eid*18;
        float rbf[16];
        #pragma unroll
        for (int k = 0; k < 16; k++) rbf[k] = pe[k];
        const float musrtd = pe[16];
        const float rstd   = pe[17];
        float efr[14];
        #pragma unroll
        for (int k = 0; k < 14; k++) efr[k] = ef[(size_t)eid*DE + k];

        float v0 = 0.f;
        #pragma unroll
        for (int k = 0; k < 14; k++) v0 += efr[k]*wA[k];
        v0 = fmaxf(v0, 0.f);

        float v2 = br2;
        #pragma unroll
        for (int k = 0; k < 16; k++) v2 += rbf[k]*wB[k];
        v2 = fmaxf(v2, 0.f);

        float v1;
        if (lane < 36) {
            v1 = 0.f;
            #pragma unroll
            for (int k = 0; k < 14; k++) v1 += efr[k]*wC[k];
        } else {
            v1 = br1;
            #pragma unroll
            for (int k = 0; k < 16; k++) v1 += rbf[k]*wC[k];
        }
        v1 = fmaxf(v1, 0.f);

        float v3 = br3;
        #pragma unroll
        for (int k = 0; k < 16; k++) v3 += rbf[k]*wD[k];
        v3 = fmaxf(v3, 0.f);

        acc0 += rstd*v0;
        acc1 += rstd*v1;
        acc2 += rstd*v2;
        acc3 += rstd*v3;
        musum += musrtd;
    };

    for (int i = 0; i < dg; i += 2) {
        const bool two = (i+1) < dg;
        const int e0 = sorted[st + i];
        const int e1 = sorted[st + i + (two ? 1 : 0)];
        do_edge(e0);
        if (two) do_edge(e1);
    }

    const float dgf = (float)dg;
    h[base + lane]       = h0  + g0*(acc0 - musum) + dgf*bb0;
    h[base + 64 + lane]  = h1v + g1*(acc1 - musum) + dgf*bb1;
    h[base + 128 + lane] = h2v + g2*(acc2 - musum) + dgf*bb2;
    if (lane < 8)
        h[base + 192 + lane] = h3v + g3*(acc3 - musum) + dgf*bb3;
}

// ---------------------------------------------------------------------------
// Kernel 3: att[b] = (h1[b] @ h2[b]^T) * T_SCALE   (512x512, K=200)
// ---------------------------------------------------------------------------
__global__ __launch_bounds__(256) void att_kernel(
    const float* __restrict__ h1, const float* __restrict__ h2,
    float* __restrict__ att)
{
    const int b = blockIdx.z;
    const int row0 = blockIdx.y * 64, col0 = blockIdx.x * 64;
    const float* A  = h1 + (size_t)b*NN*DH;
    const float* Bm = h2 + (size_t)b*NN*DH;

    __shared__ float Ast[8][68];   // [k][row]
    __shared__ float Bst[8][68];   // [k][col]
    const int tid = threadIdx.x;
    const int tx = tid & 15, ty = tid >> 4;
    const int lr = tid >> 2, lk = (tid & 3)*2;

    float acc[4][4];
    #pragma unroll
    for (int i = 0; i < 4; i++)
        #pragma unroll
        for (int j = 0; j < 4; j++) acc[i][j] = 0.f;

    for (int k0 = 0; k0 < DH; k0 += 8) {
        const float2 av = *(const float2*)&A [(size_t)(row0+lr)*DH + k0 + lk];
        const float2 bv = *(const float2*)&Bm[(size_t)(col0+lr)*DH + k0 + lk];
        __syncthreads();
        Ast[lk][lr] = av.x; Ast[lk+1][lr] = av.y;
        Bst[lk][lr] = bv.x; Bst[lk+1][lr] = bv.y;
        __syncthreads();
        #pragma unroll
        for (int kk = 0; kk < 8; kk++) {
            const float4 a4 = *(const float4*)&Ast[kk][ty*4];
            const float4 b4 = *(const float4*)&Bst[kk][tx*4];
            acc[0][0] += a4.x*b4.x; acc[0][1] += a4.x*b4.y; acc[0][2] += a4.x*b4.z; acc[0][3] += a4.x*b4.w;
            acc[1][0] += a4.y*b4.x; acc[1][1] += a4.y*b4.y; acc[1][2] += a4.y*b4.z; acc[1][3] += a4.y*b4.w;
            acc[2][0] += a4.z*b4.x; acc[2][1] += a4.z*b4.y; acc[2][2] += a4.z*b4.z; acc[2][3] += a4.z*b4.w;
            acc[3][0] += a4.w*b4.x; acc[3][1] += a4.w*b4.y; acc[3][2] += a4.w*b4.z; acc[3][3] += a4.w*b4.w;
        }
    }
    const size_t base = (size_t)b*NN*NN;
    #pragma unroll
    for (int i = 0; i < 4; i++) {
        float4 o;
        o.x = acc[i][0]*T_SCALE; o.y = acc[i][1]*T_SCALE;
        o.z = acc[i][2]*T_SCALE; o.w = acc[i][3]*T_SCALE;
        *(float4*)&att[base + (size_t)(row0+ty*4+i)*NN + col0 + tx*4] = o;
    }
}

// ---------------------------------------------------------------------------
// Kernel 4: softmax (rows of att, or of att^T) then @ V  -> out [B,N,DH]
// ---------------------------------------------------------------------------
__global__ __launch_bounds__(256) void ckern(
    const float* __restrict__ att, const float* __restrict__ V,
    float* __restrict__ out, const int trans)
{
    const int b = blockIdx.y;
    const int row0 = blockIdx.x * 32;
    const float* attb = att + (size_t)b*NN*NN;
    const float* Vb   = V   + (size_t)b*NN*DH;

    __shared__ float p[32][516];
    __shared__ float hv[8][DH];
    const int tid = threadIdx.x;

    if (!trans) {
        #pragma unroll
        for (int pass = 0; pass < 16; pass++) {
            const int f = pass*256 + tid;          // f4 index
            const int r = f >> 7, m4 = f & 127;
            const float4 v = *(const float4*)&attb[(size_t)(row0+r)*NN + 4*m4];
            *(float4*)&p[r][4*m4] = v;
        }
    } else {
        #pragma unroll
        for (int pass = 0; pass < 16; pass++) {
            const int f = pass*256 + tid;
            const int k = f >> 3, r4 = f & 7;
            const float4 v = *(const float4*)&attb[(size_t)k*NN + row0 + 4*r4];
            p[4*r4  ][k] = v.x;
            p[4*r4+1][k] = v.y;
            p[4*r4+2][k] = v.z;
            p[4*r4+3][k] = v.w;
        }
    }
    __syncthreads();

    const int wv = tid >> 6, lane = tid & 63;
    #pragma unroll
    for (int rr = 0; rr < 8; rr++) {
        const int r = wv*8 + rr;
        float v[8];
        float m = -1e30f;
        #pragma unroll
        for (int i = 0; i < 8; i++) { v[i] = p[r][lane + 64*i]; m = fmaxf(m, v[i]); }
        #pragma unroll
        for (int off = 1; off < 64; off <<= 1) m = fmaxf(m, __shfl_xor(m, off, 64));
        float s = 0.f;
        #pragma unroll
        for (int i = 0; i < 8; i++) { v[i] = __expf(v[i]-m); s += v[i]; }
        #pragma unroll
        for (int off = 1; off < 64; off <<= 1) s += __shfl_xor(s, off, 64);
        const float inv = 1.0f / s;
        #pragma unroll
        for (int i = 0; i < 8; i++) p[r][lane + 64*i] = v[i]*inv;
    }

    float acc[8][4];
    #pragma unroll
    for (int r = 0; r < 8; r++)
        #pragma unroll
        for (int j = 0; j < 4; j++) acc[r][j] = 0.0f;

    for (int m0 = 0; m0 < NN; m0 += 8) {
        __syncthreads();
        #pragma unroll
        for (int mm = 0; mm < 8; mm++)
            if (tid < DH) hv[mm][tid] = Vb[(size_t)(m0+mm)*DH + tid];
        __syncthreads();
        #pragma unroll
        for (int mm = 0; mm < 8; mm++) {
            float hvv[4];
            #pragma unroll
            for (int j = 0; j < 4; j++) {
                const int c = lane + 64*j;
                hvv[j] = (c < DH) ? hv[mm][c] : 0.0f;
            }
            #pragma unroll
            for (int r = 0; r < 8; r++) {
                const float pv = p[wv*8 + r][m0 + mm];
                acc[r][0] += pv*hvv[0];
                acc[r][1] += pv*hvv[1];
                acc[r][2] += pv*hvv[2];
                acc[r][3] += pv*hvv[3];
            }
        }
    }
    #pragma unroll
    for (int r = 0; r < 8; r++)
        #pragma unroll
        for (int j = 0; j < 4; j++) {
            const int c = lane + 64*j;
            if (c < DH)
                out[((size_t)b*NN + row0 + wv*8 + r)*DH + c] = acc[r][j];
        }
}

// ---------------------------------------------------------------------------
// Kernel 5: relu(concat(h,c)@W_down) + degree_table[deg]  -> mean over nodes
// ---------------------------------------------------------------------------
__global__ __launch_bounds__(256) void down_kernel(
    const float* __restrict__ h1, const float* __restrict__ h2,
    const float* __restrict__ c1, const float* __restrict__ c2,
    const int* __restrict__ deg1, const int* __restrict__ deg2,
    const float* __restrict__ W_down, const float* __restrict__ degree_table,
    float* __restrict__ hsg1, float* __restrict__ hsg2)
{
    const int side = blockIdx.y;
    const float* h  = side ? h2 : h1;
    const float* cc = side ? c2 : c1;
    const int*   dg = side ? deg2 : deg1;
    float* hsg = side ? hsg2 : hsg1;

    const int node0 = blockIdx.x * 32;
    const int b = node0 >> 9;

    __shared__ float x[32][404];
    __shared__ float ws[8][DH];
    __shared__ float part[4][DH];
    const int tid = threadIdx.x;

    for (int pass = 0; pass < 13; pass++) {
        const int f = pass*256 + tid;       // f4 index over 32x100
        if (f < 3200) {
            const int r = f / 100, q = f % 100;
            float4 v;
            if (q < 50) v = *(const float4*)&h [(size_t)(node0+r)*DH + 4*q];
            else        v = *(const float4*)&cc[(size_t)(node0+r)*DH + 4*q - DH];
            *(float4*)&x[r][4*q] = v;
        }
    }
    __syncthreads();

    const int wv = tid >> 6, lane = tid & 63;
    float acc[8][4];
    #pragma unroll
    for (int r = 0; r < 8; r++)
        #pragma unroll
        for (int j = 0; j < 4; j++) acc[r][j] = 0.0f;

    for (int k0 = 0; k0 < 400; k0 += 8) {
        __syncthreads();
        #pragma unroll
        for (int kk = 0; kk < 8; kk++)
            if (tid < DH) ws[kk][tid] = W_down[(size_t)(k0+kk)*DH + tid];
        __syncthreads();
        #pragma unroll
        for (int kk = 0; kk < 8; kk++) {
            float wv4[4];
            #pragma unroll
            for (int j = 0; j < 4; j++) {
                const int c = lane + 64*j;
                wv4[j] = (c < DH) ? ws[kk][c] : 0.0f;
            }
            #pragma unroll
            for (int r = 0; r < 8; r++) {
                const float xv = x[wv*8 + r][k0 + kk];
                acc[r][0] += xv*wv4[0];
                acc[r][1] += xv*wv4[1];
                acc[r][2] += xv*wv4[2];
                acc[r][3] += xv*wv4[3];
            }
        }
    }

    #pragma unroll
    for (int j = 0; j < 4; j++) {
        const int c = lane + 64*j;
        if (c < DH) {
            float colsum = 0.0f;
            #pragma unroll
            for (int r = 0; r < 8; r++) {
                int d = dg[node0 + wv*8 + r];
                d = d > 199 ? 199 : d;
                colsum += fmaxf(acc[r][j], 0.0f) + degree_table[d*DH + c];
            }
            part[wv][c] = colsum;
        }
    }
    __syncthreads();
    if (tid < DH) {
        const float tot = part[0][tid]+part[1][tid]+part[2][tid]+part[3][tid];
        unsafeAtomicAdd(&hsg[b*206 + tid], tot * (1.0f/512.0f));
    }
}

// ---------------------------------------------------------------------------
// Kernel 6: interaction mean over nodes -> hsg cols 200..205
// ---------------------------------------------------------------------------
__global__ __launch_bounds__(192) void inter_kernel(
    const float* __restrict__ i1, const float* __restrict__ i2,
    float* __restrict__ hsg1, float* __restrict__ hsg2)
{
    const int side = blockIdx.y;
    const float* it = side ? i2 : i1;
    float* hsg = side ? hsg2 : hsg1;
    const int b = blockIdx.x;
    __shared__ float red[192];
    const int tid = threadIdx.x;
    const int j = tid % 6, seg = tid / 6;   // seg < 32
    float s = 0.0f;
    for (int n = seg*16; n < seg*16 + 16; n++)
        s += it[(size_t)b*NN*DI + n*DI + j];
    red[tid] = s;
    __syncthreads();
    if (tid < 6) {
        float tot = 0.0f;
        for (int sg2 = 0; sg2 < 32; sg2++) tot += red[sg2*6 + tid];
        hsg[b*206 + 200 + tid] = tot * (1.0f/512.0f);
    }
}

// ---------------------------------------------------------------------------
// Kernel 7: final MLP, one block per batch row
// ---------------------------------------------------------------------------
__global__ __launch_bounds__(256) void mlp_kernel(
    const float* __restrict__ hsg1, const float* __restrict__ hsg2,
    const float* __restrict__ W_f1, const float* __restrict__ b_f1,
    const float* __restrict__ W_f2, const float* __restrict__ b_f2,
    const float* __restrict__ W_f3, const float* __restrict__ b_f3,
    const float* __restrict__ W_f4, const float* __restrict__ b_f4,
    float* __restrict__ out)
{
    const int b = blockIdx.x;
    __shared__ float x[618];
    __shared__ float y1[400];
    __shared__ float y2[200];
    __shared__ float y3[100];
    __shared__ float red[256];
    const int tid = threadIdx.x;

    if (tid < 206) {
        const float a = hsg1[b*206 + tid], bb = hsg2[b*206 + tid];
        x[tid] = a; x[206 + tid] = bb; x[412 + tid] = a - bb;
    }
    __syncthreads();
    for (int c = tid; c < 400; c += 256) {
        float acc = b_f1[c];
        for (int k = 0; k < 618; k++) acc += x[k]*W_f1[(size_t)k*400 + c];
        y1[c] = fmaxf(acc, 0.0f);
    }
    __syncthreads();
    if (tid < 200) {
        float acc = b_f2[tid];
        for (int k = 0; k < 400; k++) acc += y1[k]*W_f2[k*200 + tid];
        y2[tid] = fmaxf(acc, 0.0f);
    }
    __syncthreads();
    if (tid < 100) {
        float acc = b_f3[tid];
        for (int k = 0; k < 200; k++) acc += y2[k]*W_f3[k*100 + tid];
        y3[tid] = fmaxf(acc, 0.0f);
    }
    __syncthreads();
    red[tid] = (tid < 100) ? y3[tid]*W_f4[tid] : 0.0f;
    __syncthreads();
    for (int s = 128; s > 0; s >>= 1) {
        if (tid < s) red[tid] += red[tid + s];
        __syncthreads();
    }
    if (tid == 0) out[b] = red[0] + b_f4[0];
}

// ---------------------------------------------------------------------------
extern "C" void kernel_launch(void* const* d_in, const int* in_sizes, int n_in,
                              void* d_out, int out_size, void* d_ws, size_t ws_size,
                              hipStream_t stream)
{
    const float* atom1  = (const float*)d_in[0];
    const float* atom2  = (const float*)d_in[1];
    const float* coords1= (const float*)d_in[2];
    const float* coords2= (const float*)d_in[3];
    const float* efeat1 = (const float*)d_in[4];
    const float* efeat2 = (const float*)d_in[5];
    const float* inter1 = (const float*)d_in[6];
    const float* inter2 = (const float*)d_in[7];
    const int*   esrc1  = (const int*)d_in[8];
    const int*   edst1  = (const int*)d_in[9];
    const int*   esrc2  = (const int*)d_in[10];
    const int*   edst2  = (const int*)d_in[11];
    const float* W_atom = (const float*)d_in[12];
    const float* W_edge = (const float*)d_in[13];
    const float* W_rbf  = (const float*)d_in[14];
    const float* b_rbf  = (const float*)d_in[15];
    const float* ln_g   = (const float*)d_in[16];
    const float* ln_b   = (const float*)d_in[17];
    const float* W_down = (const float*)d_in[18];
    const float* deg_tab= (const float*)d_in[19];
    const float* W_f1   = (const float*)d_in[20];
    const float* b_f1   = (const float*)d_in[21];
    const float* W_f2   = (const float*)d_in[22];
    const float* b_f2   = (const float*)d_in[23];
    const float* W_f3   = (const float*)d_in[24];
    const float* b_f3   = (const float*)d_in[25];
    const float* W_f4   = (const float*)d_in[26];
    const float* b_f4   = (const float*)d_in[27];
    float* out = (float*)d_out;

    // workspace layout (floats)
    float* ws = (float*)d_ws;
    const size_t HSZ = (size_t)BN*DH;          // 6,553,600
    float* h1  = ws;
    float* h2  = h1 + HSZ;
    float* att = h2 + HSZ;                      // B*N*N = 16,777,216
    float* c1  = att + (size_t)BB*NN*NN;
    float* c2  = c1 + HSZ;
    float* hsg1 = c2 + HSZ;                     // 64*206
    float* hsg2 = hsg1 + (size_t)BB*206;
    int* deg1 = (int*)(hsg2 + (size_t)BB*206);
    int* deg2 = deg1 + BN;
    int* start1 = deg2 + BN;
    int* start2 = start1 + BN;
    int* cursor1 = start2 + BN;
    int* cursor2 = cursor1 + BN;
    int* sorted1 = cursor2 + BN;
    int* sorted2 = sorted1 + EE;
    // pre buffers alias att (+ head of c1): dead before att_kernel writes
    float* pre1 = att;
    float* pre2 = att + (size_t)EE*18;

    hipMemsetAsync(deg1, 0, 2*(size_t)BN*sizeof(int), stream);
    hipMemsetAsync(hsg1, 0, 2*(size_t)BB*206*sizeof(float), stream);

    node_kernel<<<dim3(BN/4, 2), 256, 0, stream>>>(
        atom1, atom2, W_atom, ln_g, ln_b, h1, h2);

    hist_kernel<<<EE/256, 256, 0, stream>>>(edst1, edst2, deg1, deg2);
    scan_kernel<<<2, 1024, 0, stream>>>(deg1, deg2, start1, start2, cursor1, cursor2);
    scatter_kernel<<<EE/256, 256, 0, stream>>>(edst1, edst2, cursor1, cursor2, sorted1, sorted2);

    edge_pre_kernel<<<dim3(EE/256, 2), 256, 0, stream>>>(
        efeat1, efeat2, esrc1, esrc2, edst1, edst2, coords1, coords2,
        W_edge, W_rbf, b_rbf, pre1, pre2);

    gather_edge_kernel<<<dim3(BN/4, 2), 256, 0, stream>>>(
        efeat1, efeat2, pre1, pre2,
        sorted1, sorted2, start1, start2, deg1, deg2,
        W_edge, W_rbf, b_rbf, ln_g, ln_b, h1, h2);

    att_kernel<<<dim3(8, 8, BB), 256, 0, stream>>>(h1, h2, att);

    ckern<<<dim3(NN/32, BB), 256, 0, stream>>>(att, h2, c1, 0);
    ckern<<<dim3(NN/32, BB), 256, 0, stream>>>(att, h1, c2, 1);

    down_kernel<<<dim3(BN/32, 2), 256, 0, stream>>>(
        h1, h2, c1, c2, deg1, deg2, W_down, deg_tab, hsg1, hsg2);

    inter_kernel<<<dim3(BB, 2), 192, 0, stream>>>(inter1, inter2, hsg1, hsg2);

    mlp_kernel<<<BB, 256, 0, stream>>>(
        hsg1, hsg2, W_f1, b_f1, W_f2, b_f2, W_f3, b_f3, W_f4, b_f4, out);
}

// Round 6
// 1383.695 us; speedup vs baseline: 2.3400x; 1.1489x over previous
//
#include <hip/hip_runtime.h>
#include <cstddef>
#include <cstdint>

// Problem constants
#define BB   64
#define NN   512
#define BN   (BB*NN)          // 32768
#define EE   524288
#define DA   70
#define DE   14
#define DH   200
#define DI   6
#define T_SCALE 0.07071067811865475f   // sqrt(1/200)

typedef __attribute__((ext_vector_type(8))) short short8;
typedef __attribute__((ext_vector_type(4))) short short4v;
typedef __attribute__((ext_vector_type(4))) float f32x4;

__device__ __forceinline__ short f2bf(float x) {
    union { float f; unsigned u; } v; v.f = x;
    const unsigned r = v.u + 0x7FFFu + ((v.u >> 16) & 1u);   // RNE
    return (short)(r >> 16);
}
__device__ __forceinline__ float bf2f(short s) {
    union { unsigned u; float f; } v;
    v.u = ((unsigned)(unsigned short)s) << 16;
    return v.f;
}

// ---------------------------------------------------------------------------
// Kernel 1: per-node  h = layernorm(relu(atom @ W_atom))
// ---------------------------------------------------------------------------
__global__ __launch_bounds__(256) void node_kernel(
    const float* __restrict__ atom1, const float* __restrict__ atom2,
    const float* __restrict__ W_atom,
    const float* __restrict__ ln_g, const float* __restrict__ ln_b,
    float* __restrict__ h1, float* __restrict__ h2)
{
    const int side = blockIdx.y;
    const float* atom = side ? atom2 : atom1;
    float* h = side ? h2 : h1;
    const int node0 = blockIdx.x * 4;
    const int tid = threadIdx.x;

    __shared__ float arow[4][DA];
    __shared__ float vals[4][DH];

    for (int i = tid; i < 4*DA; i += 256) {
        const int n = i / DA, k = i % DA;
        arow[n][k] = atom[(size_t)(node0+n)*DA + k];
    }
    __syncthreads();

    if (tid < DH) {
        float a0 = 0.f, a1 = 0.f, a2 = 0.f, a3 = 0.f;
        #pragma unroll 7
        for (int k = 0; k < DA; k++) {
            const float w = W_atom[k*DH + tid];
            a0 += arow[0][k]*w; a1 += arow[1][k]*w;
            a2 += arow[2][k]*w; a3 += arow[3][k]*w;
        }
        vals[0][tid] = fmaxf(a0, 0.f);
        vals[1][tid] = fmaxf(a1, 0.f);
        vals[2][tid] = fmaxf(a2, 0.f);
        vals[3][tid] = fmaxf(a3, 0.f);
    }
    __syncthreads();

    const int wv = tid >> 6, lane = tid & 63;
    float v0 = vals[wv][lane];
    float v1 = vals[wv][64+lane];
    float v2 = vals[wv][128+lane];
    float v3 = (lane < 8) ? vals[wv][192+lane] : 0.0f;
    float s  = v0+v1+v2+v3;
    float s2 = v0*v0+v1*v1+v2*v2+v3*v3;
    #pragma unroll
    for (int off = 1; off < 64; off <<= 1) {
        s  += __shfl_xor(s,  off, 64);
        s2 += __shfl_xor(s2, off, 64);
    }
    const float mean = s * (1.0f/DH);
    const float var  = s2 * (1.0f/DH) - mean*mean;
    const float rstd = rsqrtf(var + 1e-5f);
    const size_t base = (size_t)(node0+wv)*DH;
    h[base + lane]       = ln_g[lane]     *(v0-mean)*rstd + ln_b[lane];
    h[base + 64 + lane]  = ln_g[64+lane]  *(v1-mean)*rstd + ln_b[64+lane];
    h[base + 128 + lane] = ln_g[128+lane] *(v2-mean)*rstd + ln_b[128+lane];
    if (lane < 8)
        h[base + 192 + lane] = ln_g[192+lane]*(v3-mean)*rstd + ln_b[192+lane];
}

// ---------------------------------------------------------------------------
// Counting sort by dst: hist -> scan -> scatter
// ---------------------------------------------------------------------------
__global__ __launch_bounds__(256) void hist_kernel(
    const int* __restrict__ edst1, const int* __restrict__ edst2,
    int* __restrict__ deg1, int* __restrict__ deg2)
{
    const int e = blockIdx.x*256 + threadIdx.x;
    atomicAdd(&deg1[edst1[e]], 1);
    atomicAdd(&deg2[edst2[e]], 1);
}

__global__ __launch_bounds__(1024) void scan_kernel(
    const int* __restrict__ deg1, const int* __restrict__ deg2,
    int* __restrict__ start1, int* __restrict__ start2,
    int* __restrict__ cursor1, int* __restrict__ cursor2)
{
    const int side = blockIdx.x;
    const int* deg   = side ? deg2 : deg1;
    int* start  = side ? start2 : start1;
    int* cursor = side ? cursor2 : cursor1;

    __shared__ int part[1024];
    const int t = threadIdx.x;
    const int base = t * 32;
    int local[32];
    int sum = 0;
    #pragma unroll
    for (int i = 0; i < 32; i++) { local[i] = deg[base+i]; sum += local[i]; }
    part[t] = sum;
    __syncthreads();
    for (int off = 1; off < 1024; off <<= 1) {
        int v = (t >= off) ? part[t-off] : 0;
        __syncthreads();
        part[t] += v;
        __syncthreads();
    }
    int run = part[t] - sum;   // exclusive
    #pragma unroll
    for (int i = 0; i < 32; i++) {
        start[base+i] = run;
        cursor[base+i] = run;
        run += local[i];
    }
}

__global__ __launch_bounds__(256) void scatter_kernel(
    const int* __restrict__ edst1, const int* __restrict__ edst2,
    int* __restrict__ cursor1, int* __restrict__ cursor2,
    int* __restrict__ sorted1, int* __restrict__ sorted2)
{
    const int e = blockIdx.x*256 + threadIdx.x;
    {
        const int d = edst1[e];
        const int p = atomicAdd(&cursor1[d], 1);
        sorted1[p] = e;
    }
    {
        const int d = edst2[e];
        const int p = atomicAdd(&cursor2[d], 1);
        sorted2[p] = e;
    }
}

// ---------------------------------------------------------------------------
// Phase 1: per-edge precompute: rbf[16] + LN stats. 18 floats/edge out.
// ---------------------------------------------------------------------------
__global__ __launch_bounds__(256) void edge_pre_kernel(
    const float* __restrict__ efeat1, const float* __restrict__ efeat2,
    const int* __restrict__ esrc1, const int* __restrict__ esrc2,
    const int* __restrict__ edst1, const int* __restrict__ edst2,
    const float* __restrict__ coords1, const float* __restrict__ coords2,
    const float* __restrict__ W_edge, const float* __restrict__ W_rbf,
    const float* __restrict__ b_rbf,
    float* __restrict__ pre1, float* __restrict__ pre2)
{
    const int side = blockIdx.y;
    const float* ef     = side ? efeat2  : efeat1;
    const int*   esrc   = side ? esrc2   : esrc1;
    const int*   edst   = side ? edst2   : edst1;
    const float* coords = side ? coords2 : coords1;
    float* pre = side ? pre2 : pre1;

    __shared__ float WeT[100][16];
    __shared__ float WrT[100][16];
    __shared__ float sbr[100];
    const int tid = threadIdx.x;

    for (int i = tid; i < 1400; i += 256) {
        const int k = i / 100, c = i % 100;
        WeT[c][k] = W_edge[i];
    }
    for (int i = tid; i < 1600; i += 256) {
        const int k = i / 100, c = i % 100;
        WrT[c][k] = W_rbf[i];
    }
    for (int c = tid; c < 100; c += 256) { WeT[c][14] = 0.f; WeT[c][15] = 0.f; }
    if (tid < 100) sbr[tid] = b_rbf[tid];
    __syncthreads();

    const int e = blockIdx.x*256 + tid;
    const int src = esrc[e], dst = edst[e];

    float efr[16];
    #pragma unroll
    for (int k = 0; k < 14; k++) efr[k] = ef[(size_t)e*DE + k];
    efr[14] = 0.f; efr[15] = 0.f;

    const float dx = coords[src*3+0] - coords[dst*3+0];
    const float dy = coords[src*3+1] - coords[dst*3+1];
    const float dz = coords[src*3+2] - coords[dst*3+2];
    const float dist = sqrtf(dx*dx + dy*dy + dz*dz + 1e-12f);

    float rbf[16];
    #pragma unroll
    for (int k = 0; k < 16; k++) {
        const float t = 3.2f*dist - 1.0666666667f*(float)k;
        rbf[k] = __expf(-t*t);
    }

    float s = 0.f, s2 = 0.f;
    for (int c = 0; c < 100; c++) {
        const float4 we0 = *(const float4*)&WeT[c][0];
        const float4 we1 = *(const float4*)&WeT[c][4];
        const float4 we2 = *(const float4*)&WeT[c][8];
        const float4 we3 = *(const float4*)&WeT[c][12];
        float xe = efr[0]*we0.x + efr[1]*we0.y + efr[2]*we0.z + efr[3]*we0.w
                 + efr[4]*we1.x + efr[5]*we1.y + efr[6]*we1.z + efr[7]*we1.w
                 + efr[8]*we2.x + efr[9]*we2.y + efr[10]*we2.z + efr[11]*we2.w
                 + efr[12]*we3.x + efr[13]*we3.y;
        xe = fmaxf(xe, 0.f);
        s += xe; s2 += xe*xe;

        const float4 wr0 = *(const float4*)&WrT[c][0];
        const float4 wr1 = *(const float4*)&WrT[c][4];
        const float4 wr2 = *(const float4*)&WrT[c][8];
        const float4 wr3 = *(const float4*)&WrT[c][12];
        float xr = sbr[c]
                 + rbf[0]*wr0.x + rbf[1]*wr0.y + rbf[2]*wr0.z + rbf[3]*wr0.w
                 + rbf[4]*wr1.x + rbf[5]*wr1.y + rbf[6]*wr1.z + rbf[7]*wr1.w
                 + rbf[8]*wr2.x + rbf[9]*wr2.y + rbf[10]*wr2.z + rbf[11]*wr2.w
                 + rbf[12]*wr3.x + rbf[13]*wr3.y + rbf[14]*wr3.z + rbf[15]*wr3.w;
        xr = fmaxf(xr, 0.f);
        s += xr; s2 += xr*xr;
    }
    const float mean = s * (1.0f/DH);
    const float var  = s2 * (1.0f/DH) - mean*mean;
    const float rstd = rsqrtf(var + 1e-5f);

    float* pe = pre + (size_t)e*18;
    #pragma unroll
    for (int k = 0; k < 16; k += 2) {
        float2 v; v.x = rbf[k]; v.y = rbf[k+1];
        *(float2*)&pe[k] = v;
    }
    float2 st; st.x = mean*rstd; st.y = rstd;
    *(float2*)&pe[16] = st;
}

// ---------------------------------------------------------------------------
// Phase 2: per-node gather. One wave per node.
// ---------------------------------------------------------------------------
__global__ __launch_bounds__(256) void gather_edge_kernel(
    const float* __restrict__ efeat1, const float* __restrict__ efeat2,
    const float* __restrict__ pre1, const float* __restrict__ pre2,
    const int* __restrict__ sorted1, const int* __restrict__ sorted2,
    const int* __restrict__ start1, const int* __restrict__ start2,
    const int* __restrict__ deg1, const int* __restrict__ deg2,
    const float* __restrict__ W_edge, const float* __restrict__ W_rbf,
    const float* __restrict__ b_rbf,
    const float* __restrict__ ln_g, const float* __restrict__ ln_b,
    float* __restrict__ h1, float* __restrict__ h2)
{
    const int side = blockIdx.y;
    const float* ef     = side ? efeat2  : efeat1;
    const float* pre    = side ? pre2    : pre1;
    const int*   sorted = side ? sorted2 : sorted1;
    const int*   start  = side ? start2  : start1;
    const int*   deg    = side ? deg2    : deg1;
    float* h = side ? h2 : h1;

    const int lane = threadIdx.x & 63;
    const int wv = __builtin_amdgcn_readfirstlane(threadIdx.x >> 6);
    const int node = blockIdx.x*4 + wv;

    float wA[14], wB[16], wC[16], wD[16];
    #pragma unroll
    for (int k = 0; k < 14; k++) wA[k] = W_edge[k*100 + lane];
    #pragma unroll
    for (int k = 0; k < 16; k++) wB[k] = W_rbf[k*100 + 28 + lane];
    if (lane < 36) {
        #pragma unroll
        for (int k = 0; k < 14; k++) wC[k] = W_edge[k*100 + 64 + lane];
        #pragma unroll
        for (int k = 14; k < 16; k++) wC[k] = 0.0f;
    } else {
        #pragma unroll
        for (int k = 0; k < 16; k++) wC[k] = W_rbf[k*100 + (lane-36)];
    }
    if (lane < 8) {
        #pragma unroll
        for (int k = 0; k < 16; k++) wD[k] = W_rbf[k*100 + 92 + lane];
    } else {
        #pragma unroll
        for (int k = 0; k < 16; k++) wD[k] = 0.0f;
    }
    const float g0 = ln_g[lane],       bb0 = ln_b[lane];
    const float g1 = ln_g[64+lane],    bb1 = ln_b[64+lane];
    const float g2 = ln_g[128+lane],   bb2 = ln_b[128+lane];
    const float g3 = (lane<8) ? ln_g[192+lane] : 0.0f;
    const float bb3= (lane<8) ? ln_b[192+lane] : 0.0f;
    const float br2 = b_rbf[28+lane];
    const float br1 = (lane >= 36) ? b_rbf[lane-36] : 0.0f;
    const float br3 = (lane < 8)  ? b_rbf[92+lane] : 0.0f;

    const int st = start[node], dg = deg[node];
    const size_t base = (size_t)node * DH;

    const float h0  = h[base + lane];
    const float h1v = h[base + 64 + lane];
    const float h2v = h[base + 128 + lane];
    const float h3v = (lane < 8) ? h[base + 192 + lane] : 0.0f;

    float acc0 = 0.f, acc1 = 0.f, acc2 = 0.f, acc3 = 0.f, musum = 0.f;

    auto do_edge = [&](int eid) {
        const float* pe = pre + (size_t)eid*18;
        float rbf[16];
        #pragma unroll
        for (int k = 0; k < 16; k++) rbf[k] = pe[k];
        const float musrtd = pe[16];
        const float rstd   = pe[17];
        float efr[14];
        #pragma unroll
        for (int k = 0; k < 14; k++) efr[k] = ef[(size_t)eid*DE + k];

        float v0 = 0.f;
        #pragma unroll
        for (int k = 0; k < 14; k++) v0 += efr[k]*wA[k];
        v0 = fmaxf(v0, 0.f);

        float v2 = br2;
        #pragma unroll
        for (int k = 0; k < 16; k++) v2 += rbf[k]*wB[k];
        v2 = fmaxf(v2, 0.f);

        float v1;
        if (lane < 36) {
            v1 = 0.f;
            #pragma unroll
            for (int k = 0; k < 14; k++) v1 += efr[k]*wC[k];
        } else {
            v1 = br1;
            #pragma unroll
            for (int k = 0; k < 16; k++) v1 += rbf[k]*wC[k];
        }
        v1 = fmaxf(v1, 0.f);

        float v3 = br3;
        #pragma unroll
        for (int k = 0; k < 16; k++) v3 += rbf[k]*wD[k];
        v3 = fmaxf(v3, 0.f);

        acc0 += rstd*v0;
        acc1 += rstd*v1;
        acc2 += rstd*v2;
        acc3 += rstd*v3;
        musum += musrtd;
    };

    for (int i = 0; i < dg; i += 2) {
        const bool two = (i+1) < dg;
        const int e0 = sorted[st + i];
        const int e1 = sorted[st + i + (two ? 1 : 0)];
        do_edge(e0);
        if (two) do_edge(e1);
    }

    const float dgf = (float)dg;
    h[base + lane]       = h0  + g0*(acc0 - musum) + dgf*bb0;
    h[base + 64 + lane]  = h1v + g1*(acc1 - musum) + dgf*bb1;
    h[base + 128 + lane] = h2v + g2*(acc2 - musum) + dgf*bb2;
    if (lane < 8)
        h[base + 192 + lane] = h3v + g3*(acc3 - musum) + dgf*bb3;
}

// ---------------------------------------------------------------------------
// cvtT: h fp32 -> transposed split-bf16 V: hbTHI/LO [32][224][512] (half-batch)
// ---------------------------------------------------------------------------
__global__ __launch_bounds__(256) void cvtT_kernel(
    const float* __restrict__ h1, const float* __restrict__ h2, const int half,
    short* __restrict__ hbTHI1, short* __restrict__ hbTLO1,
    short* __restrict__ hbTHI2, short* __restrict__ hbTLO2)
{
    const int side = blockIdx.y;
    const float* h = side ? h2 : h1;
    short* hbTHI = side ? hbTHI2 : hbTHI1;
    short* hbTLO = side ? hbTLO2 : hbTLO1;
    const int bl = blockIdx.x >> 3;          // 0..31 (half-local b)
    const int m0 = (blockIdx.x & 7) * 64;
    const int bg = half*32 + bl;

    __shared__ short tH[64][226];
    __shared__ short tL[64][226];
    const int tid = threadIdx.x;
    for (int i = tid; i < 64*224; i += 256) {
        const int r = i / 224, c = i - r*224;
        const float v = (c < DH) ? h[((size_t)bg*NN + m0 + r)*DH + c] : 0.f;
        const short hi = f2bf(v);
        const short lo = f2bf(v - bf2f(hi));
        tH[r][c] = hi; tL[r][c] = lo;
    }
    __syncthreads();
    for (int i = tid; i < 224*64; i += 256) {
        const int c = i >> 6, m = i & 63;
        const size_t o = ((size_t)bl*224 + c)*NN + m0 + m;
        hbTHI[o] = tH[m][c];
        hbTLO[o] = tL[m][c];
    }
}

// ---------------------------------------------------------------------------
// prep_w: W_down[400][200] -> WbTHI/LO[208][448] (transposed, padded, split)
// ---------------------------------------------------------------------------
__global__ __launch_bounds__(256) void prep_w_kernel(
    const float* __restrict__ W_down,
    short* __restrict__ WbTHI, short* __restrict__ WbTLO)
{
    const int idx = blockIdx.x*256 + threadIdx.x;
    if (idx >= 208*448) return;
    const int c = idx / 448, kk = idx - c*448;
    float v = 0.f;
    if (c < 200) {
        if (kk < 200) v = W_down[(size_t)kk*DH + c];
        else if (kk >= 224 && kk < 424) v = W_down[(size_t)(200 + kk - 224)*DH + c];
    }
    const short hi = f2bf(v);
    WbTHI[idx] = hi;
    WbTLO[idx] = f2bf(v - bf2f(hi));
}

// ---------------------------------------------------------------------------
// Kernel 3: att[b] = (h1[b] @ h2[b]^T) * T_SCALE  (fp32, half-batch output)
// ---------------------------------------------------------------------------
__global__ __launch_bounds__(256) void att_kernel(
    const float* __restrict__ h1, const float* __restrict__ h2,
    float* __restrict__ att, const int half)
{
    const int bl = blockIdx.z;
    const int bg = half*32 + bl;
    const int row0 = blockIdx.y * 64, col0 = blockIdx.x * 64;
    const float* A  = h1 + (size_t)bg*NN*DH;
    const float* Bm = h2 + (size_t)bg*NN*DH;

    __shared__ float Ast[8][68];
    __shared__ float Bst[8][68];
    const int tid = threadIdx.x;
    const int tx = tid & 15, ty = tid >> 4;
    const int lr = tid >> 2, lk = (tid & 3)*2;

    float acc[4][4];
    #pragma unroll
    for (int i = 0; i < 4; i++)
        #pragma unroll
        for (int j = 0; j < 4; j++) acc[i][j] = 0.f;

    for (int k0 = 0; k0 < DH; k0 += 8) {
        const float2 av = *(const float2*)&A [(size_t)(row0+lr)*DH + k0 + lk];
        const float2 bv = *(const float2*)&Bm[(size_t)(col0+lr)*DH + k0 + lk];
        __syncthreads();
        Ast[lk][lr] = av.x; Ast[lk+1][lr] = av.y;
        Bst[lk][lr] = bv.x; Bst[lk+1][lr] = bv.y;
        __syncthreads();
        #pragma unroll
        for (int kk = 0; kk < 8; kk++) {
            const float4 a4 = *(const float4*)&Ast[kk][ty*4];
            const float4 b4 = *(const float4*)&Bst[kk][tx*4];
            acc[0][0] += a4.x*b4.x; acc[0][1] += a4.x*b4.y; acc[0][2] += a4.x*b4.z; acc[0][3] += a4.x*b4.w;
            acc[1][0] += a4.y*b4.x; acc[1][1] += a4.y*b4.y; acc[1][2] += a4.y*b4.z; acc[1][3] += a4.y*b4.w;
            acc[2][0] += a4.z*b4.x; acc[2][1] += a4.z*b4.y; acc[2][2] += a4.z*b4.z; acc[2][3] += a4.z*b4.w;
            acc[3][0] += a4.w*b4.x; acc[3][1] += a4.w*b4.y; acc[3][2] += a4.w*b4.z; acc[3][3] += a4.w*b4.w;
        }
    }
    const size_t base = (size_t)bl*NN*NN;
    #pragma unroll
    for (int i = 0; i < 4; i++) {
        float4 o;
        o.x = acc[i][0]*T_SCALE; o.y = acc[i][1]*T_SCALE;
        o.z = acc[i][2]*T_SCALE; o.w = acc[i][3]*T_SCALE;
        *(float4*)&att[base + (size_t)(row0+ty*4+i)*NN + col0 + tx*4] = o;
    }
}

// ---------------------------------------------------------------------------
// Kernel 4 (MFMA, split-V): softmax(att rows/cols) @ (Vhi+Vlo) -> c fp32
// Block = 16 output rows; waves split 13 N-tiles {4,3,3,3}.
// ---------------------------------------------------------------------------
template<int TRANS>
__global__ __launch_bounds__(256) void ckern_mfma(
    const float* __restrict__ att,
    const short* __restrict__ vTHI, const short* __restrict__ vTLO,
    float* __restrict__ cout, const int half)
{
    const int bl = blockIdx.y;                   // half-local b
    const int bg = half*32 + bl;
    const int row0 = blockIdx.x * 16;
    const float* attb = att + (size_t)bl*NN*NN;
    const short* vHI = vTHI + (size_t)bl*224*NN; // [224][512]
    const short* vLO = vTLO + (size_t)bl*224*NN;

    __shared__ float pmem[16*512];               // fp32 staging (TRANS=1); pb aliases
    __shared__ short BsH[208][40];
    __shared__ short BsL[208][40];
    short* pb = (short*)pmem;                    // bf16 probs [16][528]

    const int tid = threadIdx.x;
    const int wv = tid >> 6, lane = tid & 63;

    float vv[4][8];
    if (TRANS) {
        #pragma unroll
        for (int pass = 0; pass < 8; pass++) {
            const int f = pass*256 + tid;        // 2048
            const int k = f >> 2, r4 = f & 3;
            const float4 v = *(const float4*)&attb[(size_t)k*NN + row0 + 4*r4];
            pmem[(4*r4+0)*512 + k] = v.x;
            pmem[(4*r4+1)*512 + k] = v.y;
            pmem[(4*r4+2)*512 + k] = v.z;
            pmem[(4*r4+3)*512 + k] = v.w;
        }
        __syncthreads();
    }

    #pragma unroll
    for (int rr = 0; rr < 4; rr++) {
        const int r = 4*wv + rr;
        float m = -1e30f;
        #pragma unroll
        for (int i = 0; i < 8; i++) {
            vv[rr][i] = TRANS ? pmem[r*512 + lane + 64*i]
                              : attb[(size_t)(row0+r)*NN + lane + 64*i];
            m = fmaxf(m, vv[rr][i]);
        }
        #pragma unroll
        for (int off = 1; off < 64; off <<= 1) m = fmaxf(m, __shfl_xor(m, off, 64));
        float s = 0.f;
        #pragma unroll
        for (int i = 0; i < 8; i++) { vv[rr][i] = __expf(vv[rr][i]-m); s += vv[rr][i]; }
        #pragma unroll
        for (int off = 1; off < 64; off <<= 1) s += __shfl_xor(s, off, 64);
        const float inv = 1.0f / s;
        #pragma unroll
        for (int i = 0; i < 8; i++) vv[rr][i] *= inv;
    }
    __syncthreads();   // pmem consumed; safe to overwrite with pb
    #pragma unroll
    for (int rr = 0; rr < 4; rr++) {
        const int r = 4*wv + rr;
        #pragma unroll
        for (int i = 0; i < 8; i++) pb[r*528 + lane + 64*i] = f2bf(vv[rr][i]);
    }

    const int ntbase = (wv == 0) ? 0 : 3*wv + 1;
    const int ntcnt  = (wv == 0) ? 4 : 3;
    f32x4 acc[4];
    #pragma unroll
    for (int t = 0; t < 4; t++) acc[t] = (f32x4){0.f,0.f,0.f,0.f};

    const int arow = lane & 15, aq = lane >> 4;
    for (int k0 = 0; k0 < NN; k0 += 32) {
        __syncthreads();
        #pragma unroll
        for (int pass = 0; pass < 4; pass++) {
            const int f = pass*256 + tid;
            if (f < 832) {
                const int d = f >> 2, cc = f & 3;
                *(float4*)&BsH[d][8*cc] = *(const float4*)&vHI[(size_t)d*NN + k0 + 8*cc];
                *(float4*)&BsL[d][8*cc] = *(const float4*)&vLO[(size_t)d*NN + k0 + 8*cc];
            }
        }
        __syncthreads();
        const short8 a = *(const short8*)&pb[arow*528 + k0 + aq*8];
        #pragma unroll
        for (int t = 0; t < 4; t++) {
            if (t < ntcnt) {
                const int nt = ntbase + t;
                const short8 bh = *(const short8*)&BsH[nt*16 + arow][aq*8];
                const short8 bl_ = *(const short8*)&BsL[nt*16 + arow][aq*8];
                acc[t] = __builtin_amdgcn_mfma_f32_16x16x32_bf16(a, bh, acc[t], 0, 0, 0);
                acc[t] = __builtin_amdgcn_mfma_f32_16x16x32_bf16(a, bl_, acc[t], 0, 0, 0);
            }
        }
    }

    #pragma unroll
    for (int t = 0; t < 4; t++) {
        if (t < ntcnt) {
            const int nt = ntbase + t;
            const int col = nt*16 + arow;
            #pragma unroll
            for (int r = 0; r < 4; r++) {
                const int row = row0 + aq*4 + r;
                if (col < DH)
                    cout[((size_t)bg*NN + row)*DH + col] = acc[t][r];
            }
        }
    }
}

// ---------------------------------------------------------------------------
// Kernel 5 (MFMA, split-W): relu([h|c] @ W_down) + degree_table -> mean -> hsg
// X read from fp32, converted hi in-kernel. acc = Xhi@Whi + Xhi@Wlo.
// ---------------------------------------------------------------------------
__global__ __launch_bounds__(256) void down_mfma(
    const float* __restrict__ h1, const float* __restrict__ h2,
    const float* __restrict__ c1, const float* __restrict__ c2,
    const int* __restrict__ deg1, const int* __restrict__ deg2,
    const short* __restrict__ WbTHI, const short* __restrict__ WbTLO,
    const float* __restrict__ degree_table,
    float* __restrict__ hsg1, float* __restrict__ hsg2)
{
    const int side = blockIdx.y;
    const float* X0 = side ? h2 : h1;
    const float* X1 = side ? c2 : c1;
    const int*   dgp = side ? deg2 : deg1;
    float* hsg = side ? hsg2 : hsg1;

    const int node0 = blockIdx.x * 64;
    const int b = node0 >> 9;

    __shared__ short As[64][40];
    __shared__ short BsH[208][40];
    __shared__ short BsL[208][40];
    __shared__ float part[208];

    const int tid = threadIdx.x;
    const int wv = tid >> 6, lane = tid & 63;
    const int arow = lane & 15, aq = lane >> 4;

    if (tid < 208) part[tid] = 0.f;

    f32x4 acc[13];
    #pragma unroll
    for (int t = 0; t < 13; t++) acc[t] = (f32x4){0.f,0.f,0.f,0.f};

    for (int phase = 0; phase < 2; phase++) {
        const float* X = phase ? X1 : X0;
        for (int k0 = 0; k0 < 224; k0 += 32) {
            __syncthreads();
            // A stage: 64 rows x 32 k (fp32 -> bf16 hi), 512 float4 slots
            #pragma unroll
            for (int pass = 0; pass < 2; pass++) {
                const int f = pass*256 + tid;
                const int r = f >> 3, ch = f & 7;
                const int k = k0 + 4*ch;
                short4v hv;
                if (k < DH) {
                    const float4 v = *(const float4*)&X[(size_t)(node0+r)*DH + k];
                    hv.x = f2bf(v.x); hv.y = f2bf(v.y);
                    hv.z = f2bf(v.z); hv.w = f2bf(v.w);
                } else {
                    hv = (short4v){0,0,0,0};
                }
                *(short4v*)&As[r][4*ch] = hv;
            }
            const int kkg = phase*224 + k0;
            #pragma unroll
            for (int pass = 0; pass < 4; pass++) {
                const int f = pass*256 + tid;
                if (f < 832) {
                    const int d = f >> 2, cc = f & 3;
                    *(float4*)&BsH[d][8*cc] = *(const float4*)&WbTHI[(size_t)d*448 + kkg + 8*cc];
                    *(float4*)&BsL[d][8*cc] = *(const float4*)&WbTLO[(size_t)d*448 + kkg + 8*cc];
                }
            }
            __syncthreads();
            const short8 a = *(const short8*)&As[16*wv + arow][aq*8];
            #pragma unroll
            for (int t = 0; t < 13; t++) {
                const short8 bh = *(const short8*)&BsH[t*16 + arow][aq*8];
                const short8 bl_ = *(const short8*)&BsL[t*16 + arow][aq*8];
                acc[t] = __builtin_amdgcn_mfma_f32_16x16x32_bf16(a, bh, acc[t], 0, 0, 0);
                acc[t] = __builtin_amdgcn_mfma_f32_16x16x32_bf16(a, bl_, acc[t], 0, 0, 0);
            }
        }
    }
    __syncthreads();

    int dgc[4];
    #pragma unroll
    for (int r = 0; r < 4; r++) {
        int d = dgp[node0 + 16*wv + aq*4 + r];
        dgc[r] = d > 199 ? 199 : d;
    }
    #pragma unroll
    for (int nt = 0; nt < 13; nt++) {
        const int col = nt*16 + arow;
        float s = 0.f;
        if (col < DH) {
            #pragma unroll
            for (int r = 0; r < 4; r++)
                s += fmaxf(acc[nt][r], 0.f) + degree_table[dgc[r]*DH + col];
        }
        s += __shfl_xor(s, 16, 64);
        s += __shfl_xor(s, 32, 64);
        if (lane < 16 && col < DH) atomicAdd(&part[col], s);
    }
    __syncthreads();
    if (tid < DH) unsafeAtomicAdd(&hsg[b*206 + tid], part[tid] * (1.0f/512.0f));
}

// ---------------------------------------------------------------------------
// Kernel 6: interaction mean over nodes -> hsg cols 200..205
// ---------------------------------------------------------------------------
__global__ __launch_bounds__(192) void inter_kernel(
    const float* __restrict__ i1, const float* __restrict__ i2,
    float* __restrict__ hsg1, float* __restrict__ hsg2)
{
    const int side = blockIdx.y;
    const float* it = side ? i2 : i1;
    float* hsg = side ? hsg2 : hsg1;
    const int b = blockIdx.x;
    __shared__ float red[192];
    const int tid = threadIdx.x;
    const int j = tid % 6, seg = tid / 6;
    float s = 0.0f;
    for (int n = seg*16; n < seg*16 + 16; n++)
        s += it[(size_t)b*NN*DI + n*DI + j];
    red[tid] = s;
    __syncthreads();
    if (tid < 6) {
        float tot = 0.0f;
        for (int sg2 = 0; sg2 < 32; sg2++) tot += red[sg2*6 + tid];
        hsg[b*206 + 200 + tid] = tot * (1.0f/512.0f);
    }
}

// ---------------------------------------------------------------------------
// Kernel 7: final MLP, one block per batch row
// ---------------------------------------------------------------------------
__global__ __launch_bounds__(256) void mlp_kernel(
    const float* __restrict__ hsg1, const float* __restrict__ hsg2,
    const float* __restrict__ W_f1, const float* __restrict__ b_f1,
    const float* __restrict__ W_f2, const float* __restrict__ b_f2,
    const float* __restrict__ W_f3, const float* __restrict__ b_f3,
    const float* __restrict__ W_f4, const float* __restrict__ b_f4,
    float* __restrict__ out)
{
    const int b = blockIdx.x;
    __shared__ float x[618];
    __shared__ float y1[400];
    __shared__ float y2[200];
    __shared__ float y3[100];
    __shared__ float red[256];
    const int tid = threadIdx.x;

    if (tid < 206) {
        const float a = hsg1[b*206 + tid], bb = hsg2[b*206 + tid];
        x[tid] = a; x[206 + tid] = bb; x[412 + tid] = a - bb;
    }
    __syncthreads();
    for (int c = tid; c < 400; c += 256) {
        float acc = b_f1[c];
        for (int k = 0; k < 618; k++) acc += x[k]*W_f1[(size_t)k*400 + c];
        y1[c] = fmaxf(acc, 0.0f);
    }
    __syncthreads();
    if (tid < 200) {
        float acc = b_f2[tid];
        for (int k = 0; k < 400; k++) acc += y1[k]*W_f2[k*200 + tid];
        y2[tid] = fmaxf(acc, 0.0f);
    }
    __syncthreads();
    if (tid < 100) {
        float acc = b_f3[tid];
        for (int k = 0; k < 200; k++) acc += y2[k]*W_f3[k*100 + tid];
        y3[tid] = fmaxf(acc, 0.0f);
    }
    __syncthreads();
    red[tid] = (tid < 100) ? y3[tid]*W_f4[tid] : 0.0f;
    __syncthreads();
    for (int s = 128; s > 0; s >>= 1) {
        if (tid < s) red[tid] += red[tid + s];
        __syncthreads();
    }
    if (tid == 0) out[b] = red[0] + b_f4[0];
}

// ---------------------------------------------------------------------------
extern "C" void kernel_launch(void* const* d_in, const int* in_sizes, int n_in,
                              void* d_out, int out_size, void* d_ws, size_t ws_size,
                              hipStream_t stream)
{
    const float* atom1  = (const float*)d_in[0];
    const float* atom2  = (const float*)d_in[1];
    const float* coords1= (const float*)d_in[2];
    const float* coords2= (const float*)d_in[3];
    const float* efeat1 = (const float*)d_in[4];
    const float* efeat2 = (const float*)d_in[5];
    const float* inter1 = (const float*)d_in[6];
    const float* inter2 = (const float*)d_in[7];
    const int*   esrc1  = (const int*)d_in[8];
    const int*   edst1  = (const int*)d_in[9];
    const int*   esrc2  = (const int*)d_in[10];
    const int*   edst2  = (const int*)d_in[11];
    const float* W_atom = (const float*)d_in[12];
    const float* W_edge = (const float*)d_in[13];
    const float* W_rbf  = (const float*)d_in[14];
    const float* b_rbf  = (const float*)d_in[15];
    const float* ln_g   = (const float*)d_in[16];
    const float* ln_b   = (const float*)d_in[17];
    const float* W_down = (const float*)d_in[18];
    const float* deg_tab= (const float*)d_in[19];
    const float* W_f1   = (const float*)d_in[20];
    const float* b_f1   = (const float*)d_in[21];
    const float* W_f2   = (const float*)d_in[22];
    const float* b_f2   = (const float*)d_in[23];
    const float* W_f3   = (const float*)d_in[24];
    const float* b_f3   = (const float*)d_in[25];
    const float* W_f4   = (const float*)d_in[26];
    const float* b_f4   = (const float*)d_in[27];
    float* out = (float*)d_out;

    // workspace layout (bytes tight; total ~173 MB, <= known-safe 183 MB)
    float* ws = (float*)d_ws;
    const size_t HSZ = (size_t)BN*DH;              // 6,553,600 floats
    const size_t HBT = (size_t)32*224*NN;          // 3,670,016 shorts per buffer
    float* h1  = ws;                               // HSZ
    float* h2  = h1 + HSZ;                         // HSZ
    float* att = h2 + HSZ;                         // 32*NN*NN fp32 (half-batch)
    short* hbTHI1 = (short*)(att + (size_t)32*NN*NN);
    short* hbTLO1 = hbTHI1 + HBT;
    short* hbTHI2 = hbTLO1 + HBT;
    short* hbTLO2 = hbTHI2 + HBT;
    float* c1 = (float*)(hbTLO2 + HBT);            // HSZ fp32
    float* c2 = c1 + HSZ;                          // HSZ fp32
    short* WbTHI = (short*)(c2 + HSZ);             // 208*448
    short* WbTLO = WbTHI + 208*448;
    float* hsg1 = (float*)(WbTLO + 208*448);
    float* hsg2 = hsg1 + (size_t)BB*206;
    int* deg1 = (int*)(hsg2 + (size_t)BB*206);
    int* deg2 = deg1 + BN;
    int* start1 = deg2 + BN;
    int* start2 = start1 + BN;
    int* cursor1 = start2 + BN;
    int* cursor2 = cursor1 + BN;
    int* sorted1 = cursor2 + BN;
    int* sorted2 = sorted1 + EE;
    // pre (2 x EE x 18 fp32 = 75.5 MB) aliases att+hbT+head-of-c1 (all dead
    // until after gather consumes pre)
    float* pre1 = att;
    float* pre2 = att + (size_t)EE*18;

    hipMemsetAsync(deg1, 0, 2*(size_t)BN*sizeof(int), stream);
    hipMemsetAsync(hsg1, 0, 2*(size_t)BB*206*sizeof(float), stream);

    node_kernel<<<dim3(BN/4, 2), 256, 0, stream>>>(
        atom1, atom2, W_atom, ln_g, ln_b, h1, h2);

    hist_kernel<<<EE/256, 256, 0, stream>>>(edst1, edst2, deg1, deg2);
    scan_kernel<<<2, 1024, 0, stream>>>(deg1, deg2, start1, start2, cursor1, cursor2);
    scatter_kernel<<<EE/256, 256, 0, stream>>>(edst1, edst2, cursor1, cursor2, sorted1, sorted2);

    edge_pre_kernel<<<dim3(EE/256, 2), 256, 0, stream>>>(
        efeat1, efeat2, esrc1, esrc2, edst1, edst2, coords1, coords2,
        W_edge, W_rbf, b_rbf, pre1, pre2);

    gather_edge_kernel<<<dim3(BN/4, 2), 256, 0, stream>>>(
        efeat1, efeat2, pre1, pre2,
        sorted1, sorted2, start1, start2, deg1, deg2,
        W_edge, W_rbf, b_rbf, ln_g, ln_b, h1, h2);

    prep_w_kernel<<<(208*448 + 255)/256, 256, 0, stream>>>(W_down, WbTHI, WbTLO);

    for (int half = 0; half < 2; half++) {
        cvtT_kernel<<<dim3(256, 2), 256, 0, stream>>>(
            h1, h2, half, hbTHI1, hbTLO1, hbTHI2, hbTLO2);
        att_kernel<<<dim3(8, 8, 32), 256, 0, stream>>>(h1, h2, att, half);
        ckern_mfma<0><<<dim3(NN/16, 32), 256, 0, stream>>>(att, hbTHI2, hbTLO2, c1, half);
        ckern_mfma<1><<<dim3(NN/16, 32), 256, 0, stream>>>(att, hbTHI1, hbTLO1, c2, half);
    }

    down_mfma<<<dim3(BN/64, 2), 256, 0, stream>>>(
        h1, h2, c1, c2, deg1, deg2, WbTHI, WbTLO, deg_tab, hsg1, hsg2);

    inter_kernel<<<dim3(BB, 2), 192, 0, stream>>>(inter1, inter2, hsg1, hsg2);

    mlp_kernel<<<BB, 256, 0, stream>>>(
        hsg1, hsg2, W_f1, b_f1, W_f2, b_f2, W_f3, b_f3, W_f4, b_f4, out);
}

// Round 7
// 1351.603 us; speedup vs baseline: 2.3955x; 1.0237x over previous
//
#include <hip/hip_runtime.h>
#include <cstddef>
#include <cstdint>

// Problem constants
#define BB   64
#define NN   512
#define BN   (BB*NN)          // 32768
#define HBN  16384            // nodes per half
#define EE   524288
#define DA   70
#define DE   14
#define DH   200
#define DI   6
#define T_SCALE 0.07071067811865475f   // sqrt(1/200)

typedef __attribute__((ext_vector_type(8))) short short8;
typedef __attribute__((ext_vector_type(4))) float f32x4;

__device__ __forceinline__ short f2bf(float x) {
    union { float f; unsigned u; } v; v.f = x;
    const unsigned r = v.u + 0x7FFFu + ((v.u >> 16) & 1u);   // RNE
    return (short)(r >> 16);
}
__device__ __forceinline__ float bf2f(short s) {
    union { unsigned u; float f; } v;
    v.u = ((unsigned)(unsigned short)s) << 16;
    return v.f;
}

// ---------------------------------------------------------------------------
// Kernel 1: per-node  h = layernorm(relu(atom @ W_atom))
// ---------------------------------------------------------------------------
__global__ __launch_bounds__(256) void node_kernel(
    const float* __restrict__ atom1, const float* __restrict__ atom2,
    const float* __restrict__ W_atom,
    const float* __restrict__ ln_g, const float* __restrict__ ln_b,
    float* __restrict__ h1, float* __restrict__ h2)
{
    const int side = blockIdx.y;
    const float* atom = side ? atom2 : atom1;
    float* h = side ? h2 : h1;
    const int node0 = blockIdx.x * 4;
    const int tid = threadIdx.x;

    __shared__ float arow[4][DA];
    __shared__ float vals[4][DH];

    for (int i = tid; i < 4*DA; i += 256) {
        const int n = i / DA, k = i % DA;
        arow[n][k] = atom[(size_t)(node0+n)*DA + k];
    }
    __syncthreads();

    if (tid < DH) {
        float a0 = 0.f, a1 = 0.f, a2 = 0.f, a3 = 0.f;
        #pragma unroll 7
        for (int k = 0; k < DA; k++) {
            const float w = W_atom[k*DH + tid];
            a0 += arow[0][k]*w; a1 += arow[1][k]*w;
            a2 += arow[2][k]*w; a3 += arow[3][k]*w;
        }
        vals[0][tid] = fmaxf(a0, 0.f);
        vals[1][tid] = fmaxf(a1, 0.f);
        vals[2][tid] = fmaxf(a2, 0.f);
        vals[3][tid] = fmaxf(a3, 0.f);
    }
    __syncthreads();

    const int wv = tid >> 6, lane = tid & 63;
    float v0 = vals[wv][lane];
    float v1 = vals[wv][64+lane];
    float v2 = vals[wv][128+lane];
    float v3 = (lane < 8) ? vals[wv][192+lane] : 0.0f;
    float s  = v0+v1+v2+v3;
    float s2 = v0*v0+v1*v1+v2*v2+v3*v3;
    #pragma unroll
    for (int off = 1; off < 64; off <<= 1) {
        s  += __shfl_xor(s,  off, 64);
        s2 += __shfl_xor(s2, off, 64);
    }
    const float mean = s * (1.0f/DH);
    const float var  = s2 * (1.0f/DH) - mean*mean;
    const float rstd = rsqrtf(var + 1e-5f);
    const size_t base = (size_t)(node0+wv)*DH;
    h[base + lane]       = ln_g[lane]     *(v0-mean)*rstd + ln_b[lane];
    h[base + 64 + lane]  = ln_g[64+lane]  *(v1-mean)*rstd + ln_b[64+lane];
    h[base + 128 + lane] = ln_g[128+lane] *(v2-mean)*rstd + ln_b[128+lane];
    if (lane < 8)
        h[base + 192 + lane] = ln_g[192+lane]*(v3-mean)*rstd + ln_b[192+lane];
}

// ---------------------------------------------------------------------------
// Counting sort by dst: hist -> scan -> scatter (+rank)
// ---------------------------------------------------------------------------
__global__ __launch_bounds__(256) void hist_kernel(
    const int* __restrict__ edst1, const int* __restrict__ edst2,
    int* __restrict__ deg1, int* __restrict__ deg2)
{
    const int e = blockIdx.x*256 + threadIdx.x;
    atomicAdd(&deg1[edst1[e]], 1);
    atomicAdd(&deg2[edst2[e]], 1);
}

__global__ __launch_bounds__(1024) void scan_kernel(
    const int* __restrict__ deg1, const int* __restrict__ deg2,
    int* __restrict__ start1, int* __restrict__ start2,
    int* __restrict__ cursor1, int* __restrict__ cursor2)
{
    const int side = blockIdx.x;
    const int* deg   = side ? deg2 : deg1;
    int* start  = side ? start2 : start1;
    int* cursor = side ? cursor2 : cursor1;

    __shared__ int part[1024];
    const int t = threadIdx.x;
    const int base = t * 32;
    int local[32];
    int sum = 0;
    #pragma unroll
    for (int i = 0; i < 32; i++) { local[i] = deg[base+i]; sum += local[i]; }
    part[t] = sum;
    __syncthreads();
    for (int off = 1; off < 1024; off <<= 1) {
        int v = (t >= off) ? part[t-off] : 0;
        __syncthreads();
        part[t] += v;
        __syncthreads();
    }
    int run = part[t] - sum;   // exclusive
    #pragma unroll
    for (int i = 0; i < 32; i++) {
        start[base+i] = run;
        cursor[base+i] = run;
        run += local[i];
    }
}

__global__ __launch_bounds__(256) void scatter_kernel(
    const int* __restrict__ edst1, const int* __restrict__ edst2,
    int* __restrict__ cursor1, int* __restrict__ cursor2,
    int* __restrict__ sorted1, int* __restrict__ sorted2,
    int* __restrict__ rank1, int* __restrict__ rank2)
{
    const int e = blockIdx.x*256 + threadIdx.x;
    {
        const int d = edst1[e];
        const int p = atomicAdd(&cursor1[d], 1);
        sorted1[p] = e;
        rank1[e] = p;
    }
    {
        const int d = edst2[e];
        const int p = atomicAdd(&cursor2[d], 1);
        sorted2[p] = e;
        rank2[e] = p;
    }
}

// ---------------------------------------------------------------------------
// Phase 1: per-edge precompute: rbf[16] + LN stats -> pre[rank[e]] (20 floats)
// ---------------------------------------------------------------------------
__global__ __launch_bounds__(256) void edge_pre_kernel(
    const float* __restrict__ efeat1, const float* __restrict__ efeat2,
    const int* __restrict__ esrc1, const int* __restrict__ esrc2,
    const int* __restrict__ edst1, const int* __restrict__ edst2,
    const float* __restrict__ coords1, const float* __restrict__ coords2,
    const int* __restrict__ rank1, const int* __restrict__ rank2,
    const float* __restrict__ W_edge, const float* __restrict__ W_rbf,
    const float* __restrict__ b_rbf,
    float* __restrict__ pre1, float* __restrict__ pre2)
{
    const int side = blockIdx.y;
    const float* ef     = side ? efeat2  : efeat1;
    const int*   esrc   = side ? esrc2   : esrc1;
    const int*   edst   = side ? edst2   : edst1;
    const float* coords = side ? coords2 : coords1;
    const int*   rank   = side ? rank2   : rank1;
    float* pre = side ? pre2 : pre1;

    __shared__ float WeT[100][16];
    __shared__ float WrT[100][16];
    __shared__ float sbr[100];
    const int tid = threadIdx.x;

    for (int i = tid; i < 1400; i += 256) {
        const int k = i / 100, c = i % 100;
        WeT[c][k] = W_edge[i];
    }
    for (int i = tid; i < 1600; i += 256) {
        const int k = i / 100, c = i % 100;
        WrT[c][k] = W_rbf[i];
    }
    for (int c = tid; c < 100; c += 256) { WeT[c][14] = 0.f; WeT[c][15] = 0.f; }
    if (tid < 100) sbr[tid] = b_rbf[tid];
    __syncthreads();

    const int e = blockIdx.x*256 + tid;
    const int src = esrc[e], dst = edst[e];

    float efr[16];
    #pragma unroll
    for (int k = 0; k < 14; k++) efr[k] = ef[(size_t)e*DE + k];
    efr[14] = 0.f; efr[15] = 0.f;

    const float dx = coords[src*3+0] - coords[dst*3+0];
    const float dy = coords[src*3+1] - coords[dst*3+1];
    const float dz = coords[src*3+2] - coords[dst*3+2];
    const float dist = sqrtf(dx*dx + dy*dy + dz*dz + 1e-12f);

    float rbf[16];
    #pragma unroll
    for (int k = 0; k < 16; k++) {
        const float t = 3.2f*dist - 1.0666666667f*(float)k;
        rbf[k] = __expf(-t*t);
    }

    float s = 0.f, s2 = 0.f;
    for (int c = 0; c < 100; c++) {
        const float4 we0 = *(const float4*)&WeT[c][0];
        const float4 we1 = *(const float4*)&WeT[c][4];
        const float4 we2 = *(const float4*)&WeT[c][8];
        const float4 we3 = *(const float4*)&WeT[c][12];
        float xe = efr[0]*we0.x + efr[1]*we0.y + efr[2]*we0.z + efr[3]*we0.w
                 + efr[4]*we1.x + efr[5]*we1.y + efr[6]*we1.z + efr[7]*we1.w
                 + efr[8]*we2.x + efr[9]*we2.y + efr[10]*we2.z + efr[11]*we2.w
                 + efr[12]*we3.x + efr[13]*we3.y;
        xe = fmaxf(xe, 0.f);
        s += xe; s2 += xe*xe;

        const float4 wr0 = *(const float4*)&WrT[c][0];
        const float4 wr1 = *(const float4*)&WrT[c][4];
        const float4 wr2 = *(const float4*)&WrT[c][8];
        const float4 wr3 = *(const float4*)&WrT[c][12];
        float xr = sbr[c]
                 + rbf[0]*wr0.x + rbf[1]*wr0.y + rbf[2]*wr0.z + rbf[3]*wr0.w
                 + rbf[4]*wr1.x + rbf[5]*wr1.y + rbf[6]*wr1.z + rbf[7]*wr1.w
                 + rbf[8]*wr2.x + rbf[9]*wr2.y + rbf[10]*wr2.z + rbf[11]*wr2.w
                 + rbf[12]*wr3.x + rbf[13]*wr3.y + rbf[14]*wr3.z + rbf[15]*wr3.w;
        xr = fmaxf(xr, 0.f);
        s += xr; s2 += xr*xr;
    }
    const float mean = s * (1.0f/DH);
    const float var  = s2 * (1.0f/DH) - mean*mean;
    const float rstd = rsqrtf(var + 1e-5f);

    float* pe = pre + (size_t)rank[e]*20;
    #pragma unroll
    for (int k = 0; k < 16; k += 4) {
        float4 v; v.x = rbf[k]; v.y = rbf[k+1]; v.z = rbf[k+2]; v.w = rbf[k+3];
        *(float4*)&pe[k] = v;
    }
    float2 st; st.x = mean*rstd; st.y = rstd;
    *(float2*)&pe[16] = st;
}

// ---------------------------------------------------------------------------
// Phase 2: per-node gather. One wave per node. pre is rank-ordered ->
// sequential reads per node segment.
// ---------------------------------------------------------------------------
__global__ __launch_bounds__(256) void gather_edge_kernel(
    const float* __restrict__ efeat1, const float* __restrict__ efeat2,
    const float* __restrict__ pre1, const float* __restrict__ pre2,
    const int* __restrict__ sorted1, const int* __restrict__ sorted2,
    const int* __restrict__ start1, const int* __restrict__ start2,
    const int* __restrict__ deg1, const int* __restrict__ deg2,
    const float* __restrict__ W_edge, const float* __restrict__ W_rbf,
    const float* __restrict__ b_rbf,
    const float* __restrict__ ln_g, const float* __restrict__ ln_b,
    float* __restrict__ h1, float* __restrict__ h2)
{
    const int side = blockIdx.y;
    const float* ef     = side ? efeat2  : efeat1;
    const float* pre    = side ? pre2    : pre1;
    const int*   sorted = side ? sorted2 : sorted1;
    const int*   start  = side ? start2  : start1;
    const int*   deg    = side ? deg2    : deg1;
    float* h = side ? h2 : h1;

    const int lane = threadIdx.x & 63;
    const int wv = __builtin_amdgcn_readfirstlane(threadIdx.x >> 6);
    const int node = blockIdx.x*4 + wv;

    float wA[14], wB[16], wC[16], wD[16];
    #pragma unroll
    for (int k = 0; k < 14; k++) wA[k] = W_edge[k*100 + lane];
    #pragma unroll
    for (int k = 0; k < 16; k++) wB[k] = W_rbf[k*100 + 28 + lane];
    if (lane < 36) {
        #pragma unroll
        for (int k = 0; k < 14; k++) wC[k] = W_edge[k*100 + 64 + lane];
        #pragma unroll
        for (int k = 14; k < 16; k++) wC[k] = 0.0f;
    } else {
        #pragma unroll
        for (int k = 0; k < 16; k++) wC[k] = W_rbf[k*100 + (lane-36)];
    }
    if (lane < 8) {
        #pragma unroll
        for (int k = 0; k < 16; k++) wD[k] = W_rbf[k*100 + 92 + lane];
    } else {
        #pragma unroll
        for (int k = 0; k < 16; k++) wD[k] = 0.0f;
    }
    const float g0 = ln_g[lane],       bb0 = ln_b[lane];
    const float g1 = ln_g[64+lane],    bb1 = ln_b[64+lane];
    const float g2 = ln_g[128+lane],   bb2 = ln_b[128+lane];
    const float g3 = (lane<8) ? ln_g[192+lane] : 0.0f;
    const float bb3= (lane<8) ? ln_b[192+lane] : 0.0f;
    const float br2 = b_rbf[28+lane];
    const float br1 = (lane >= 36) ? b_rbf[lane-36] : 0.0f;
    const float br3 = (lane < 8)  ? b_rbf[92+lane] : 0.0f;

    const int st = start[node], dg = deg[node];
    const size_t base = (size_t)node * DH;

    const float h0  = h[base + lane];
    const float h1v = h[base + 64 + lane];
    const float h2v = h[base + 128 + lane];
    const float h3v = (lane < 8) ? h[base + 192 + lane] : 0.0f;

    float acc0 = 0.f, acc1 = 0.f, acc2 = 0.f, acc3 = 0.f, musum = 0.f;

    auto do_edge = [&](int pos, int eid) {
        const float* pe = pre + (size_t)pos*20;
        float rbf[16];
        #pragma unroll
        for (int k = 0; k < 16; k++) rbf[k] = pe[k];
        const float musrtd = pe[16];
        const float rstd   = pe[17];
        float efr[14];
        #pragma unroll
        for (int k = 0; k < 14; k++) efr[k] = ef[(size_t)eid*DE + k];

        float v0 = 0.f;
        #pragma unroll
        for (int k = 0; k < 14; k++) v0 += efr[k]*wA[k];
        v0 = fmaxf(v0, 0.f);

        float v2 = br2;
        #pragma unroll
        for (int k = 0; k < 16; k++) v2 += rbf[k]*wB[k];
        v2 = fmaxf(v2, 0.f);

        float v1;
        if (lane < 36) {
            v1 = 0.f;
            #pragma unroll
            for (int k = 0; k < 14; k++) v1 += efr[k]*wC[k];
        } else {
            v1 = br1;
            #pragma unroll
            for (int k = 0; k < 16; k++) v1 += rbf[k]*wC[k];
        }
        v1 = fmaxf(v1, 0.f);

        float v3 = br3;
        #pragma unroll
        for (int k = 0; k < 16; k++) v3 += rbf[k]*wD[k];
        v3 = fmaxf(v3, 0.f);

        acc0 += rstd*v0;
        acc1 += rstd*v1;
        acc2 += rstd*v2;
        acc3 += rstd*v3;
        musum += musrtd;
    };

    for (int i = 0; i < dg; i += 2) {
        const bool two = (i+1) < dg;
        const int e0 = sorted[st + i];
        const int e1 = sorted[st + i + (two ? 1 : 0)];
        do_edge(st + i, e0);
        if (two) do_edge(st + i + 1, e1);
    }

    const float dgf = (float)dg;
    h[base + lane]       = h0  + g0*(acc0 - musum) + dgf*bb0;
    h[base + 64 + lane]  = h1v + g1*(acc1 - musum) + dgf*bb1;
    h[base + 128 + lane] = h2v + g2*(acc2 - musum) + dgf*bb2;
    if (lane < 8)
        h[base + 192 + lane] = h3v + g3*(acc3 - musum) + dgf*bb3;
}

// ---------------------------------------------------------------------------
// cvt (per half): h fp32 -> hb hi/lo [16384][224] rows + hbT hi/lo [32][224][512]
// ---------------------------------------------------------------------------
__global__ __launch_bounds__(256) void cvt_kernel(
    const float* __restrict__ h1, const float* __restrict__ h2, const int half,
    short* __restrict__ hbH1, short* __restrict__ hbL1,
    short* __restrict__ hbH2, short* __restrict__ hbL2,
    short* __restrict__ hTH1, short* __restrict__ hTL1,
    short* __restrict__ hTH2, short* __restrict__ hTL2)
{
    const int side = blockIdx.y;
    const float* h = side ? h2 : h1;
    short* hbH = side ? hbH2 : hbH1;
    short* hbL = side ? hbL2 : hbL1;
    short* hTH = side ? hTH2 : hTH1;
    short* hTL = side ? hTL2 : hTL1;

    const int nl0 = blockIdx.x * 64;          // local node
    const int bl = nl0 >> 9, m0 = nl0 & 511;
    const int ng0 = half*HBN + nl0;

    __shared__ short tH[64][226];
    __shared__ short tL[64][226];
    const int tid = threadIdx.x;
    for (int i = tid; i < 64*224; i += 256) {
        const int r = i / 224, c = i - r*224;
        const float v = (c < DH) ? h[(size_t)(ng0+r)*DH + c] : 0.f;
        const short hi = f2bf(v);
        const short lo = f2bf(v - bf2f(hi));
        tH[r][c] = hi; tL[r][c] = lo;
        hbH[(size_t)(nl0+r)*224 + c] = hi;
        hbL[(size_t)(nl0+r)*224 + c] = lo;
    }
    __syncthreads();
    for (int i = tid; i < 224*64; i += 256) {
        const int c = i >> 6, m = i & 63;
        const size_t o = ((size_t)bl*224 + c)*NN + m0 + m;
        hTH[o] = tH[m][c];
        hTL[o] = tL[m][c];
    }
}

// ---------------------------------------------------------------------------
// prep_w: W_down[400][200] -> WbTHI/LO[208][448] (transposed, padded, split)
// ---------------------------------------------------------------------------
__global__ __launch_bounds__(256) void prep_w_kernel(
    const float* __restrict__ W_down,
    short* __restrict__ WbTHI, short* __restrict__ WbTLO)
{
    const int idx = blockIdx.x*256 + threadIdx.x;
    if (idx >= 208*448) return;
    const int c = idx / 448, kk = idx - c*448;
    float v = 0.f;
    if (c < 200) {
        if (kk < 200) v = W_down[(size_t)kk*DH + c];
        else if (kk >= 224 && kk < 424) v = W_down[(size_t)(200 + kk - 224)*DH + c];
    }
    const short hi = f2bf(v);
    WbTHI[idx] = hi;
    WbTLO[idx] = f2bf(v - bf2f(hi));
}

// ---------------------------------------------------------------------------
// Fused attention (per half, per direction):
//   logits = (Q@K^T)*T_SCALE (split bf16: hh+hl+lh), row-softmax, P@(Vhi+Vlo)
// Block: 32 Q-rows, one b. 4 waves: (mt = wave&1 -> 16-row M-tile,
// ch = wave>>1 -> col half for QK / N-tile half for PV).
// Q,K from row-major hb (hi/lo); V from transposed hbT (hi/lo). Out: cb bf16.
// ---------------------------------------------------------------------------
__global__ __launch_bounds__(256) void attn_kernel(
    const short* __restrict__ QH, const short* __restrict__ QL,
    const short* __restrict__ KH, const short* __restrict__ KL,
    const short* __restrict__ VTH, const short* __restrict__ VTL,
    short* __restrict__ cb)
{
    const int b = blockIdx.y;                 // half-local batch
    const int q0 = blockIdx.x * 32;
    const short* Qh = QH + (size_t)b*NN*224;
    const short* Ql = QL + (size_t)b*NN*224;
    const short* Kh = KH + (size_t)b*NN*224;
    const short* Kl = KL + (size_t)b*NN*224;
    const short* Vh = VTH + (size_t)b*224*NN;
    const short* Vl = VTL + (size_t)b*224*NN;

    __shared__ short smem[29696];             // 59.4 KB, multi-use
    __shared__ float sm_[2][2][16];
    __shared__ float ss_[2][2][16];

    short* AqH = smem;                        // [32][232]
    short* AqL = AqH + 32*232;
    short* KsH = AqL + 32*232;
    short* KsL = KsH + 32*232;                // end 29696
    short* pb  = smem;                        // [32][520] = 16640 (aliases Aq/Ks)
    short* Vs  = smem + 16640;                // [208][40] = 8320

    const int tid = threadIdx.x;
    const int wv = tid >> 6, lane = tid & 63;
    const int arow = lane & 15, aq = lane >> 4;
    const int mt = wv & 1, ch = wv >> 1;

    // stage Q rows (hi+lo)
    for (int f = tid; f < 896; f += 256) {
        const int r = f / 28, c = (f % 28) * 8;
        *(short8*)&AqH[r*232 + c] = *(const short8*)&Qh[(size_t)(q0+r)*224 + c];
        *(short8*)&AqL[r*232 + c] = *(const short8*)&Ql[(size_t)(q0+r)*224 + c];
    }

    f32x4 acc[16];
    #pragma unroll
    for (int t = 0; t < 16; t++) acc[t] = (f32x4){0.f,0.f,0.f,0.f};

    const int abase = (mt*16 + arow)*232 + aq*8;
    const int bbase = (ch*16 + arow)*232 + aq*8;

    #pragma unroll
    for (int ct = 0; ct < 16; ct++) {
        __syncthreads();
        for (int f = tid; f < 896; f += 256) {
            const int r = f / 28, c = (f % 28) * 8;
            *(short8*)&KsH[r*232 + c] = *(const short8*)&Kh[(size_t)(ct*32+r)*224 + c];
            *(short8*)&KsL[r*232 + c] = *(const short8*)&Kl[(size_t)(ct*32+r)*224 + c];
        }
        __syncthreads();
        #pragma unroll
        for (int k0 = 0; k0 < 224; k0 += 32) {
            const short8 ah = *(const short8*)&AqH[abase + k0];
            const short8 al = *(const short8*)&AqL[abase + k0];
            const short8 bh = *(const short8*)&KsH[bbase + k0];
            const short8 bl = *(const short8*)&KsL[bbase + k0];
            acc[ct] = __builtin_amdgcn_mfma_f32_16x16x32_bf16(ah, bh, acc[ct], 0, 0, 0);
            acc[ct] = __builtin_amdgcn_mfma_f32_16x16x32_bf16(ah, bl, acc[ct], 0, 0, 0);
            acc[ct] = __builtin_amdgcn_mfma_f32_16x16x32_bf16(al, bh, acc[ct], 0, 0, 0);
        }
    }

    // softmax: lane holds rows {aq*4+r | r<4} (in M-tile mt), cols {ct*32+ch*16+arow}
    float mr[4], sr[4], iv[4];
    #pragma unroll
    for (int r = 0; r < 4; r++) {
        float m = -1e30f;
        #pragma unroll
        for (int ct = 0; ct < 16; ct++) {
            acc[ct][r] *= T_SCALE;
            m = fmaxf(m, acc[ct][r]);
        }
        m = fmaxf(m, __shfl_xor(m, 1, 64));
        m = fmaxf(m, __shfl_xor(m, 2, 64));
        m = fmaxf(m, __shfl_xor(m, 4, 64));
        m = fmaxf(m, __shfl_xor(m, 8, 64));
        mr[r] = m;
    }
    if (arow == 0) {
        #pragma unroll
        for (int r = 0; r < 4; r++) sm_[mt][ch][aq*4+r] = mr[r];
    }
    __syncthreads();
    #pragma unroll
    for (int r = 0; r < 4; r++) {
        const float M = fmaxf(mr[r], sm_[mt][1-ch][aq*4+r]);
        float s = 0.f;
        #pragma unroll
        for (int ct = 0; ct < 16; ct++) {
            const float e = __expf(acc[ct][r] - M);
            acc[ct][r] = e;
            s += e;
        }
        s += __shfl_xor(s, 1, 64);
        s += __shfl_xor(s, 2, 64);
        s += __shfl_xor(s, 4, 64);
        s += __shfl_xor(s, 8, 64);
        sr[r] = s;
    }
    if (arow == 0) {
        #pragma unroll
        for (int r = 0; r < 4; r++) ss_[mt][ch][aq*4+r] = sr[r];
    }
    __syncthreads();
    #pragma unroll
    for (int r = 0; r < 4; r++)
        iv[r] = 1.0f / (sr[r] + ss_[mt][1-ch][aq*4+r]);

    // write P bf16 to pb (Aq/Ks dead)
    #pragma unroll
    for (int ct = 0; ct < 16; ct++) {
        const int col = ct*32 + ch*16 + arow;
        #pragma unroll
        for (int r = 0; r < 4; r++)
            pb[(mt*16 + aq*4 + r)*520 + col] = f2bf(acc[ct][r] * iv[r]);
    }

    // PV: two passes (V-hi then V-lo), N-tiles split 7/6 across ch
    const int nbase = ch ? 7 : 0;
    const int ncnt  = ch ? 6 : 7;
    f32x4 pacc[7];
    #pragma unroll
    for (int t = 0; t < 7; t++) pacc[t] = (f32x4){0.f,0.f,0.f,0.f};

    for (int pass = 0; pass < 2; pass++) {
        const short* Vp = pass ? Vl : Vh;
        for (int k0 = 0; k0 < NN; k0 += 32) {
            __syncthreads();
            for (int f = tid; f < 832; f += 256) {
                const int fe = f >> 2, cq = (f & 3) * 8;
                *(short8*)&Vs[fe*40 + cq] = *(const short8*)&Vp[(size_t)fe*NN + k0 + cq];
            }
            __syncthreads();
            const short8 a = *(const short8*)&pb[(mt*16 + arow)*520 + k0 + aq*8];
            #pragma unroll
            for (int t = 0; t < 7; t++) {
                if (t < ncnt) {
                    const int nt = nbase + t;
                    const short8 bf = *(const short8*)&Vs[(nt*16 + arow)*40 + aq*8];
                    pacc[t] = __builtin_amdgcn_mfma_f32_16x16x32_bf16(a, bf, pacc[t], 0, 0, 0);
                }
            }
        }
    }

    // epilogue: cb bf16, pad cols [200,224) with zeros
    #pragma unroll
    for (int t = 0; t < 7; t++) {
        if (t < ncnt) {
            const int nt = nbase + t;
            const int col = nt*16 + arow;
            #pragma unroll
            for (int r = 0; r < 4; r++) {
                const int row = q0 + mt*16 + aq*4 + r;
                const short v = (col < DH) ? f2bf(pacc[t][r]) : (short)0;
                cb[((size_t)b*NN + row)*224 + col] = v;
            }
        }
    }
    if (ch) {
        const int col = 208 + arow;
        #pragma unroll
        for (int r = 0; r < 4; r++) {
            const int row = q0 + mt*16 + aq*4 + r;
            cb[((size_t)b*NN + row)*224 + col] = 0;
        }
    }
}

// ---------------------------------------------------------------------------
// down (per half, MFMA, split-W): relu([hb|cb] @ W_down) + degree_table -> hsg
// ---------------------------------------------------------------------------
__global__ __launch_bounds__(256) void down_mfma(
    const short* __restrict__ hbH1, const short* __restrict__ hbH2,
    const short* __restrict__ cb1, const short* __restrict__ cb2,
    const int* __restrict__ deg1, const int* __restrict__ deg2,
    const short* __restrict__ WbTH, const short* __restrict__ WbTL,
    const float* __restrict__ degree_table,
    float* __restrict__ hsg1, float* __restrict__ hsg2, const int half)
{
    const int side = blockIdx.y;
    const short* X0 = side ? hbH2 : hbH1;
    const short* X1 = side ? cb2 : cb1;
    const int*   dgp = side ? deg2 : deg1;
    float* hsg = side ? hsg2 : hsg1;

    const int nl0 = blockIdx.x * 64;
    const int ng0 = half*HBN + nl0;
    const int b = ng0 >> 9;

    __shared__ short As[64*40];
    __shared__ short BsH[208*40];
    __shared__ short BsL[208*40];
    __shared__ float part[208];

    const int tid = threadIdx.x;
    const int wv = tid >> 6, lane = tid & 63;
    const int arow = lane & 15, aq = lane >> 4;

    if (tid < 208) part[tid] = 0.f;

    f32x4 acc[13];
    #pragma unroll
    for (int t = 0; t < 13; t++) acc[t] = (f32x4){0.f,0.f,0.f,0.f};

    const int sr = tid >> 2, sc = (tid & 3) * 8;

    for (int phase = 0; phase < 2; phase++) {
        const short* X = phase ? X1 : X0;
        for (int k0 = 0; k0 < 224; k0 += 32) {
            __syncthreads();
            *(short8*)&As[sr*40 + sc] =
                *(const short8*)&X[(size_t)(nl0+sr)*224 + k0 + sc];
            const int kkg = phase*224 + k0;
            #pragma unroll
            for (int pass = 0; pass < 4; pass++) {
                const int f = pass*256 + tid;
                if (f < 832) {
                    const int d = f >> 2, cc = (f & 3) * 8;
                    *(short8*)&BsH[d*40 + cc] = *(const short8*)&WbTH[(size_t)d*448 + kkg + cc];
                    *(short8*)&BsL[d*40 + cc] = *(const short8*)&WbTL[(size_t)d*448 + kkg + cc];
                }
            }
            __syncthreads();
            const short8 a = *(const short8*)&As[(16*wv + arow)*40 + aq*8];
            #pragma unroll
            for (int t = 0; t < 13; t++) {
                const short8 bh = *(const short8*)&BsH[(t*16 + arow)*40 + aq*8];
                const short8 bl = *(const short8*)&BsL[(t*16 + arow)*40 + aq*8];
                acc[t] = __builtin_amdgcn_mfma_f32_16x16x32_bf16(a, bh, acc[t], 0, 0, 0);
                acc[t] = __builtin_amdgcn_mfma_f32_16x16x32_bf16(a, bl, acc[t], 0, 0, 0);
            }
        }
    }
    __syncthreads();

    int dgc[4];
    #pragma unroll
    for (int r = 0; r < 4; r++) {
        int d = dgp[ng0 + 16*wv + aq*4 + r];
        dgc[r] = d > 199 ? 199 : d;
    }
    #pragma unroll
    for (int nt = 0; nt < 13; nt++) {
        const int col = nt*16 + arow;
        float s = 0.f;
        if (col < DH) {
            #pragma unroll
            for (int r = 0; r < 4; r++)
                s += fmaxf(acc[nt][r], 0.f) + degree_table[dgc[r]*DH + col];
        }
        s += __shfl_xor(s, 16, 64);
        s += __shfl_xor(s, 32, 64);
        if (lane < 16 && col < DH) atomicAdd(&part[col], s);
    }
    __syncthreads();
    if (tid < DH) unsafeAtomicAdd(&hsg[b*206 + tid], part[tid] * (1.0f/512.0f));
}

// ---------------------------------------------------------------------------
// Kernel 6: interaction mean over nodes -> hsg cols 200..205
// ---------------------------------------------------------------------------
__global__ __launch_bounds__(192) void inter_kernel(
    const float* __restrict__ i1, const float* __restrict__ i2,
    float* __restrict__ hsg1, float* __restrict__ hsg2)
{
    const int side = blockIdx.y;
    const float* it = side ? i2 : i1;
    float* hsg = side ? hsg2 : hsg1;
    const int b = blockIdx.x;
    __shared__ float red[192];
    const int tid = threadIdx.x;
    const int j = tid % 6, seg = tid / 6;
    float s = 0.0f;
    for (int n = seg*16; n < seg*16 + 16; n++)
        s += it[(size_t)b*NN*DI + n*DI + j];
    red[tid] = s;
    __syncthreads();
    if (tid < 6) {
        float tot = 0.0f;
        for (int sg2 = 0; sg2 < 32; sg2++) tot += red[sg2*6 + tid];
        hsg[b*206 + 200 + tid] = tot * (1.0f/512.0f);
    }
}

// ---------------------------------------------------------------------------
// Kernel 7: final MLP, one block per batch row
// ---------------------------------------------------------------------------
__global__ __launch_bounds__(256) void mlp_kernel(
    const float* __restrict__ hsg1, const float* __restrict__ hsg2,
    const float* __restrict__ W_f1, const float* __restrict__ b_f1,
    const float* __restrict__ W_f2, const float* __restrict__ b_f2,
    const float* __restrict__ W_f3, const float* __restrict__ b_f3,
    const float* __restrict__ W_f4, const float* __restrict__ b_f4,
    float* __restrict__ out)
{
    const int b = blockIdx.x;
    __shared__ float x[618];
    __shared__ float y1[400];
    __shared__ float y2[200];
    __shared__ float y3[100];
    __shared__ float red[256];
    const int tid = threadIdx.x;

    if (tid < 206) {
        const float a = hsg1[b*206 + tid], bb = hsg2[b*206 + tid];
        x[tid] = a; x[206 + tid] = bb; x[412 + tid] = a - bb;
    }
    __syncthreads();
    for (int c = tid; c < 400; c += 256) {
        float acc = b_f1[c];
        for (int k = 0; k < 618; k++) acc += x[k]*W_f1[(size_t)k*400 + c];
        y1[c] = fmaxf(acc, 0.0f);
    }
    __syncthreads();
    if (tid < 200) {
        float acc = b_f2[tid];
        for (int k = 0; k < 400; k++) acc += y1[k]*W_f2[k*200 + tid];
        y2[tid] = fmaxf(acc, 0.0f);
    }
    __syncthreads();
    if (tid < 100) {
        float acc = b_f3[tid];
        for (int k = 0; k < 200; k++) acc += y2[k]*W_f3[k*100 + tid];
        y3[tid] = fmaxf(acc, 0.0f);
    }
    __syncthreads();
    red[tid] = (tid < 100) ? y3[tid]*W_f4[tid] : 0.0f;
    __syncthreads();
    for (int s = 128; s > 0; s >>= 1) {
        if (tid < s) red[tid] += red[tid + s];
        __syncthreads();
    }
    if (tid == 0) out[b] = red[0] + b_f4[0];
}

// ---------------------------------------------------------------------------
extern "C" void kernel_launch(void* const* d_in, const int* in_sizes, int n_in,
                              void* d_out, int out_size, void* d_ws, size_t ws_size,
                              hipStream_t stream)
{
    const float* atom1  = (const float*)d_in[0];
    const float* atom2  = (const float*)d_in[1];
    const float* coords1= (const float*)d_in[2];
    const float* coords2= (const float*)d_in[3];
    const float* efeat1 = (const float*)d_in[4];
    const float* efeat2 = (const float*)d_in[5];
    const float* inter1 = (const float*)d_in[6];
    const float* inter2 = (const float*)d_in[7];
    const int*   esrc1  = (const int*)d_in[8];
    const int*   edst1  = (const int*)d_in[9];
    const int*   esrc2  = (const int*)d_in[10];
    const int*   edst2  = (const int*)d_in[11];
    const float* W_atom = (const float*)d_in[12];
    const float* W_edge = (const float*)d_in[13];
    const float* W_rbf  = (const float*)d_in[14];
    const float* b_rbf  = (const float*)d_in[15];
    const float* ln_g   = (const float*)d_in[16];
    const float* ln_b   = (const float*)d_in[17];
    const float* W_down = (const float*)d_in[18];
    const float* deg_tab= (const float*)d_in[19];
    const float* W_f1   = (const float*)d_in[20];
    const float* b_f1   = (const float*)d_in[21];
    const float* W_f2   = (const float*)d_in[22];
    const float* b_f2   = (const float*)d_in[23];
    const float* W_f3   = (const float*)d_in[24];
    const float* b_f3   = (const float*)d_in[25];
    const float* W_f4   = (const float*)d_in[26];
    const float* b_f4   = (const float*)d_in[27];
    float* out = (float*)d_out;

    // ---- workspace layout (~146 MB)
    float* ws = (float*)d_ws;
    const size_t HSZ = (size_t)BN*DH;              // per-side h floats
    float* h1  = ws;
    float* h2  = h1 + HSZ;
    // pool region: max(pre 2*EE*20 floats = 83.9MB, bf16 pool 73.4MB)
    float* poolf = h2 + HSZ;
    const size_t PRESZ = (size_t)EE*20;
    float* pre1 = poolf;
    float* pre2 = pre1 + PRESZ;
    short* pool = (short*)poolf;
    const size_t HB = (size_t)32*NN*224;           // 3,670,016 shorts
    short* hbH1 = pool;           short* hbL1 = hbH1 + HB;
    short* hbH2 = hbL1 + HB;      short* hbL2 = hbH2 + HB;
    short* hTH1 = hbL2 + HB;      short* hTL1 = hTH1 + HB;
    short* hTH2 = hTL1 + HB;      short* hTL2 = hTH2 + HB;
    short* cb1  = hTL2 + HB;      short* cb2  = cb1 + HB;
    float* after = poolf + 2*PRESZ;
    short* WbTH = (short*)after;
    short* WbTL = WbTH + 208*448;
    float* hsg1 = (float*)(WbTL + 208*448);
    float* hsg2 = hsg1 + (size_t)BB*206;
    int* deg1 = (int*)(hsg2 + (size_t)BB*206);
    int* deg2 = deg1 + BN;
    int* start1 = deg2 + BN;
    int* start2 = start1 + BN;
    int* cursor1 = start2 + BN;
    int* cursor2 = cursor1 + BN;
    int* sorted1 = cursor2 + BN;
    int* sorted2 = sorted1 + EE;
    int* rank1 = sorted2 + EE;
    int* rank2 = rank1 + EE;

    hipMemsetAsync(deg1, 0, 2*(size_t)BN*sizeof(int), stream);
    hipMemsetAsync(hsg1, 0, 2*(size_t)BB*206*sizeof(float), stream);

    node_kernel<<<dim3(BN/4, 2), 256, 0, stream>>>(
        atom1, atom2, W_atom, ln_g, ln_b, h1, h2);

    hist_kernel<<<EE/256, 256, 0, stream>>>(edst1, edst2, deg1, deg2);
    scan_kernel<<<2, 1024, 0, stream>>>(deg1, deg2, start1, start2, cursor1, cursor2);
    scatter_kernel<<<EE/256, 256, 0, stream>>>(edst1, edst2, cursor1, cursor2,
                                               sorted1, sorted2, rank1, rank2);

    edge_pre_kernel<<<dim3(EE/256, 2), 256, 0, stream>>>(
        efeat1, efeat2, esrc1, esrc2, edst1, edst2, coords1, coords2,
        rank1, rank2, W_edge, W_rbf, b_rbf, pre1, pre2);

    gather_edge_kernel<<<dim3(BN/4, 2), 256, 0, stream>>>(
        efeat1, efeat2, pre1, pre2,
        sorted1, sorted2, start1, start2, deg1, deg2,
        W_edge, W_rbf, b_rbf, ln_g, ln_b, h1, h2);

    prep_w_kernel<<<(208*448 + 255)/256, 256, 0, stream>>>(W_down, WbTH, WbTL);

    for (int half = 0; half < 2; half++) {
        cvt_kernel<<<dim3(HBN/64, 2), 256, 0, stream>>>(
            h1, h2, half, hbH1, hbL1, hbH2, hbL2, hTH1, hTL1, hTH2, hTL2);
        // dir0: c1 = softmax_rows(h1@h2^T) @ h2
        attn_kernel<<<dim3(16, 32), 256, 0, stream>>>(
            hbH1, hbL1, hbH2, hbL2, hTH2, hTL2, cb1);
        // dir1: c2 = softmax_rows(h2@h1^T) @ h1   (== column softmax of att)
        attn_kernel<<<dim3(16, 32), 256, 0, stream>>>(
            hbH2, hbL2, hbH1, hbL1, hTH1, hTL1, cb2);
        down_mfma<<<dim3(HBN/64, 2), 256, 0, stream>>>(
            hbH1, hbH2, cb1, cb2, deg1, deg2, WbTH, WbTL, deg_tab,
            hsg1, hsg2, half);
    }

    inter_kernel<<<dim3(BB, 2), 192, 0, stream>>>(inter1, inter2, hsg1, hsg2);

    mlp_kernel<<<BB, 256, 0, stream>>>(
        hsg1, hsg2, W_f1, b_f1, W_f2, b_f2, W_f3, b_f3, W_f4, b_f4, out);
}

// Round 8
// 1339.703 us; speedup vs baseline: 2.4168x; 1.0089x over previous
//
#include <hip/hip_runtime.h>
#include <cstddef>
#include <cstdint>

// Problem constants
#define BB   64
#define NN   512
#define BN   (BB*NN)          // 32768
#define HBN  16384            // nodes per half
#define EE   524288
#define DA   70
#define DE   14
#define DH   200
#define DI   6
#define T_SCALE 0.07071067811865475f   // sqrt(1/200)

typedef __attribute__((ext_vector_type(8))) short short8;
typedef __attribute__((ext_vector_type(4))) float f32x4;

__device__ __forceinline__ short f2bf(float x) {
    union { float f; unsigned u; } v; v.f = x;
    const unsigned r = v.u + 0x7FFFu + ((v.u >> 16) & 1u);   // RNE
    return (short)(r >> 16);
}
__device__ __forceinline__ float bf2f(short s) {
    union { unsigned u; float f; } v;
    v.u = ((unsigned)(unsigned short)s) << 16;
    return v.f;
}

// ---------------------------------------------------------------------------
// Kernel 1: per-node  h = layernorm(relu(atom @ W_atom))
// ---------------------------------------------------------------------------
__global__ __launch_bounds__(256) void node_kernel(
    const float* __restrict__ atom1, const float* __restrict__ atom2,
    const float* __restrict__ W_atom,
    const float* __restrict__ ln_g, const float* __restrict__ ln_b,
    float* __restrict__ h1, float* __restrict__ h2)
{
    const int side = blockIdx.y;
    const float* atom = side ? atom2 : atom1;
    float* h = side ? h2 : h1;
    const int node0 = blockIdx.x * 4;
    const int tid = threadIdx.x;

    __shared__ float arow[4][DA];
    __shared__ float vals[4][DH];

    for (int i = tid; i < 4*DA; i += 256) {
        const int n = i / DA, k = i % DA;
        arow[n][k] = atom[(size_t)(node0+n)*DA + k];
    }
    __syncthreads();

    if (tid < DH) {
        float a0 = 0.f, a1 = 0.f, a2 = 0.f, a3 = 0.f;
        #pragma unroll 7
        for (int k = 0; k < DA; k++) {
            const float w = W_atom[k*DH + tid];
            a0 += arow[0][k]*w; a1 += arow[1][k]*w;
            a2 += arow[2][k]*w; a3 += arow[3][k]*w;
        }
        vals[0][tid] = fmaxf(a0, 0.f);
        vals[1][tid] = fmaxf(a1, 0.f);
        vals[2][tid] = fmaxf(a2, 0.f);
        vals[3][tid] = fmaxf(a3, 0.f);
    }
    __syncthreads();

    const int wv = tid >> 6, lane = tid & 63;
    float v0 = vals[wv][lane];
    float v1 = vals[wv][64+lane];
    float v2 = vals[wv][128+lane];
    float v3 = (lane < 8) ? vals[wv][192+lane] : 0.0f;
    float s  = v0+v1+v2+v3;
    float s2 = v0*v0+v1*v1+v2*v2+v3*v3;
    #pragma unroll
    for (int off = 1; off < 64; off <<= 1) {
        s  += __shfl_xor(s,  off, 64);
        s2 += __shfl_xor(s2, off, 64);
    }
    const float mean = s * (1.0f/DH);
    const float var  = s2 * (1.0f/DH) - mean*mean;
    const float rstd = rsqrtf(var + 1e-5f);
    const size_t base = (size_t)(node0+wv)*DH;
    h[base + lane]       = ln_g[lane]     *(v0-mean)*rstd + ln_b[lane];
    h[base + 64 + lane]  = ln_g[64+lane]  *(v1-mean)*rstd + ln_b[64+lane];
    h[base + 128 + lane] = ln_g[128+lane] *(v2-mean)*rstd + ln_b[128+lane];
    if (lane < 8)
        h[base + 192 + lane] = ln_g[192+lane]*(v3-mean)*rstd + ln_b[192+lane];
}

// ---------------------------------------------------------------------------
// Counting sort by dst: hist -> scan -> scatter (+rank)
// ---------------------------------------------------------------------------
__global__ __launch_bounds__(256) void hist_kernel(
    const int* __restrict__ edst1, const int* __restrict__ edst2,
    int* __restrict__ deg1, int* __restrict__ deg2)
{
    const int e = blockIdx.x*256 + threadIdx.x;
    atomicAdd(&deg1[edst1[e]], 1);
    atomicAdd(&deg2[edst2[e]], 1);
}

__global__ __launch_bounds__(1024) void scan_kernel(
    const int* __restrict__ deg1, const int* __restrict__ deg2,
    int* __restrict__ start1, int* __restrict__ start2,
    int* __restrict__ cursor1, int* __restrict__ cursor2)
{
    const int side = blockIdx.x;
    const int* deg   = side ? deg2 : deg1;
    int* start  = side ? start2 : start1;
    int* cursor = side ? cursor2 : cursor1;

    __shared__ int part[1024];
    const int t = threadIdx.x;
    const int base = t * 32;
    int local[32];
    int sum = 0;
    #pragma unroll
    for (int i = 0; i < 32; i++) { local[i] = deg[base+i]; sum += local[i]; }
    part[t] = sum;
    __syncthreads();
    for (int off = 1; off < 1024; off <<= 1) {
        int v = (t >= off) ? part[t-off] : 0;
        __syncthreads();
        part[t] += v;
        __syncthreads();
    }
    int run = part[t] - sum;   // exclusive
    #pragma unroll
    for (int i = 0; i < 32; i++) {
        start[base+i] = run;
        cursor[base+i] = run;
        run += local[i];
    }
}

__global__ __launch_bounds__(256) void scatter_kernel(
    const int* __restrict__ edst1, const int* __restrict__ edst2,
    int* __restrict__ cursor1, int* __restrict__ cursor2,
    int* __restrict__ sorted1, int* __restrict__ sorted2,
    int* __restrict__ rank1, int* __restrict__ rank2)
{
    const int e = blockIdx.x*256 + threadIdx.x;
    {
        const int d = edst1[e];
        const int p = atomicAdd(&cursor1[d], 1);
        sorted1[p] = e;
        rank1[e] = p;
    }
    {
        const int d = edst2[e];
        const int p = atomicAdd(&cursor2[d], 1);
        sorted2[p] = e;
        rank2[e] = p;
    }
}

// ---------------------------------------------------------------------------
// Phase 1: per-edge precompute: rbf[16] + LN stats -> pre[rank[e]] (20 floats)
// ---------------------------------------------------------------------------
__global__ __launch_bounds__(256) void edge_pre_kernel(
    const float* __restrict__ efeat1, const float* __restrict__ efeat2,
    const int* __restrict__ esrc1, const int* __restrict__ esrc2,
    const int* __restrict__ edst1, const int* __restrict__ edst2,
    const float* __restrict__ coords1, const float* __restrict__ coords2,
    const int* __restrict__ rank1, const int* __restrict__ rank2,
    const float* __restrict__ W_edge, const float* __restrict__ W_rbf,
    const float* __restrict__ b_rbf,
    float* __restrict__ pre1, float* __restrict__ pre2)
{
    const int side = blockIdx.y;
    const float* ef     = side ? efeat2  : efeat1;
    const int*   esrc   = side ? esrc2   : esrc1;
    const int*   edst   = side ? edst2   : edst1;
    const float* coords = side ? coords2 : coords1;
    const int*   rank   = side ? rank2   : rank1;
    float* pre = side ? pre2 : pre1;

    __shared__ float WeT[100][16];
    __shared__ float WrT[100][16];
    __shared__ float sbr[100];
    const int tid = threadIdx.x;

    for (int i = tid; i < 1400; i += 256) {
        const int k = i / 100, c = i % 100;
        WeT[c][k] = W_edge[i];
    }
    for (int i = tid; i < 1600; i += 256) {
        const int k = i / 100, c = i % 100;
        WrT[c][k] = W_rbf[i];
    }
    for (int c = tid; c < 100; c += 256) { WeT[c][14] = 0.f; WeT[c][15] = 0.f; }
    if (tid < 100) sbr[tid] = b_rbf[tid];
    __syncthreads();

    const int e = blockIdx.x*256 + tid;
    const int src = esrc[e], dst = edst[e];

    float efr[16];
    #pragma unroll
    for (int k = 0; k < 14; k++) efr[k] = ef[(size_t)e*DE + k];
    efr[14] = 0.f; efr[15] = 0.f;

    const float dx = coords[src*3+0] - coords[dst*3+0];
    const float dy = coords[src*3+1] - coords[dst*3+1];
    const float dz = coords[src*3+2] - coords[dst*3+2];
    const float dist = sqrtf(dx*dx + dy*dy + dz*dz + 1e-12f);

    float rbf[16];
    #pragma unroll
    for (int k = 0; k < 16; k++) {
        const float t = 3.2f*dist - 1.0666666667f*(float)k;
        rbf[k] = __expf(-t*t);
    }

    float s = 0.f, s2 = 0.f;
    for (int c = 0; c < 100; c++) {
        const float4 we0 = *(const float4*)&WeT[c][0];
        const float4 we1 = *(const float4*)&WeT[c][4];
        const float4 we2 = *(const float4*)&WeT[c][8];
        const float4 we3 = *(const float4*)&WeT[c][12];
        float xe = efr[0]*we0.x + efr[1]*we0.y + efr[2]*we0.z + efr[3]*we0.w
                 + efr[4]*we1.x + efr[5]*we1.y + efr[6]*we1.z + efr[7]*we1.w
                 + efr[8]*we2.x + efr[9]*we2.y + efr[10]*we2.z + efr[11]*we2.w
                 + efr[12]*we3.x + efr[13]*we3.y;
        xe = fmaxf(xe, 0.f);
        s += xe; s2 += xe*xe;

        const float4 wr0 = *(const float4*)&WrT[c][0];
        const float4 wr1 = *(const float4*)&WrT[c][4];
        const float4 wr2 = *(const float4*)&WrT[c][8];
        const float4 wr3 = *(const float4*)&WrT[c][12];
        float xr = sbr[c]
                 + rbf[0]*wr0.x + rbf[1]*wr0.y + rbf[2]*wr0.z + rbf[3]*wr0.w
                 + rbf[4]*wr1.x + rbf[5]*wr1.y + rbf[6]*wr1.z + rbf[7]*wr1.w
                 + rbf[8]*wr2.x + rbf[9]*wr2.y + rbf[10]*wr2.z + rbf[11]*wr2.w
                 + rbf[12]*wr3.x + rbf[13]*wr3.y + rbf[14]*wr3.z + rbf[15]*wr3.w;
        xr = fmaxf(xr, 0.f);
        s += xr; s2 += xr*xr;
    }
    const float mean = s * (1.0f/DH);
    const float var  = s2 * (1.0f/DH) - mean*mean;
    const float rstd = rsqrtf(var + 1e-5f);

    float* pe = pre + (size_t)rank[e]*20;
    #pragma unroll
    for (int k = 0; k < 16; k += 4) {
        float4 v; v.x = rbf[k]; v.y = rbf[k+1]; v.z = rbf[k+2]; v.w = rbf[k+3];
        *(float4*)&pe[k] = v;
    }
    float2 st; st.x = mean*rstd; st.y = rstd;
    *(float2*)&pe[16] = st;
}

// ---------------------------------------------------------------------------
// Phase 2: per-node gather. One wave per node. pre is rank-ordered.
// Wave-uniform values pinned to SGPRs via readfirstlane.
// ---------------------------------------------------------------------------
__global__ __launch_bounds__(256) void gather_edge_kernel(
    const float* __restrict__ efeat1, const float* __restrict__ efeat2,
    const float* __restrict__ pre1, const float* __restrict__ pre2,
    const int* __restrict__ sorted1, const int* __restrict__ sorted2,
    const int* __restrict__ start1, const int* __restrict__ start2,
    const int* __restrict__ deg1, const int* __restrict__ deg2,
    const float* __restrict__ W_edge, const float* __restrict__ W_rbf,
    const float* __restrict__ b_rbf,
    const float* __restrict__ ln_g, const float* __restrict__ ln_b,
    float* __restrict__ h1, float* __restrict__ h2)
{
    const int side = blockIdx.y;
    const float* ef     = side ? efeat2  : efeat1;
    const float* pre    = side ? pre2    : pre1;
    const int*   sorted = side ? sorted2 : sorted1;
    const int*   start  = side ? start2  : start1;
    const int*   deg    = side ? deg2    : deg1;
    float* h = side ? h2 : h1;

    const int lane = threadIdx.x & 63;
    const int wv = __builtin_amdgcn_readfirstlane(threadIdx.x >> 6);
    const int node = blockIdx.x*4 + wv;

    float wA[14], wB[16], wC[16], wD[16];
    #pragma unroll
    for (int k = 0; k < 14; k++) wA[k] = W_edge[k*100 + lane];
    #pragma unroll
    for (int k = 0; k < 16; k++) wB[k] = W_rbf[k*100 + 28 + lane];
    if (lane < 36) {
        #pragma unroll
        for (int k = 0; k < 14; k++) wC[k] = W_edge[k*100 + 64 + lane];
        #pragma unroll
        for (int k = 14; k < 16; k++) wC[k] = 0.0f;
    } else {
        #pragma unroll
        for (int k = 0; k < 16; k++) wC[k] = W_rbf[k*100 + (lane-36)];
    }
    if (lane < 8) {
        #pragma unroll
        for (int k = 0; k < 16; k++) wD[k] = W_rbf[k*100 + 92 + lane];
    } else {
        #pragma unroll
        for (int k = 0; k < 16; k++) wD[k] = 0.0f;
    }
    const float g0 = ln_g[lane],       bb0 = ln_b[lane];
    const float g1 = ln_g[64+lane],    bb1 = ln_b[64+lane];
    const float g2 = ln_g[128+lane],   bb2 = ln_b[128+lane];
    const float g3 = (lane<8) ? ln_g[192+lane] : 0.0f;
    const float bb3= (lane<8) ? ln_b[192+lane] : 0.0f;
    const float br2 = b_rbf[28+lane];
    const float br1 = (lane >= 36) ? b_rbf[lane-36] : 0.0f;
    const float br3 = (lane < 8)  ? b_rbf[92+lane] : 0.0f;

    const int st = __builtin_amdgcn_readfirstlane(start[node]);
    const int dg = __builtin_amdgcn_readfirstlane(deg[node]);
    const size_t base = (size_t)node * DH;

    const float h0  = h[base + lane];
    const float h1v = h[base + 64 + lane];
    const float h2v = h[base + 128 + lane];
    const float h3v = (lane < 8) ? h[base + 192 + lane] : 0.0f;

    float acc0 = 0.f, acc1 = 0.f, acc2 = 0.f, acc3 = 0.f, musum = 0.f;

    auto do_edge = [&](int pos, int eid) {
        const float* pe = pre + (size_t)pos*20;
        float rbf[16];
        #pragma unroll
        for (int k = 0; k < 16; k++) rbf[k] = pe[k];
        const float musrtd = pe[16];
        const float rstd   = pe[17];
        float efr[14];
        #pragma unroll
        for (int k = 0; k < 14; k++) efr[k] = ef[(size_t)eid*DE + k];

        float v0 = 0.f;
        #pragma unroll
        for (int k = 0; k < 14; k++) v0 += efr[k]*wA[k];
        v0 = fmaxf(v0, 0.f);

        float v2 = br2;
        #pragma unroll
        for (int k = 0; k < 16; k++) v2 += rbf[k]*wB[k];
        v2 = fmaxf(v2, 0.f);

        float v1;
        if (lane < 36) {
            v1 = 0.f;
            #pragma unroll
            for (int k = 0; k < 14; k++) v1 += efr[k]*wC[k];
        } else {
            v1 = br1;
            #pragma unroll
            for (int k = 0; k < 16; k++) v1 += rbf[k]*wC[k];
        }
        v1 = fmaxf(v1, 0.f);

        float v3 = br3;
        #pragma unroll
        for (int k = 0; k < 16; k++) v3 += rbf[k]*wD[k];
        v3 = fmaxf(v3, 0.f);

        acc0 += rstd*v0;
        acc1 += rstd*v1;
        acc2 += rstd*v2;
        acc3 += rstd*v3;
        musum += musrtd;
    };

    int i = 0;
    for (; i + 1 < dg; i += 2) {
        const int e0 = __builtin_amdgcn_readfirstlane(sorted[st + i]);
        const int e1 = __builtin_amdgcn_readfirstlane(sorted[st + i + 1]);
        do_edge(st + i, e0);
        do_edge(st + i + 1, e1);
    }
    if (i < dg) {
        const int e0 = __builtin_amdgcn_readfirstlane(sorted[st + i]);
        do_edge(st + i, e0);
    }

    const float dgf = (float)dg;
    h[base + lane]       = h0  + g0*(acc0 - musum) + dgf*bb0;
    h[base + 64 + lane]  = h1v + g1*(acc1 - musum) + dgf*bb1;
    h[base + 128 + lane] = h2v + g2*(acc2 - musum) + dgf*bb2;
    if (lane < 8)
        h[base + 192 + lane] = h3v + g3*(acc3 - musum) + dgf*bb3;
}

// ---------------------------------------------------------------------------
// cvt (per half): h fp32 -> hb hi/lo [16384][224] rows + hbT hi/lo [32][224][512]
// ---------------------------------------------------------------------------
__global__ __launch_bounds__(256) void cvt_kernel(
    const float* __restrict__ h1, const float* __restrict__ h2, const int half,
    short* __restrict__ hbH1, short* __restrict__ hbL1,
    short* __restrict__ hbH2, short* __restrict__ hbL2,
    short* __restrict__ hTH1, short* __restrict__ hTL1,
    short* __restrict__ hTH2, short* __restrict__ hTL2)
{
    const int side = blockIdx.y;
    const float* h = side ? h2 : h1;
    short* hbH = side ? hbH2 : hbH1;
    short* hbL = side ? hbL2 : hbL1;
    short* hTH = side ? hTH2 : hTH1;
    short* hTL = side ? hTL2 : hTL1;

    const int nl0 = blockIdx.x * 64;          // local node
    const int bl = nl0 >> 9, m0 = nl0 & 511;
    const int ng0 = half*HBN + nl0;

    __shared__ short tH[64][226];
    __shared__ short tL[64][226];
    const int tid = threadIdx.x;
    for (int i = tid; i < 64*224; i += 256) {
        const int r = i / 224, c = i - r*224;
        const float v = (c < DH) ? h[(size_t)(ng0+r)*DH + c] : 0.f;
        const short hi = f2bf(v);
        const short lo = f2bf(v - bf2f(hi));
        tH[r][c] = hi; tL[r][c] = lo;
        hbH[(size_t)(nl0+r)*224 + c] = hi;
        hbL[(size_t)(nl0+r)*224 + c] = lo;
    }
    __syncthreads();
    for (int i = tid; i < 224*64; i += 256) {
        const int c = i >> 6, m = i & 63;
        const size_t o = ((size_t)bl*224 + c)*NN + m0 + m;
        hTH[o] = tH[m][c];
        hTL[o] = tL[m][c];
    }
}

// ---------------------------------------------------------------------------
// prep_w: W_down[400][200] -> WbTHI/LO[208][448] (transposed, padded, split)
// ---------------------------------------------------------------------------
__global__ __launch_bounds__(256) void prep_w_kernel(
    const float* __restrict__ W_down,
    short* __restrict__ WbTHI, short* __restrict__ WbTLO)
{
    const int idx = blockIdx.x*256 + threadIdx.x;
    if (idx >= 208*448) return;
    const int c = idx / 448, kk = idx - c*448;
    float v = 0.f;
    if (c < 200) {
        if (kk < 200) v = W_down[(size_t)kk*DH + c];
        else if (kk >= 224 && kk < 424) v = W_down[(size_t)(200 + kk - 224)*DH + c];
    }
    const short hi = f2bf(v);
    WbTHI[idx] = hi;
    WbTLO[idx] = f2bf(v - bf2f(hi));
}

// ---------------------------------------------------------------------------
// Fused attention v2 (per half, per direction): barrier-light.
// Q fragments in registers; K/V fragments streamed from global (L2-hot);
// only P goes through LDS (D-layout -> A-layout).
// Block: 32 Q-rows, one b. Wave wv: mt=wv&1 (M-tile), ch=wv>>1 (col half).
// ---------------------------------------------------------------------------
__global__ __launch_bounds__(256) void attn_kernel(
    const short* __restrict__ QH, const short* __restrict__ QL,
    const short* __restrict__ KH, const short* __restrict__ KL,
    const short* __restrict__ VTH, const short* __restrict__ VTL,
    short* __restrict__ cb)
{
    const int b = blockIdx.y;                 // half-local batch
    const int q0 = blockIdx.x * 32;
    const short* Qh = QH + (size_t)b*NN*224;
    const short* Ql = QL + (size_t)b*NN*224;
    const short* Kh = KH + (size_t)b*NN*224;
    const short* Kl = KL + (size_t)b*NN*224;
    const short* Vh = VTH + (size_t)b*224*NN;
    const short* Vl = VTL + (size_t)b*224*NN;

    __shared__ short pb[32*528];              // 33.8 KB: P bf16, pitch 528
    __shared__ float sm_[2][2][16];
    __shared__ float ss_[2][2][16];

    const int tid = threadIdx.x;
    const int wv = tid >> 6, lane = tid & 63;
    const int arow = lane & 15, aq = lane >> 4;
    const int mt = wv & 1, ch = wv >> 1;

    // Q fragments in registers (A-layout: A[m=arow][k=aq*8+j])
    const int qrow = q0 + mt*16 + arow;
    short8 qfh[7], qfl[7];
    #pragma unroll
    for (int k = 0; k < 7; k++) {
        qfh[k] = *(const short8*)&Qh[(size_t)qrow*224 + k*32 + aq*8];
        qfl[k] = *(const short8*)&Ql[(size_t)qrow*224 + k*32 + aq*8];
    }

    f32x4 acc[16];
    #pragma unroll
    for (int t = 0; t < 16; t++) acc[t] = (f32x4){0.f,0.f,0.f,0.f};

    // QK^T: stream K fragments from global (B-layout: B[n=arow][k=aq*8+j])
    #pragma unroll
    for (int ct = 0; ct < 16; ct++) {
        const size_t kb = (size_t)(ct*32 + ch*16 + arow)*224;
        #pragma unroll
        for (int k = 0; k < 7; k++) {
            const short8 bh = *(const short8*)&Kh[kb + k*32 + aq*8];
            const short8 bl = *(const short8*)&Kl[kb + k*32 + aq*8];
            acc[ct] = __builtin_amdgcn_mfma_f32_16x16x32_bf16(qfh[k], bh, acc[ct], 0, 0, 0);
            acc[ct] = __builtin_amdgcn_mfma_f32_16x16x32_bf16(qfh[k], bl, acc[ct], 0, 0, 0);
            acc[ct] = __builtin_amdgcn_mfma_f32_16x16x32_bf16(qfl[k], bh, acc[ct], 0, 0, 0);
        }
    }

    // softmax: lane holds rows aq*4+r (M-tile mt), cols ct*32+ch*16+arow
    float mr[4], sr[4], iv[4];
    #pragma unroll
    for (int r = 0; r < 4; r++) {
        float m = -1e30f;
        #pragma unroll
        for (int ct = 0; ct < 16; ct++) {
            acc[ct][r] *= T_SCALE;
            m = fmaxf(m, acc[ct][r]);
        }
        m = fmaxf(m, __shfl_xor(m, 1, 64));
        m = fmaxf(m, __shfl_xor(m, 2, 64));
        m = fmaxf(m, __shfl_xor(m, 4, 64));
        m = fmaxf(m, __shfl_xor(m, 8, 64));
        mr[r] = m;
    }
    if (arow == 0) {
        #pragma unroll
        for (int r = 0; r < 4; r++) sm_[mt][ch][aq*4+r] = mr[r];
    }
    __syncthreads();
    #pragma unroll
    for (int r = 0; r < 4; r++) {
        const float M = fmaxf(mr[r], sm_[mt][1-ch][aq*4+r]);
        float s = 0.f;
        #pragma unroll
        for (int ct = 0; ct < 16; ct++) {
            const float e = __expf(acc[ct][r] - M);
            acc[ct][r] = e;
            s += e;
        }
        s += __shfl_xor(s, 1, 64);
        s += __shfl_xor(s, 2, 64);
        s += __shfl_xor(s, 4, 64);
        s += __shfl_xor(s, 8, 64);
        sr[r] = s;
    }
    if (arow == 0) {
        #pragma unroll
        for (int r = 0; r < 4; r++) ss_[mt][ch][aq*4+r] = sr[r];
    }
    __syncthreads();
    #pragma unroll
    for (int r = 0; r < 4; r++)
        iv[r] = 1.0f / (sr[r] + ss_[mt][1-ch][aq*4+r]);

    // write P bf16
    #pragma unroll
    for (int ct = 0; ct < 16; ct++) {
        const int col = ct*32 + ch*16 + arow;
        #pragma unroll
        for (int r = 0; r < 4; r++)
            pb[(mt*16 + aq*4 + r)*528 + col] = f2bf(acc[ct][r] * iv[r]);
    }
    __syncthreads();   // P written by both waves of each M-tile before reads

    // PV: stream V fragments from global. N-tiles split 7/6 across ch.
    const int nbase = ch ? 7 : 0;
    const int ncnt  = ch ? 6 : 7;
    f32x4 pacc[7];
    #pragma unroll
    for (int t = 0; t < 7; t++) pacc[t] = (f32x4){0.f,0.f,0.f,0.f};

    for (int k0 = 0; k0 < NN; k0 += 32) {
        const short8 a = *(const short8*)&pb[(mt*16 + arow)*528 + k0 + aq*8];
        #pragma unroll
        for (int t = 0; t < 7; t++) {
            if (t < ncnt) {
                const size_t vb = (size_t)((nbase+t)*16 + arow)*NN + k0 + aq*8;
                const short8 bh = *(const short8*)&Vh[vb];
                const short8 bl = *(const short8*)&Vl[vb];
                pacc[t] = __builtin_amdgcn_mfma_f32_16x16x32_bf16(a, bh, pacc[t], 0, 0, 0);
                pacc[t] = __builtin_amdgcn_mfma_f32_16x16x32_bf16(a, bl, pacc[t], 0, 0, 0);
            }
        }
    }

    // epilogue: cb bf16, pad cols [200,224) with zeros
    #pragma unroll
    for (int t = 0; t < 7; t++) {
        if (t < ncnt) {
            const int col = (nbase+t)*16 + arow;
            #pragma unroll
            for (int r = 0; r < 4; r++) {
                const int row = q0 + mt*16 + aq*4 + r;
                const short v = (col < DH) ? f2bf(pacc[t][r]) : (short)0;
                cb[((size_t)b*NN + row)*224 + col] = v;
            }
        }
    }
    if (ch) {
        const int col = 208 + arow;
        #pragma unroll
        for (int r = 0; r < 4; r++) {
            const int row = q0 + mt*16 + aq*4 + r;
            cb[((size_t)b*NN + row)*224 + col] = 0;
        }
    }
}

// ---------------------------------------------------------------------------
// down (per half, MFMA, split-W): relu([hb|cb] @ W_down) + degree_table -> hsg
// ---------------------------------------------------------------------------
__global__ __launch_bounds__(256) void down_mfma(
    const short* __restrict__ hbH1, const short* __restrict__ hbH2,
    const short* __restrict__ cb1, const short* __restrict__ cb2,
    const int* __restrict__ deg1, const int* __restrict__ deg2,
    const short* __restrict__ WbTH, const short* __restrict__ WbTL,
    const float* __restrict__ degree_table,
    float* __restrict__ hsg1, float* __restrict__ hsg2, const int half)
{
    const int side = blockIdx.y;
    const short* X0 = side ? hbH2 : hbH1;
    const short* X1 = side ? cb2 : cb1;
    const int*   dgp = side ? deg2 : deg1;
    float* hsg = side ? hsg2 : hsg1;

    const int nl0 = blockIdx.x * 64;
    const int ng0 = half*HBN + nl0;
    const int b = ng0 >> 9;

    __shared__ short As[64*40];
    __shared__ short BsH[208*40];
    __shared__ short BsL[208*40];
    __shared__ float part[208];

    const int tid = threadIdx.x;
    const int wv = tid >> 6, lane = tid & 63;
    const int arow = lane & 15, aq = lane >> 4;

    if (tid < 208) part[tid] = 0.f;

    f32x4 acc[13];
    #pragma unroll
    for (int t = 0; t < 13; t++) acc[t] = (f32x4){0.f,0.f,0.f,0.f};

    const int sr = tid >> 2, sc = (tid & 3) * 8;

    for (int phase = 0; phase < 2; phase++) {
        const short* X = phase ? X1 : X0;
        for (int k0 = 0; k0 < 224; k0 += 32) {
            __syncthreads();
            *(short8*)&As[sr*40 + sc] =
                *(const short8*)&X[(size_t)(nl0+sr)*224 + k0 + sc];
            const int kkg = phase*224 + k0;
            #pragma unroll
            for (int pass = 0; pass < 4; pass++) {
                const int f = pass*256 + tid;
                if (f < 832) {
                    const int d = f >> 2, cc = (f & 3) * 8;
                    *(short8*)&BsH[d*40 + cc] = *(const short8*)&WbTH[(size_t)d*448 + kkg + cc];
                    *(short8*)&BsL[d*40 + cc] = *(const short8*)&WbTL[(size_t)d*448 + kkg + cc];
                }
            }
            __syncthreads();
            const short8 a = *(const short8*)&As[(16*wv + arow)*40 + aq*8];
            #pragma unroll
            for (int t = 0; t < 13; t++) {
                const short8 bh = *(const short8*)&BsH[(t*16 + arow)*40 + aq*8];
                const short8 bl = *(const short8*)&BsL[(t*16 + arow)*40 + aq*8];
                acc[t] = __builtin_amdgcn_mfma_f32_16x16x32_bf16(a, bh, acc[t], 0, 0, 0);
                acc[t] = __builtin_amdgcn_mfma_f32_16x16x32_bf16(a, bl, acc[t], 0, 0, 0);
            }
        }
    }
    __syncthreads();

    int dgc[4];
    #pragma unroll
    for (int r = 0; r < 4; r++) {
        int d = dgp[ng0 + 16*wv + aq*4 + r];
        dgc[r] = d > 199 ? 199 : d;
    }
    #pragma unroll
    for (int nt = 0; nt < 13; nt++) {
        const int col = nt*16 + arow;
        float s = 0.f;
        if (col < DH) {
            #pragma unroll
            for (int r = 0; r < 4; r++)
                s += fmaxf(acc[nt][r], 0.f) + degree_table[dgc[r]*DH + col];
        }
        s += __shfl_xor(s, 16, 64);
        s += __shfl_xor(s, 32, 64);
        if (lane < 16 && col < DH) atomicAdd(&part[col], s);
    }
    __syncthreads();
    if (tid < DH) unsafeAtomicAdd(&hsg[b*206 + tid], part[tid] * (1.0f/512.0f));
}

// ---------------------------------------------------------------------------
// Kernel 6: interaction mean over nodes -> hsg cols 200..205
// ---------------------------------------------------------------------------
__global__ __launch_bounds__(192) void inter_kernel(
    const float* __restrict__ i1, const float* __restrict__ i2,
    float* __restrict__ hsg1, float* __restrict__ hsg2)
{
    const int side = blockIdx.y;
    const float* it = side ? i2 : i1;
    float* hsg = side ? hsg2 : hsg1;
    const int b = blockIdx.x;
    __shared__ float red[192];
    const int tid = threadIdx.x;
    const int j = tid % 6, seg = tid / 6;
    float s = 0.0f;
    for (int n = seg*16; n < seg*16 + 16; n++)
        s += it[(size_t)b*NN*DI + n*DI + j];
    red[tid] = s;
    __syncthreads();
    if (tid < 6) {
        float tot = 0.0f;
        for (int sg2 = 0; sg2 < 32; sg2++) tot += red[sg2*6 + tid];
        hsg[b*206 + 200 + tid] = tot * (1.0f/512.0f);
    }
}

// ---------------------------------------------------------------------------
// Kernel 7: final MLP, one block per batch row
// ---------------------------------------------------------------------------
__global__ __launch_bounds__(256) void mlp_kernel(
    const float* __restrict__ hsg1, const float* __restrict__ hsg2,
    const float* __restrict__ W_f1, const float* __restrict__ b_f1,
    const float* __restrict__ W_f2, const float* __restrict__ b_f2,
    const float* __restrict__ W_f3, const float* __restrict__ b_f3,
    const float* __restrict__ W_f4, const float* __restrict__ b_f4,
    float* __restrict__ out)
{
    const int b = blockIdx.x;
    __shared__ float x[618];
    __shared__ float y1[400];
    __shared__ float y2[200];
    __shared__ float y3[100];
    __shared__ float red[256];
    const int tid = threadIdx.x;

    if (tid < 206) {
        const float a = hsg1[b*206 + tid], bb = hsg2[b*206 + tid];
        x[tid] = a; x[206 + tid] = bb; x[412 + tid] = a - bb;
    }
    __syncthreads();
    for (int c = tid; c < 400; c += 256) {
        float acc = b_f1[c];
        for (int k = 0; k < 618; k++) acc += x[k]*W_f1[(size_t)k*400 + c];
        y1[c] = fmaxf(acc, 0.0f);
    }
    __syncthreads();
    if (tid < 200) {
        float acc = b_f2[tid];
        for (int k = 0; k < 400; k++) acc += y1[k]*W_f2[k*200 + tid];
        y2[tid] = fmaxf(acc, 0.0f);
    }
    __syncthreads();
    if (tid < 100) {
        float acc = b_f3[tid];
        for (int k = 0; k < 200; k++) acc += y2[k]*W_f3[k*100 + tid];
        y3[tid] = fmaxf(acc, 0.0f);
    }
    __syncthreads();
    red[tid] = (tid < 100) ? y3[tid]*W_f4[tid] : 0.0f;
    __syncthreads();
    for (int s = 128; s > 0; s >>= 1) {
        if (tid < s) red[tid] += red[tid + s];
        __syncthreads();
    }
    if (tid == 0) out[b] = red[0] + b_f4[0];
}

// ---------------------------------------------------------------------------
extern "C" void kernel_launch(void* const* d_in, const int* in_sizes, int n_in,
                              void* d_out, int out_size, void* d_ws, size_t ws_size,
                              hipStream_t stream)
{
    const float* atom1  = (const float*)d_in[0];
    const float* atom2  = (const float*)d_in[1];
    const float* coords1= (const float*)d_in[2];
    const float* coords2= (const float*)d_in[3];
    const float* efeat1 = (const float*)d_in[4];
    const float* efeat2 = (const float*)d_in[5];
    const float* inter1 = (const float*)d_in[6];
    const float* inter2 = (const float*)d_in[7];
    const int*   esrc1  = (const int*)d_in[8];
    const int*   edst1  = (const int*)d_in[9];
    const int*   esrc2  = (const int*)d_in[10];
    const int*   edst2  = (const int*)d_in[11];
    const float* W_atom = (const float*)d_in[12];
    const float* W_edge = (const float*)d_in[13];
    const float* W_rbf  = (const float*)d_in[14];
    const float* b_rbf  = (const float*)d_in[15];
    const float* ln_g   = (const float*)d_in[16];
    const float* ln_b   = (const float*)d_in[17];
    const float* W_down = (const float*)d_in[18];
    const float* deg_tab= (const float*)d_in[19];
    const float* W_f1   = (const float*)d_in[20];
    const float* b_f1   = (const float*)d_in[21];
    const float* W_f2   = (const float*)d_in[22];
    const float* b_f2   = (const float*)d_in[23];
    const float* W_f3   = (const float*)d_in[24];
    const float* b_f3   = (const float*)d_in[25];
    const float* W_f4   = (const float*)d_in[26];
    const float* b_f4   = (const float*)d_in[27];
    float* out = (float*)d_out;

    // ---- workspace layout (~146 MB)
    float* ws = (float*)d_ws;
    const size_t HSZ = (size_t)BN*DH;              // per-side h floats
    float* h1  = ws;
    float* h2  = h1 + HSZ;
    // pool region: max(pre 2*EE*20 floats = 83.9MB, bf16 pool 73.4MB)
    float* poolf = h2 + HSZ;
    const size_t PRESZ = (size_t)EE*20;
    float* pre1 = poolf;
    float* pre2 = pre1 + PRESZ;
    short* pool = (short*)poolf;
    const size_t HB = (size_t)32*NN*224;           // 3,670,016 shorts
    short* hbH1 = pool;           short* hbL1 = hbH1 + HB;
    short* hbH2 = hbL1 + HB;      short* hbL2 = hbH2 + HB;
    short* hTH1 = hbL2 + HB;      short* hTL1 = hTH1 + HB;
    short* hTH2 = hTL1 + HB;      short* hTL2 = hTH2 + HB;
    short* cb1  = hTL2 + HB;      short* cb2  = cb1 + HB;
    float* after = poolf + 2*PRESZ;
    short* WbTH = (short*)after;
    short* WbTL = WbTH + 208*448;
    float* hsg1 = (float*)(WbTL + 208*448);
    float* hsg2 = hsg1 + (size_t)BB*206;
    int* deg1 = (int*)(hsg2 + (size_t)BB*206);
    int* deg2 = deg1 + BN;
    int* start1 = deg2 + BN;
    int* start2 = start1 + BN;
    int* cursor1 = start2 + BN;
    int* cursor2 = cursor1 + BN;
    int* sorted1 = cursor2 + BN;
    int* sorted2 = sorted1 + EE;
    int* rank1 = sorted2 + EE;
    int* rank2 = rank1 + EE;

    hipMemsetAsync(deg1, 0, 2*(size_t)BN*sizeof(int), stream);
    hipMemsetAsync(hsg1, 0, 2*(size_t)BB*206*sizeof(float), stream);

    node_kernel<<<dim3(BN/4, 2), 256, 0, stream>>>(
        atom1, atom2, W_atom, ln_g, ln_b, h1, h2);

    hist_kernel<<<EE/256, 256, 0, stream>>>(edst1, edst2, deg1, deg2);
    scan_kernel<<<2, 1024, 0, stream>>>(deg1, deg2, start1, start2, cursor1, cursor2);
    scatter_kernel<<<EE/256, 256, 0, stream>>>(edst1, edst2, cursor1, cursor2,
                                               sorted1, sorted2, rank1, rank2);

    edge_pre_kernel<<<dim3(EE/256, 2), 256, 0, stream>>>(
        efeat1, efeat2, esrc1, esrc2, edst1, edst2, coords1, coords2,
        rank1, rank2, W_edge, W_rbf, b_rbf, pre1, pre2);

    gather_edge_kernel<<<dim3(BN/4, 2), 256, 0, stream>>>(
        efeat1, efeat2, pre1, pre2,
        sorted1, sorted2, start1, start2, deg1, deg2,
        W_edge, W_rbf, b_rbf, ln_g, ln_b, h1, h2);

    prep_w_kernel<<<(208*448 + 255)/256, 256, 0, stream>>>(W_down, WbTH, WbTL);

    for (int half = 0; half < 2; half++) {
        cvt_kernel<<<dim3(HBN/64, 2), 256, 0, stream>>>(
            h1, h2, half, hbH1, hbL1, hbH2, hbL2, hTH1, hTL1, hTH2, hTL2);
        // dir0: c1 = softmax_rows(h1@h2^T) @ h2
        attn_kernel<<<dim3(16, 32), 256, 0, stream>>>(
            hbH1, hbL1, hbH2, hbL2, hTH2, hTL2, cb1);
        // dir1: c2 = softmax_rows(h2@h1^T) @ h1
        attn_kernel<<<dim3(16, 32), 256, 0, stream>>>(
            hbH2, hbL2, hbH1, hbL1, hTH1, hTL1, cb2);
        down_mfma<<<dim3(HBN/64, 2), 256, 0, stream>>>(
            hbH1, hbH2, cb1, cb2, deg1, deg2, WbTH, WbTL, deg_tab,
            hsg1, hsg2, half);
    }

    inter_kernel<<<dim3(BB, 2), 192, 0, stream>>>(inter1, inter2, hsg1, hsg2);

    mlp_kernel<<<BB, 256, 0, stream>>>(
        hsg1, hsg2, W_f1, b_f1, W_f2, b_f2, W_f3, b_f3, W_f4, b_f4, out);
}

// Round 9
// 1287.427 us; speedup vs baseline: 2.5149x; 1.0406x over previous
//
#include <hip/hip_runtime.h>
#include <cstddef>
#include <cstdint>

// Problem constants
#define BB   64
#define NN   512
#define BN   (BB*NN)          // 32768
#define HBN  16384            // nodes per half
#define EE   524288
#define DA   70
#define DE   14
#define DH   200
#define DI   6
#define T_SCALE 0.07071067811865475f   // sqrt(1/200)

typedef __attribute__((ext_vector_type(8))) short short8;
typedef __attribute__((ext_vector_type(4))) float f32x4;

__device__ __forceinline__ short f2bf(float x) {
    union { float f; unsigned u; } v; v.f = x;
    const unsigned r = v.u + 0x7FFFu + ((v.u >> 16) & 1u);   // RNE
    return (short)(r >> 16);
}
__device__ __forceinline__ float bf2f(short s) {
    union { unsigned u; float f; } v;
    v.u = ((unsigned)(unsigned short)s) << 16;
    return v.f;
}
__device__ __forceinline__ float bits2f(unsigned u) {
    union { unsigned u; float f; } v; v.u = u; return v.f;
}

// ---------------------------------------------------------------------------
// Kernel 1: per-node  h = layernorm(relu(atom @ W_atom))
// ---------------------------------------------------------------------------
__global__ __launch_bounds__(256) void node_kernel(
    const float* __restrict__ atom1, const float* __restrict__ atom2,
    const float* __restrict__ W_atom,
    const float* __restrict__ ln_g, const float* __restrict__ ln_b,
    float* __restrict__ h1, float* __restrict__ h2)
{
    const int side = blockIdx.y;
    const float* atom = side ? atom2 : atom1;
    float* h = side ? h2 : h1;
    const int node0 = blockIdx.x * 4;
    const int tid = threadIdx.x;

    __shared__ float arow[4][DA];
    __shared__ float vals[4][DH];

    for (int i = tid; i < 4*DA; i += 256) {
        const int n = i / DA, k = i % DA;
        arow[n][k] = atom[(size_t)(node0+n)*DA + k];
    }
    __syncthreads();

    if (tid < DH) {
        float a0 = 0.f, a1 = 0.f, a2 = 0.f, a3 = 0.f;
        #pragma unroll 7
        for (int k = 0; k < DA; k++) {
            const float w = W_atom[k*DH + tid];
            a0 += arow[0][k]*w; a1 += arow[1][k]*w;
            a2 += arow[2][k]*w; a3 += arow[3][k]*w;
        }
        vals[0][tid] = fmaxf(a0, 0.f);
        vals[1][tid] = fmaxf(a1, 0.f);
        vals[2][tid] = fmaxf(a2, 0.f);
        vals[3][tid] = fmaxf(a3, 0.f);
    }
    __syncthreads();

    const int wv = tid >> 6, lane = tid & 63;
    float v0 = vals[wv][lane];
    float v1 = vals[wv][64+lane];
    float v2 = vals[wv][128+lane];
    float v3 = (lane < 8) ? vals[wv][192+lane] : 0.0f;
    float s  = v0+v1+v2+v3;
    float s2 = v0*v0+v1*v1+v2*v2+v3*v3;
    #pragma unroll
    for (int off = 1; off < 64; off <<= 1) {
        s  += __shfl_xor(s,  off, 64);
        s2 += __shfl_xor(s2, off, 64);
    }
    const float mean = s * (1.0f/DH);
    const float var  = s2 * (1.0f/DH) - mean*mean;
    const float rstd = rsqrtf(var + 1e-5f);
    const size_t base = (size_t)(node0+wv)*DH;
    h[base + lane]       = ln_g[lane]     *(v0-mean)*rstd + ln_b[lane];
    h[base + 64 + lane]  = ln_g[64+lane]  *(v1-mean)*rstd + ln_b[64+lane];
    h[base + 128 + lane] = ln_g[128+lane] *(v2-mean)*rstd + ln_b[128+lane];
    if (lane < 8)
        h[base + 192 + lane] = ln_g[192+lane]*(v3-mean)*rstd + ln_b[192+lane];
}

// ---------------------------------------------------------------------------
// Counting sort by dst: hist -> scan -> scatter (rank only)
// ---------------------------------------------------------------------------
__global__ __launch_bounds__(256) void hist_kernel(
    const int* __restrict__ edst1, const int* __restrict__ edst2,
    int* __restrict__ deg1, int* __restrict__ deg2)
{
    const int e = blockIdx.x*256 + threadIdx.x;
    atomicAdd(&deg1[edst1[e]], 1);
    atomicAdd(&deg2[edst2[e]], 1);
}

__global__ __launch_bounds__(1024) void scan_kernel(
    const int* __restrict__ deg1, const int* __restrict__ deg2,
    int* __restrict__ start1, int* __restrict__ start2,
    int* __restrict__ cursor1, int* __restrict__ cursor2)
{
    const int side = blockIdx.x;
    const int* deg   = side ? deg2 : deg1;
    int* start  = side ? start2 : start1;
    int* cursor = side ? cursor2 : cursor1;

    __shared__ int part[1024];
    const int t = threadIdx.x;
    const int base = t * 32;
    int local[32];
    int sum = 0;
    #pragma unroll
    for (int i = 0; i < 32; i++) { local[i] = deg[base+i]; sum += local[i]; }
    part[t] = sum;
    __syncthreads();
    for (int off = 1; off < 1024; off <<= 1) {
        int v = (t >= off) ? part[t-off] : 0;
        __syncthreads();
        part[t] += v;
        __syncthreads();
    }
    int run = part[t] - sum;   // exclusive
    #pragma unroll
    for (int i = 0; i < 32; i++) {
        start[base+i] = run;
        cursor[base+i] = run;
        run += local[i];
    }
}

__global__ __launch_bounds__(256) void scatter_kernel(
    const int* __restrict__ edst1, const int* __restrict__ edst2,
    int* __restrict__ cursor1, int* __restrict__ cursor2,
    int* __restrict__ rank1, int* __restrict__ rank2)
{
    const int e = blockIdx.x*256 + threadIdx.x;
    {
        const int d = edst1[e];
        rank1[e] = atomicAdd(&cursor1[d], 1);
    }
    {
        const int d = edst2[e];
        rank2[e] = atomicAdd(&cursor2[d], 1);
    }
}

// ---------------------------------------------------------------------------
// Phase 1: per-edge precompute -> pre[rank[e]] (24 floats, 96 B):
//   f[0..13] = ef fp32 ; f[14..21] = rbf bf16 x16 packed ; f[22]=mu*rstd ; f[23]=rstd
// Stats computed with the SAME quantized rbf that gather unpacks.
// ---------------------------------------------------------------------------
__global__ __launch_bounds__(256) void edge_pre_kernel(
    const float* __restrict__ efeat1, const float* __restrict__ efeat2,
    const int* __restrict__ esrc1, const int* __restrict__ esrc2,
    const int* __restrict__ edst1, const int* __restrict__ edst2,
    const float* __restrict__ coords1, const float* __restrict__ coords2,
    const int* __restrict__ rank1, const int* __restrict__ rank2,
    const float* __restrict__ W_edge, const float* __restrict__ W_rbf,
    const float* __restrict__ b_rbf,
    float* __restrict__ pre1, float* __restrict__ pre2)
{
    const int side = blockIdx.y;
    const float* ef     = side ? efeat2  : efeat1;
    const int*   esrc   = side ? esrc2   : esrc1;
    const int*   edst   = side ? edst2   : edst1;
    const float* coords = side ? coords2 : coords1;
    const int*   rank   = side ? rank2   : rank1;
    float* pre = side ? pre2 : pre1;

    __shared__ float WeT[100][16];
    __shared__ float WrT[100][16];
    __shared__ float sbr[100];
    const int tid = threadIdx.x;

    for (int i = tid; i < 1400; i += 256) {
        const int k = i / 100, c = i % 100;
        WeT[c][k] = W_edge[i];
    }
    for (int i = tid; i < 1600; i += 256) {
        const int k = i / 100, c = i % 100;
        WrT[c][k] = W_rbf[i];
    }
    for (int c = tid; c < 100; c += 256) { WeT[c][14] = 0.f; WeT[c][15] = 0.f; }
    if (tid < 100) sbr[tid] = b_rbf[tid];
    __syncthreads();

    const int e = blockIdx.x*256 + tid;
    const int src = esrc[e], dst = edst[e];

    float efr[16];
    #pragma unroll
    for (int k = 0; k < 14; k++) efr[k] = ef[(size_t)e*DE + k];
    efr[14] = 0.f; efr[15] = 0.f;

    const float dx = coords[src*3+0] - coords[dst*3+0];
    const float dy = coords[src*3+1] - coords[dst*3+1];
    const float dz = coords[src*3+2] - coords[dst*3+2];
    const float dist = sqrtf(dx*dx + dy*dy + dz*dz + 1e-12f);

    float rbf[16];
    unsigned short rbs[16];
    #pragma unroll
    for (int k = 0; k < 16; k++) {
        const float t = 3.2f*dist - 1.0666666667f*(float)k;
        const float r = __expf(-t*t);
        const short s = f2bf(r);
        rbs[k] = (unsigned short)s;
        rbf[k] = bf2f(s);             // quantized value used for stats
    }

    float s = 0.f, s2 = 0.f;
    for (int c = 0; c < 100; c++) {
        const float4 we0 = *(const float4*)&WeT[c][0];
        const float4 we1 = *(const float4*)&WeT[c][4];
        const float4 we2 = *(const float4*)&WeT[c][8];
        const float4 we3 = *(const float4*)&WeT[c][12];
        float xe = efr[0]*we0.x + efr[1]*we0.y + efr[2]*we0.z + efr[3]*we0.w
                 + efr[4]*we1.x + efr[5]*we1.y + efr[6]*we1.z + efr[7]*we1.w
                 + efr[8]*we2.x + efr[9]*we2.y + efr[10]*we2.z + efr[11]*we2.w
                 + efr[12]*we3.x + efr[13]*we3.y;
        xe = fmaxf(xe, 0.f);
        s += xe; s2 += xe*xe;

        const float4 wr0 = *(const float4*)&WrT[c][0];
        const float4 wr1 = *(const float4*)&WrT[c][4];
        const float4 wr2 = *(const float4*)&WrT[c][8];
        const float4 wr3 = *(const float4*)&WrT[c][12];
        float xr = sbr[c]
                 + rbf[0]*wr0.x + rbf[1]*wr0.y + rbf[2]*wr0.z + rbf[3]*wr0.w
                 + rbf[4]*wr1.x + rbf[5]*wr1.y + rbf[6]*wr1.z + rbf[7]*wr1.w
                 + rbf[8]*wr2.x + rbf[9]*wr2.y + rbf[10]*wr2.z + rbf[11]*wr2.w
                 + rbf[12]*wr3.x + rbf[13]*wr3.y + rbf[14]*wr3.z + rbf[15]*wr3.w;
        xr = fmaxf(xr, 0.f);
        s += xr; s2 += xr*xr;
    }
    const float mean = s * (1.0f/DH);
    const float var  = s2 * (1.0f/DH) - mean*mean;
    const float rstd = rsqrtf(var + 1e-5f);

    float* pe = pre + (size_t)rank[e]*24;
    float4 w0; w0.x = efr[0];  w0.y = efr[1];  w0.z = efr[2];  w0.w = efr[3];
    float4 w1; w1.x = efr[4];  w1.y = efr[5];  w1.z = efr[6];  w1.w = efr[7];
    float4 w2; w2.x = efr[8];  w2.y = efr[9];  w2.z = efr[10]; w2.w = efr[11];
    float4 w3, w4, w5;
    w3.x = efr[12]; w3.y = efr[13];
    w3.z = bits2f((unsigned)rbs[0]  | ((unsigned)rbs[1]  << 16));
    w3.w = bits2f((unsigned)rbs[2]  | ((unsigned)rbs[3]  << 16));
    w4.x = bits2f((unsigned)rbs[4]  | ((unsigned)rbs[5]  << 16));
    w4.y = bits2f((unsigned)rbs[6]  | ((unsigned)rbs[7]  << 16));
    w4.z = bits2f((unsigned)rbs[8]  | ((unsigned)rbs[9]  << 16));
    w4.w = bits2f((unsigned)rbs[10] | ((unsigned)rbs[11] << 16));
    w5.x = bits2f((unsigned)rbs[12] | ((unsigned)rbs[13] << 16));
    w5.y = bits2f((unsigned)rbs[14] | ((unsigned)rbs[15] << 16));
    w5.z = mean*rstd; w5.w = rstd;
    *(float4*)&pe[0]  = w0; *(float4*)&pe[4]  = w1; *(float4*)&pe[8]  = w2;
    *(float4*)&pe[12] = w3; *(float4*)&pe[16] = w4; *(float4*)&pe[20] = w5;
}

// ---------------------------------------------------------------------------
// Phase 2: per-node gather. One wave per node. Block's pre data is contiguous;
// each wave stages 32-edge chunks into its private LDS slab with vector loads,
// then reads wave-uniform (broadcast). No barriers.
// ---------------------------------------------------------------------------
__global__ __launch_bounds__(256) void gather_edge_kernel(
    const float* __restrict__ pre1, const float* __restrict__ pre2,
    const int* __restrict__ start1, const int* __restrict__ start2,
    const int* __restrict__ deg1, const int* __restrict__ deg2,
    const float* __restrict__ W_edge, const float* __restrict__ W_rbf,
    const float* __restrict__ b_rbf,
    const float* __restrict__ ln_g, const float* __restrict__ ln_b,
    float* __restrict__ h1, float* __restrict__ h2)
{
    const int side = blockIdx.y;
    const float* pre    = side ? pre2    : pre1;
    const int*   start  = side ? start2  : start1;
    const int*   deg    = side ? deg2    : deg1;
    float* h = side ? h2 : h1;

    __shared__ float stage[4][32*24];   // 12 KB, per-wave slabs

    const int lane = threadIdx.x & 63;
    const int wv = __builtin_amdgcn_readfirstlane(threadIdx.x >> 6);
    const int node = blockIdx.x*4 + wv;
    float* st_w = stage[wv];

    float wA[14], wB[16], wC[16], wD[16];
    #pragma unroll
    for (int k = 0; k < 14; k++) wA[k] = W_edge[k*100 + lane];
    #pragma unroll
    for (int k = 0; k < 16; k++) wB[k] = W_rbf[k*100 + 28 + lane];
    if (lane < 36) {
        #pragma unroll
        for (int k = 0; k < 14; k++) wC[k] = W_edge[k*100 + 64 + lane];
        #pragma unroll
        for (int k = 14; k < 16; k++) wC[k] = 0.0f;
    } else {
        #pragma unroll
        for (int k = 0; k < 16; k++) wC[k] = W_rbf[k*100 + (lane-36)];
    }
    if (lane < 8) {
        #pragma unroll
        for (int k = 0; k < 16; k++) wD[k] = W_rbf[k*100 + 92 + lane];
    } else {
        #pragma unroll
        for (int k = 0; k < 16; k++) wD[k] = 0.0f;
    }
    const float g0 = ln_g[lane],       bb0 = ln_b[lane];
    const float g1 = ln_g[64+lane],    bb1 = ln_b[64+lane];
    const float g2 = ln_g[128+lane],   bb2 = ln_b[128+lane];
    const float g3 = (lane<8) ? ln_g[192+lane] : 0.0f;
    const float bb3= (lane<8) ? ln_b[192+lane] : 0.0f;
    const float br2 = b_rbf[28+lane];
    const float br1 = (lane >= 36) ? b_rbf[lane-36] : 0.0f;
    const float br3 = (lane < 8)  ? b_rbf[92+lane] : 0.0f;

    const int st = __builtin_amdgcn_readfirstlane(start[node]);
    const int dg = __builtin_amdgcn_readfirstlane(deg[node]);
    const size_t base = (size_t)node * DH;

    const float h0  = h[base + lane];
    const float h1v = h[base + 64 + lane];
    const float h2v = h[base + 128 + lane];
    const float h3v = (lane < 8) ? h[base + 192 + lane] : 0.0f;

    float acc0 = 0.f, acc1 = 0.f, acc2 = 0.f, acc3 = 0.f, musum = 0.f;

    for (int c0 = 0; c0 < dg; c0 += 32) {
        const int cnt = (dg - c0 < 32) ? (dg - c0) : 32;
        const int o = lane*12;
        if (o < cnt*24) {
            const float* src = pre + (size_t)(st + c0)*24 + o;
            *(float4*)&st_w[o]   = *(const float4*)&src[0];
            *(float4*)&st_w[o+4] = *(const float4*)&src[4];
            *(float4*)&st_w[o+8] = *(const float4*)&src[8];
        }
        for (int i = 0; i < cnt; i++) {
            const int eb = i*24;
            float efr[14];
            #pragma unroll
            for (int k = 0; k < 14; k++) efr[k] = st_w[eb + k];
            float rbf[16];
            #pragma unroll
            for (int p = 0; p < 8; p++) {
                const unsigned u = __float_as_uint(st_w[eb + 14 + p]);
                rbf[2*p]   = bits2f(u << 16);
                rbf[2*p+1] = bits2f(u & 0xffff0000u);
            }
            const float musrtd = st_w[eb + 22];
            const float rstd   = st_w[eb + 23];

            float v0 = 0.f;
            #pragma unroll
            for (int k = 0; k < 14; k++) v0 += efr[k]*wA[k];
            v0 = fmaxf(v0, 0.f);

            float v2 = br2;
            #pragma unroll
            for (int k = 0; k < 16; k++) v2 += rbf[k]*wB[k];
            v2 = fmaxf(v2, 0.f);

            float v1;
            if (lane < 36) {
                v1 = 0.f;
                #pragma unroll
                for (int k = 0; k < 14; k++) v1 += efr[k]*wC[k];
            } else {
                v1 = br1;
                #pragma unroll
                for (int k = 0; k < 16; k++) v1 += rbf[k]*wC[k];
            }
            v1 = fmaxf(v1, 0.f);

            float v3 = br3;
            #pragma unroll
            for (int k = 0; k < 16; k++) v3 += rbf[k]*wD[k];
            v3 = fmaxf(v3, 0.f);

            acc0 += rstd*v0;
            acc1 += rstd*v1;
            acc2 += rstd*v2;
            acc3 += rstd*v3;
            musum += musrtd;
        }
    }

    const float dgf = (float)dg;
    h[base + lane]       = h0  + g0*(acc0 - musum) + dgf*bb0;
    h[base + 64 + lane]  = h1v + g1*(acc1 - musum) + dgf*bb1;
    h[base + 128 + lane] = h2v + g2*(acc2 - musum) + dgf*bb2;
    if (lane < 8)
        h[base + 192 + lane] = h3v + g3*(acc3 - musum) + dgf*bb3;
}

// ---------------------------------------------------------------------------
// cvt (per half): h fp32 -> hb hi/lo [16384][224] rows + hbT hi/lo [32][224][512]
// ---------------------------------------------------------------------------
__global__ __launch_bounds__(256) void cvt_kernel(
    const float* __restrict__ h1, const float* __restrict__ h2, const int half,
    short* __restrict__ hbH1, short* __restrict__ hbL1,
    short* __restrict__ hbH2, short* __restrict__ hbL2,
    short* __restrict__ hTH1, short* __restrict__ hTL1,
    short* __restrict__ hTH2, short* __restrict__ hTL2)
{
    const int side = blockIdx.y;
    const float* h = side ? h2 : h1;
    short* hbH = side ? hbH2 : hbH1;
    short* hbL = side ? hbL2 : hbL1;
    short* hTH = side ? hTH2 : hTH1;
    short* hTL = side ? hTL2 : hTL1;

    const int nl0 = blockIdx.x * 64;          // local node
    const int bl = nl0 >> 9, m0 = nl0 & 511;
    const int ng0 = half*HBN + nl0;

    __shared__ short tH[64][226];
    __shared__ short tL[64][226];
    const int tid = threadIdx.x;
    for (int i = tid; i < 64*224; i += 256) {
        const int r = i / 224, c = i - r*224;
        const float v = (c < DH) ? h[(size_t)(ng0+r)*DH + c] : 0.f;
        const short hi = f2bf(v);
        const short lo = f2bf(v - bf2f(hi));
        tH[r][c] = hi; tL[r][c] = lo;
        hbH[(size_t)(nl0+r)*224 + c] = hi;
        hbL[(size_t)(nl0+r)*224 + c] = lo;
    }
    __syncthreads();
    for (int i = tid; i < 224*64; i += 256) {
        const int c = i >> 6, m = i & 63;
        const size_t o = ((size_t)bl*224 + c)*NN + m0 + m;
        hTH[o] = tH[m][c];
        hTL[o] = tL[m][c];
    }
}

// ---------------------------------------------------------------------------
// prep_w: W_down[400][200] -> WbTHI/LO[208][448] (transposed, padded, split)
// ---------------------------------------------------------------------------
__global__ __launch_bounds__(256) void prep_w_kernel(
    const float* __restrict__ W_down,
    short* __restrict__ WbTHI, short* __restrict__ WbTLO)
{
    const int idx = blockIdx.x*256 + threadIdx.x;
    if (idx >= 208*448) return;
    const int c = idx / 448, kk = idx - c*448;
    float v = 0.f;
    if (c < 200) {
        if (kk < 200) v = W_down[(size_t)kk*DH + c];
        else if (kk >= 224 && kk < 424) v = W_down[(size_t)(200 + kk - 224)*DH + c];
    }
    const short hi = f2bf(v);
    WbTHI[idx] = hi;
    WbTLO[idx] = f2bf(v - bf2f(hi));
}

// ---------------------------------------------------------------------------
// Fused attention v3: 16 Q-rows per block (grid 32x32 = 1024 blocks -> 4/CU),
// 4 waves split the 32 key-tiles (acc[8] each); cross-wave softmax via LDS;
// K/V fragments streamed from global (L2); 3 barriers per block.
// ---------------------------------------------------------------------------
__global__ __launch_bounds__(256, 4) void attn_kernel(
    const short* __restrict__ QH, const short* __restrict__ QL,
    const short* __restrict__ KH, const short* __restrict__ KL,
    const short* __restrict__ VTH, const short* __restrict__ VTL,
    short* __restrict__ cb)
{
    const int b = blockIdx.y;                 // half-local batch
    const int q0 = blockIdx.x * 16;
    const short* Qh = QH + (size_t)b*NN*224;
    const short* Ql = QL + (size_t)b*NN*224;
    const short* Kh = KH + (size_t)b*NN*224;
    const short* Kl = KL + (size_t)b*NN*224;
    const short* Vh = VTH + (size_t)b*224*NN;
    const short* Vl = VTL + (size_t)b*224*NN;

    __shared__ short pb[16*520];              // 16.3 KB P bf16
    __shared__ float sm_[4][16];
    __shared__ float ss_[4][16];

    const int tid = threadIdx.x;
    const int wv = tid >> 6, lane = tid & 63;
    const int arow = lane & 15, aq = lane >> 4;

    // Q fragments in registers (A-layout): all waves use the same 16 rows
    const int qrow = q0 + arow;
    short8 qfh[7], qfl[7];
    #pragma unroll
    for (int k = 0; k < 7; k++) {
        qfh[k] = *(const short8*)&Qh[(size_t)qrow*224 + k*32 + aq*8];
        qfl[k] = *(const short8*)&Ql[(size_t)qrow*224 + k*32 + aq*8];
    }

    // QK^T: wave wv handles key-tiles nt = wv*8 + t  (16 keys each)
    f32x4 acc[8];
    #pragma unroll
    for (int t = 0; t < 8; t++) acc[t] = (f32x4){0.f,0.f,0.f,0.f};

    #pragma unroll
    for (int t = 0; t < 8; t++) {
        const size_t kb = (size_t)((wv*8 + t)*16 + arow)*224;
        #pragma unroll
        for (int k = 0; k < 7; k++) {
            const short8 bh = *(const short8*)&Kh[kb + k*32 + aq*8];
            const short8 bl = *(const short8*)&Kl[kb + k*32 + aq*8];
            acc[t] = __builtin_amdgcn_mfma_f32_16x16x32_bf16(qfh[k], bh, acc[t], 0, 0, 0);
            acc[t] = __builtin_amdgcn_mfma_f32_16x16x32_bf16(qfh[k], bl, acc[t], 0, 0, 0);
            acc[t] = __builtin_amdgcn_mfma_f32_16x16x32_bf16(qfl[k], bh, acc[t], 0, 0, 0);
        }
    }

    // softmax: lane holds rows aq*4+r, cols (wv*8+t)*16+arow
    float mr[4], sr[4], iv[4];
    #pragma unroll
    for (int r = 0; r < 4; r++) {
        float m = -1e30f;
        #pragma unroll
        for (int t = 0; t < 8; t++) {
            acc[t][r] *= T_SCALE;
            m = fmaxf(m, acc[t][r]);
        }
        m = fmaxf(m, __shfl_xor(m, 1, 64));
        m = fmaxf(m, __shfl_xor(m, 2, 64));
        m = fmaxf(m, __shfl_xor(m, 4, 64));
        m = fmaxf(m, __shfl_xor(m, 8, 64));
        mr[r] = m;
    }
    if (arow == 0) {
        #pragma unroll
        for (int r = 0; r < 4; r++) sm_[wv][aq*4+r] = mr[r];
    }
    __syncthreads();
    #pragma unroll
    for (int r = 0; r < 4; r++) {
        const int row = aq*4 + r;
        const float M = fmaxf(fmaxf(sm_[0][row], sm_[1][row]),
                              fmaxf(sm_[2][row], sm_[3][row]));
        float s = 0.f;
        #pragma unroll
        for (int t = 0; t < 8; t++) {
            const float e = __expf(acc[t][r] - M);
            acc[t][r] = e;
            s += e;
        }
        s += __shfl_xor(s, 1, 64);
        s += __shfl_xor(s, 2, 64);
        s += __shfl_xor(s, 4, 64);
        s += __shfl_xor(s, 8, 64);
        sr[r] = s;
    }
    if (arow == 0) {
        #pragma unroll
        for (int r = 0; r < 4; r++) ss_[wv][aq*4+r] = sr[r];
    }
    __syncthreads();
    #pragma unroll
    for (int r = 0; r < 4; r++) {
        const int row = aq*4 + r;
        iv[r] = 1.0f / (ss_[0][row] + ss_[1][row] + ss_[2][row] + ss_[3][row]);
    }

    // write P bf16 (rows aq*4+r, this wave's cols)
    #pragma unroll
    for (int t = 0; t < 8; t++) {
        const int col = (wv*8 + t)*16 + arow;
        #pragma unroll
        for (int r = 0; r < 4; r++)
            pb[(aq*4 + r)*520 + col] = f2bf(acc[t][r] * iv[r]);
    }
    __syncthreads();

    // PV: N-tiles split {4,3,3,3} across waves; V streamed from global
    const int nbase = (wv == 0) ? 0 : 3*wv + 1;
    const int ncnt  = (wv == 0) ? 4 : 3;
    f32x4 pacc[4];
    #pragma unroll
    for (int t = 0; t < 4; t++) pacc[t] = (f32x4){0.f,0.f,0.f,0.f};

    for (int k0 = 0; k0 < NN; k0 += 32) {
        const short8 a = *(const short8*)&pb[arow*520 + k0 + aq*8];
        #pragma unroll
        for (int t = 0; t < 4; t++) {
            if (t < ncnt) {
                const size_t vb = (size_t)((nbase+t)*16 + arow)*NN + k0 + aq*8;
                const short8 bh = *(const short8*)&Vh[vb];
                const short8 bl = *(const short8*)&Vl[vb];
                pacc[t] = __builtin_amdgcn_mfma_f32_16x16x32_bf16(a, bh, pacc[t], 0, 0, 0);
                pacc[t] = __builtin_amdgcn_mfma_f32_16x16x32_bf16(a, bl, pacc[t], 0, 0, 0);
            }
        }
    }

    // epilogue: cb bf16, pad cols [200,224) with zeros
    #pragma unroll
    for (int t = 0; t < 4; t++) {
        if (t < ncnt) {
            const int col = (nbase+t)*16 + arow;
            #pragma unroll
            for (int r = 0; r < 4; r++) {
                const int row = q0 + aq*4 + r;
                const short v = (col < DH) ? f2bf(pacc[t][r]) : (short)0;
                cb[((size_t)b*NN + row)*224 + col] = v;
            }
        }
    }
    if (wv == 3) {
        const int col = 208 + arow;
        #pragma unroll
        for (int r = 0; r < 4; r++) {
            const int row = q0 + aq*4 + r;
            cb[((size_t)b*NN + row)*224 + col] = 0;
        }
    }
}

// ---------------------------------------------------------------------------
// down (per half, MFMA, split-W): relu([hb|cb] @ W_down) + degree_table -> hsg
// ---------------------------------------------------------------------------
__global__ __launch_bounds__(256) void down_mfma(
    const short* __restrict__ hbH1, const short* __restrict__ hbH2,
    const short* __restrict__ cb1, const short* __restrict__ cb2,
    const int* __restrict__ deg1, const int* __restrict__ deg2,
    const short* __restrict__ WbTH, const short* __restrict__ WbTL,
    const float* __restrict__ degree_table,
    float* __restrict__ hsg1, float* __restrict__ hsg2, const int half)
{
    const int side = blockIdx.y;
    const short* X0 = side ? hbH2 : hbH1;
    const short* X1 = side ? cb2 : cb1;
    const int*   dgp = side ? deg2 : deg1;
    float* hsg = side ? hsg2 : hsg1;

    const int nl0 = blockIdx.x * 64;
    const int ng0 = half*HBN + nl0;
    const int b = ng0 >> 9;

    __shared__ short As[64*40];
    __shared__ short BsH[208*40];
    __shared__ short BsL[208*40];
    __shared__ float part[208];

    const int tid = threadIdx.x;
    const int wv = tid >> 6, lane = tid & 63;
    const int arow = lane & 15, aq = lane >> 4;

    if (tid < 208) part[tid] = 0.f;

    f32x4 acc[13];
    #pragma unroll
    for (int t = 0; t < 13; t++) acc[t] = (f32x4){0.f,0.f,0.f,0.f};

    const int sr = tid >> 2, sc = (tid & 3) * 8;

    for (int phase = 0; phase < 2; phase++) {
        const short* X = phase ? X1 : X0;
        for (int k0 = 0; k0 < 224; k0 += 32) {
            __syncthreads();
            *(short8*)&As[sr*40 + sc] =
                *(const short8*)&X[(size_t)(nl0+sr)*224 + k0 + sc];
            const int kkg = phase*224 + k0;
            #pragma unroll
            for (int pass = 0; pass < 4; pass++) {
                const int f = pass*256 + tid;
                if (f < 832) {
                    const int d = f >> 2, cc = (f & 3) * 8;
                    *(short8*)&BsH[d*40 + cc] = *(const short8*)&WbTH[(size_t)d*448 + kkg + cc];
                    *(short8*)&BsL[d*40 + cc] = *(const short8*)&WbTL[(size_t)d*448 + kkg + cc];
                }
            }
            __syncthreads();
            const short8 a = *(const short8*)&As[(16*wv + arow)*40 + aq*8];
            #pragma unroll
            for (int t = 0; t < 13; t++) {
                const short8 bh = *(const short8*)&BsH[(t*16 + arow)*40 + aq*8];
                const short8 bl = *(const short8*)&BsL[(t*16 + arow)*40 + aq*8];
                acc[t] = __builtin_amdgcn_mfma_f32_16x16x32_bf16(a, bh, acc[t], 0, 0, 0);
                acc[t] = __builtin_amdgcn_mfma_f32_16x16x32_bf16(a, bl, acc[t], 0, 0, 0);
            }
        }
    }
    __syncthreads();

    int dgc[4];
    #pragma unroll
    for (int r = 0; r < 4; r++) {
        int d = dgp[ng0 + 16*wv + aq*4 + r];
        dgc[r] = d > 199 ? 199 : d;
    }
    #pragma unroll
    for (int nt = 0; nt < 13; nt++) {
        const int col = nt*16 + arow;
        float s = 0.f;
        if (col < DH) {
            #pragma unroll
            for (int r = 0; r < 4; r++)
                s += fmaxf(acc[nt][r], 0.f) + degree_table[dgc[r]*DH + col];
        }
        s += __shfl_xor(s, 16, 64);
        s += __shfl_xor(s, 32, 64);
        if (lane < 16 && col < DH) atomicAdd(&part[col], s);
    }
    __syncthreads();
    if (tid < DH) unsafeAtomicAdd(&hsg[b*206 + tid], part[tid] * (1.0f/512.0f));
}

// ---------------------------------------------------------------------------
// Kernel 6: interaction mean over nodes -> hsg cols 200..205
// ---------------------------------------------------------------------------
__global__ __launch_bounds__(192) void inter_kernel(
    const float* __restrict__ i1, const float* __restrict__ i2,
    float* __restrict__ hsg1, float* __restrict__ hsg2)
{
    const int side = blockIdx.y;
    const float* it = side ? i2 : i1;
    float* hsg = side ? hsg2 : hsg1;
    const int b = blockIdx.x;
    __shared__ float red[192];
    const int tid = threadIdx.x;
    const int j = tid % 6, seg = tid / 6;
    float s = 0.0f;
    for (int n = seg*16; n < seg*16 + 16; n++)
        s += it[(size_t)b*NN*DI + n*DI + j];
    red[tid] = s;
    __syncthreads();
    if (tid < 6) {
        float tot = 0.0f;
        for (int sg2 = 0; sg2 < 32; sg2++) tot += red[sg2*6 + tid];
        hsg[b*206 + 200 + tid] = tot * (1.0f/512.0f);
    }
}

// ---------------------------------------------------------------------------
// Kernel 7: final MLP, one block per batch row
// ---------------------------------------------------------------------------
__global__ __launch_bounds__(256) void mlp_kernel(
    const float* __restrict__ hsg1, const float* __restrict__ hsg2,
    const float* __restrict__ W_f1, const float* __restrict__ b_f1,
    const float* __restrict__ W_f2, const float* __restrict__ b_f2,
    const float* __restrict__ W_f3, const float* __restrict__ b_f3,
    const float* __restrict__ W_f4, const float* __restrict__ b_f4,
    float* __restrict__ out)
{
    const int b = blockIdx.x;
    __shared__ float x[618];
    __shared__ float y1[400];
    __shared__ float y2[200];
    __shared__ float y3[100];
    __shared__ float red[256];
    const int tid = threadIdx.x;

    if (tid < 206) {
        const float a = hsg1[b*206 + tid], bb = hsg2[b*206 + tid];
        x[tid] = a; x[206 + tid] = bb; x[412 + tid] = a - bb;
    }
    __syncthreads();
    for (int c = tid; c < 400; c += 256) {
        float acc = b_f1[c];
        for (int k = 0; k < 618; k++) acc += x[k]*W_f1[(size_t)k*400 + c];
        y1[c] = fmaxf(acc, 0.0f);
    }
    __syncthreads();
    if (tid < 200) {
        float acc = b_f2[tid];
        for (int k = 0; k < 400; k++) acc += y1[k]*W_f2[k*200 + tid];
        y2[tid] = fmaxf(acc, 0.0f);
    }
    __syncthreads();
    if (tid < 100) {
        float acc = b_f3[tid];
        for (int k = 0; k < 200; k++) acc += y2[k]*W_f3[k*100 + tid];
        y3[tid] = fmaxf(acc, 0.0f);
    }
    __syncthreads();
    red[tid] = (tid < 100) ? y3[tid]*W_f4[tid] : 0.0f;
    __syncthreads();
    for (int s = 128; s > 0; s >>= 1) {
        if (tid < s) red[tid] += red[tid + s];
        __syncthreads();
    }
    if (tid == 0) out[b] = red[0] + b_f4[0];
}

// ---------------------------------------------------------------------------
extern "C" void kernel_launch(void* const* d_in, const int* in_sizes, int n_in,
                              void* d_out, int out_size, void* d_ws, size_t ws_size,
                              hipStream_t stream)
{
    const float* atom1  = (const float*)d_in[0];
    const float* atom2  = (const float*)d_in[1];
    const float* coords1= (const float*)d_in[2];
    const float* coords2= (const float*)d_in[3];
    const float* efeat1 = (const float*)d_in[4];
    const float* efeat2 = (const float*)d_in[5];
    const float* inter1 = (const float*)d_in[6];
    const float* inter2 = (const float*)d_in[7];
    const int*   esrc1  = (const int*)d_in[8];
    const int*   edst1  = (const int*)d_in[9];
    const int*   esrc2  = (const int*)d_in[10];
    const int*   edst2  = (const int*)d_in[11];
    const float* W_atom = (const float*)d_in[12];
    const float* W_edge = (const float*)d_in[13];
    const float* W_rbf  = (const float*)d_in[14];
    const float* b_rbf  = (const float*)d_in[15];
    const float* ln_g   = (const float*)d_in[16];
    const float* ln_b   = (const float*)d_in[17];
    const float* W_down = (const float*)d_in[18];
    const float* deg_tab= (const float*)d_in[19];
    const float* W_f1   = (const float*)d_in[20];
    const float* b_f1   = (const float*)d_in[21];
    const float* W_f2   = (const float*)d_in[22];
    const float* b_f2   = (const float*)d_in[23];
    const float* W_f3   = (const float*)d_in[24];
    const float* b_f3   = (const float*)d_in[25];
    const float* W_f4   = (const float*)d_in[26];
    const float* b_f4   = (const float*)d_in[27];
    float* out = (float*)d_out;

    // ---- workspace layout (~159 MB)
    float* ws = (float*)d_ws;
    const size_t HSZ = (size_t)BN*DH;              // per-side h floats
    float* h1  = ws;
    float* h2  = h1 + HSZ;
    // pool region: max(pre 2*EE*24 floats = 100.7 MB, bf16 pool 73.4 MB)
    float* poolf = h2 + HSZ;
    const size_t PRESZ = (size_t)EE*24;
    float* pre1 = poolf;
    float* pre2 = pre1 + PRESZ;
    short* pool = (short*)poolf;
    const size_t HB = (size_t)32*NN*224;           // 3,670,016 shorts
    short* hbH1 = pool;           short* hbL1 = hbH1 + HB;
    short* hbH2 = hbL1 + HB;      short* hbL2 = hbH2 + HB;
    short* hTH1 = hbL2 + HB;      short* hTL1 = hTH1 + HB;
    short* hTH2 = hTL1 + HB;      short* hTL2 = hTH2 + HB;
    short* cb1  = hTL2 + HB;      short* cb2  = cb1 + HB;
    float* after = poolf + 2*PRESZ;
    short* WbTH = (short*)after;
    short* WbTL = WbTH + 208*448;
    float* hsg1 = (float*)(WbTL + 208*448);
    float* hsg2 = hsg1 + (size_t)BB*206;
    int* deg1 = (int*)(hsg2 + (size_t)BB*206);
    int* deg2 = deg1 + BN;
    int* start1 = deg2 + BN;
    int* start2 = start1 + BN;
    int* cursor1 = start2 + BN;
    int* cursor2 = cursor1 + BN;
    int* rank1 = cursor2 + BN;
    int* rank2 = rank1 + EE;

    hipMemsetAsync(deg1, 0, 2*(size_t)BN*sizeof(int), stream);
    hipMemsetAsync(hsg1, 0, 2*(size_t)BB*206*sizeof(float), stream);

    node_kernel<<<dim3(BN/4, 2), 256, 0, stream>>>(
        atom1, atom2, W_atom, ln_g, ln_b, h1, h2);

    hist_kernel<<<EE/256, 256, 0, stream>>>(edst1, edst2, deg1, deg2);
    scan_kernel<<<2, 1024, 0, stream>>>(deg1, deg2, start1, start2, cursor1, cursor2);
    scatter_kernel<<<EE/256, 256, 0, stream>>>(edst1, edst2, cursor1, cursor2,
                                               rank1, rank2);

    edge_pre_kernel<<<dim3(EE/256, 2), 256, 0, stream>>>(
        efeat1, efeat2, esrc1, esrc2, edst1, edst2, coords1, coords2,
        rank1, rank2, W_edge, W_rbf, b_rbf, pre1, pre2);

    gather_edge_kernel<<<dim3(BN/4, 2), 256, 0, stream>>>(
        pre1, pre2, start1, start2, deg1, deg2,
        W_edge, W_rbf, b_rbf, ln_g, ln_b, h1, h2);

    prep_w_kernel<<<(208*448 + 255)/256, 256, 0, stream>>>(W_down, WbTH, WbTL);

    for (int half = 0; half < 2; half++) {
        cvt_kernel<<<dim3(HBN/64, 2), 256, 0, stream>>>(
            h1, h2, half, hbH1, hbL1, hbH2, hbL2, hTH1, hTL1, hTH2, hTL2);
        // dir0: c1 = softmax_rows(h1@h2^T) @ h2
        attn_kernel<<<dim3(NN/16, 32), 256, 0, stream>>>(
            hbH1, hbL1, hbH2, hbL2, hTH2, hTL2, cb1);
        // dir1: c2 = softmax_rows(h2@h1^T) @ h1
        attn_kernel<<<dim3(NN/16, 32), 256, 0, stream>>>(
            hbH2, hbL2, hbH1, hbL1, hTH1, hTL1, cb2);
        down_mfma<<<dim3(HBN/64, 2), 256, 0, stream>>>(
            hbH1, hbH2, cb1, cb2, deg1, deg2, WbTH, WbTL, deg_tab,
            hsg1, hsg2, half);
    }

    inter_kernel<<<dim3(BB, 2), 192, 0, stream>>>(inter1, inter2, hsg1, hsg2);

    mlp_kernel<<<BB, 256, 0, stream>>>(
        hsg1, hsg2, W_f1, b_f1, W_f2, b_f2, W_f3, b_f3, W_f4, b_f4, out);
}